// Round 6
// baseline (247.380 us; speedup 1.0000x reference)
//
#include <hip/hip_runtime.h>
#include <math.h>

// Problem constants
#define BB 2
#define CC 64
#define NN 4096      // 16*16*16
#define CN (CC*NN)
#define NJ 4         // j-split chunks for flash partials
#define NT ((NN/NJ)/64)   // 16 j-tiles per chunk

#define LOG2E 1.4426950408889634f
#define QSCALE 0.18033688011112042f   // log2e / sqrt(64)

#define XT_ROWS 4097                  // row 0 = zero guard row
#define WQKV_OFF (27*80*64)           // offset of transposed QKV weights inside Wr
#define PST 68                        // P-tile LDS stride in floats (bank-balanced)

typedef __attribute__((ext_vector_type(8))) short short8;
typedef __attribute__((ext_vector_type(4))) float float4v;
typedef unsigned short ushortT;

__device__ __forceinline__ ushortT f2bf(float x) {
    union { float f; unsigned u; } v; v.f = x;
    unsigned r = v.u + 0x7FFF + ((v.u >> 16) & 1);   // RNE
    return (ushortT)(r >> 16);
}
__device__ __forceinline__ float bf2f(short s) {
    union { unsigned u; float f; } v;
    v.u = ((unsigned)(unsigned short)s) << 16;
    return v.f;
}
// pack 2 fp32 -> 1 VGPR holding 2 bf16: low16 = bf(a), high16 = bf(b)
__device__ __forceinline__ unsigned pk2(float a, float b) {
    unsigned ua = __float_as_uint(a) + 0x8000u;
    unsigned ub = __float_as_uint(b) + 0x8000u;
    return __builtin_amdgcn_perm(ub, ua, 0x07060302);
}
__device__ __forceinline__ short8 pack8(float4 a, float4 b) {
    union { unsigned u[4]; short8 s; } r;
    r.u[0] = pk2(a.x, a.y); r.u[1] = pk2(a.z, a.w);
    r.u[2] = pk2(b.x, b.y); r.u[3] = pk2(b.z, b.w);
    return r.s;
}

// ---------------- PE table value: global channel c (0..63), coord 0..15 ----------------
__device__ __forceinline__ float pe_tab_val(int c, int pos) {
    int c2 = (c < 22) ? c : (c < 44) ? (c - 22) : (c - 44);
    int is_cos = (c2 >= 11);
    int k = c2 - (is_cos ? 11 : 0);
    float freq = exp2f(-1.2079738526863135f * (float)k);
    float arg = (float)pos * freq;
    return is_cos ? cosf(arg) : sinf(arg);
}

// ---------------- Merged: x_pe + Xt transpose (blocks 0..255) | weight reorg (blocks 256..) ----------------
__global__ __launch_bounds__(256) void k_pre(const float* __restrict__ x,
                                             const float* __restrict__ qw,
                                             const float* __restrict__ kw,
                                             const float* __restrict__ vw,
                                             const float* __restrict__ Wq,
                                             const float* __restrict__ Wk,
                                             const float* __restrict__ Wv,
                                             float* __restrict__ xpe,
                                             ushortT* __restrict__ Xt,
                                             ushortT* __restrict__ Wr) {
    int blk = blockIdx.x, t = threadIdx.x;
    if (blk < 256) {
        __shared__ float sPE[64][17];
        __shared__ float sT[64][33];
        int b = blk >> 7, pos0 = (blk & 127) * 32;
        #pragma unroll
        for (int k = 0; k < 4; k++) {
            int e = t + k * 256;            // 0..1023
            int c = e >> 4, coord = e & 15;
            sPE[c][coord] = pe_tab_val(c, coord);
        }
        __syncthreads();
        int pin = t & 31, cg = t >> 5;
        #pragma unroll
        for (int pass = 0; pass < 8; pass++) {
            int c = pass * 8 + cg;
            int pos = pos0 + pin;
            int coord = (c < 22) ? (pos >> 8) : (c < 44) ? ((pos >> 4) & 15) : (pos & 15);
            size_t gi = (size_t)(b * 64 + c) * NN + pos;
            float v = x[gi] + sPE[c][coord];
            xpe[gi] = v;
            sT[c][pin] = v;
        }
        __syncthreads();
        int icn = t & 63, pg = t >> 6;
        #pragma unroll
        for (int pass = 0; pass < 8; pass++) {
            int po = pass * 4 + pg;
            Xt[((size_t)b * XT_ROWS + pos0 + po + 1) * 64 + icn] = f2bf(sT[icn][po]);
        }
        if ((blk & 127) == 0 && t < 64)
            Xt[((size_t)b * XT_ROWS) * 64 + t] = 0;   // zero guard row
    } else {
        int idx = (blk - 256) * 256 + t;
        if (idx < WQKV_OFF) {
            int ic = idx & 63;
            int oc = (idx >> 6) % 80;
            int tap = idx / 5120;
            float v;
            if (oc < 8)       v = qw[(oc * 64 + ic) * 27 + tap] * LOG2E;
            else if (oc < 16) v = kw[((oc - 8) * 64 + ic) * 27 + tap];
            else              v = vw[((oc - 16) * 64 + ic) * 27 + tap];
            Wr[idx] = f2bf(v);
        } else if (idx < WQKV_OFF + 3 * 64 * 64) {
            int idx2 = idx - WQKV_OFF;
            int c = idx2 & 63, d = (idx2 >> 6) & 63, mat = idx2 >> 12;
            const float* Wm = (mat == 0) ? Wq : (mat == 1) ? Wk : Wv;
            float v = Wm[c * 64 + d] * ((mat == 0) ? QSCALE : 1.f);
            Wr[idx] = f2bf(v);
        }
    }
}

// ---------------- Merged producers: QKV (y=0..2) + conv (y=3..7) ----------------
__global__ __launch_bounds__(256) void k_prod(const ushortT* __restrict__ Xt,
                                              const ushortT* __restrict__ Wr,
                                              const float* __restrict__ qb,
                                              const float* __restrict__ kb,
                                              const float* __restrict__ vb,
                                              ushortT* __restrict__ Qb,
                                              ushortT* __restrict__ Kb,
                                              ushortT* __restrict__ Vtb,
                                              ushortT* __restrict__ Mt,
                                              ushortT* __restrict__ Nt,
                                              ushortT* __restrict__ Wvt) {
    int t = threadIdx.x, w = t >> 6, l = t & 63;
    int lane15 = l & 15, q = l >> 4;
    int b = blockIdx.z, y = blockIdx.y;
    if (y < 3) {
        // ---- QKV via MFMA: wave = 16 rows x 64 cols, K=64 ----
        int mat = y;
        int i0 = blockIdx.x * 64 + w * 16;
        const ushortT* Wt = Wr + WQKV_OFF + mat * 4096;
        const ushortT* xrow = Xt + ((size_t)b * XT_ROWS + i0 + lane15 + 1) * 64;
        short8 a0 = *(const short8*)(xrow + q * 8);
        short8 a1 = *(const short8*)(xrow + 32 + q * 8);
        float4v acc[4];
        #pragma unroll
        for (int cg = 0; cg < 4; cg++) {
            const ushortT* wrow = Wt + (cg * 16 + lane15) * 64;
            short8 b0 = *(const short8*)(wrow + q * 8);
            short8 b1 = *(const short8*)(wrow + 32 + q * 8);
            float4v a = (float4v)0.f;
            a = __builtin_amdgcn_mfma_f32_16x16x32_bf16(a0, b0, a, 0, 0, 0);
            a = __builtin_amdgcn_mfma_f32_16x16x32_bf16(a1, b1, a, 0, 0, 0);
            acc[cg] = a;
        }
        if (mat < 2) {
            ushortT* o = (mat == 0) ? Qb : Kb;
            #pragma unroll
            for (int cg = 0; cg < 4; cg++)
                #pragma unroll
                for (int r = 0; r < 4; r++)
                    o[((size_t)(b * NN + i0 + q * 4 + r)) * 64 + cg * 16 + lane15] = f2bf(acc[cg][r]);
        } else {
            #pragma unroll
            for (int cg = 0; cg < 4; cg++)
                #pragma unroll
                for (int r = 0; r < 4; r++)
                    Vtb[((size_t)(b * 64 + cg * 16 + lane15)) * NN + i0 + q * 4 + r] = f2bf(acc[cg][r]);
        }
    } else {
        // ---- conv via per-tap MFMA implicit GEMM: wave = 16 pos x 16 oc ----
        int ocg = y - 3;
        int pos0 = blockIdx.x * 64 + w * 16;
        const ushortT* xb = Xt + (size_t)b * XT_ROWS * 64;
        int pos = pos0 + lane15;
        int dz = pos & 15, wy = (pos >> 4) & 15, hx = pos >> 8;
        float4v acc = (float4v)0.f;
        #pragma unroll
        for (int tap = 0; tap < 27; tap++) {
            const int dh = tap / 9 - 1, dw = (tap / 3) % 3 - 1, dd = tap % 3 - 1;
            const int shift = dh * 256 + dw * 16 + dd;
            const ushortT* wrow = Wr + ((size_t)tap * 80 + ocg * 16 + lane15) * 64 + q * 8;
            short8 a0 = *(const short8*)(wrow);
            short8 a1 = *(const short8*)(wrow + 32);
            bool ok = ((unsigned)(hx + dh) < 16u) &&
                      ((unsigned)(wy + dw) < 16u) &&
                      ((unsigned)(dz + dd) < 16u);
            int row = ok ? (pos + shift + 1) : 0;
            const ushortT* xrow = xb + (size_t)row * 64 + q * 8;
            short8 b0 = *(const short8*)xrow;
            short8 b1 = *(const short8*)(xrow + 32);
            acc = __builtin_amdgcn_mfma_f32_16x16x32_bf16(a0, b0, acc, 0, 0, 0);
            acc = __builtin_amdgcn_mfma_f32_16x16x32_bf16(a1, b1, acc, 0, 0, 0);
        }
        if (ocg == 0) {
            #pragma unroll
            for (int r = 0; r < 4; r++) {
                int ol = q * 4 + r;
                float v = acc[r];
                if (ol < 8)
                    Mt[((size_t)(b * NN + pos)) * 8 + ol] = f2bf(v + qb[ol] * LOG2E);
                else
                    Nt[((size_t)(b * NN + pos)) * 8 + (ol - 8)] = f2bf(v + kb[ol - 8]);
            }
        } else {
            #pragma unroll
            for (int r = 0; r < 4; r++) {
                int oc = (ocg - 1) * 16 + q * 4 + r;
                Wvt[((size_t)(b * 64 + oc)) * NN + pos] = f2bf(acc[r] + vb[oc]);
            }
        }
    }
}

// ---------------- MFMA flash body: ONLINE softmax in S^T layout ----------------
template<int KCH>
__device__ __forceinline__ void load_kf(short8 (&kf)[4][KCH], const ushortT* __restrict__ Km,
                                        int b, int jb, int lane15, int q, int DQ) {
    #pragma unroll
    for (int sub = 0; sub < 4; sub++) {
        const ushortT* krow = Km + ((size_t)(b * NN + jb + sub * 16 + lane15)) * DQ;
        if (KCH == 2) {
            kf[sub][0] = *(const short8*)(krow + q * 8);
            kf[sub][1] = *(const short8*)(krow + 32 + q * 8);
        } else {
            short8 z = (short8)0;
            if (q == 0) z = *(const short8*)krow;
            kf[sub][0] = z;
        }
    }
}

template<int DQ>
__device__ __forceinline__ void flash_body(int it, int jc, int b, int w, int l,
                                           const ushortT* __restrict__ Qm,
                                           const ushortT* __restrict__ Km,
                                           const ushortT* __restrict__ Vt,
                                           float* __restrict__ pM,
                                           float* __restrict__ pL,
                                           ushortT* __restrict__ pAcc,
                                           float* __restrict__ myP) {
    constexpr int KCH = (DQ == 64) ? 2 : 1;
    int lane15 = l & 15, q = l >> 4;
    int i0 = it * 64 + w * 16;

    // Q fragments (B-operand: lane n = query i, k = channel)
    short8 qf[KCH];
    {
        const ushortT* qrow = Qm + ((size_t)(b * NN + i0 + lane15)) * DQ;
        if (KCH == 2) {
            qf[0] = *(const short8*)(qrow + q * 8);
            qf[1] = *(const short8*)(qrow + 32 + q * 8);
        } else {
            short8 z = (short8)0;
            if (q == 0) z = *(const short8*)qrow;
            qf[0] = z;
        }
    }

    float m_run = -3e38f;   // running row max for query i = lane15 (log2 domain)
    float Lacc = 0.f;       // per-lane partial denominator (this lane's j-subset)
    float4v O[4];
    #pragma unroll
    for (int cs = 0; cs < 4; cs++) O[cs] = (float4v)0.f;

    const int jbase0 = jc * (NN / NJ);

    short8 kf[4][KCH];
    load_kf<KCH>(kf, Km, b, jbase0, lane15, q, DQ);

    float* wr_base = myP + lane15 * PST + q * 4;
    const float* rd_base = myP + lane15 * PST + q * 8;

    for (int jt = 0; jt < NT; jt++) {
        int jb = jbase0 + jt * 64;

        // V loads (B-operand for PV: lane n = channel c, k = j)
        short8 va[4], vb_[4];
        #pragma unroll
        for (int sub = 0; sub < 4; sub++) {
            const ushortT* vrow = Vt + ((size_t)(b * 64 + sub * 16 + lane15)) * NN + jb;
            va[sub]  = *(const short8*)(vrow + q * 8);
            vb_[sub] = *(const short8*)(vrow + 32 + q * 8);
        }

        // ---- S^T = K Q^T: lane holds col i = lane15, rows j = sub*16 + q*4 + r ----
        float4v s[4];
        #pragma unroll
        for (int sub = 0; sub < 4; sub++) {
            float4v acc = (float4v)0.f;
            #pragma unroll
            for (int kc = 0; kc < KCH; kc++)
                acc = __builtin_amdgcn_mfma_f32_16x16x32_bf16(kf[sub][kc], qf[kc], acc, 0, 0, 0);
            s[sub] = acc;
        }

        // reload K for next tile (in flight during softmax + PV)
        int jn = (jt + 1 < NT) ? (jb + 64) : jbase0;
        load_kf<KCH>(kf, Km, b, jn, lane15, q, DQ);

        // ---- online softmax: row max for query lane15 (2 shfls) ----
        float tmax = fmaxf(fmaxf(fmaxf(s[0][0], s[0][1]), fmaxf(s[0][2], s[0][3])),
                           fmaxf(fmaxf(s[1][0], s[1][1]), fmaxf(s[1][2], s[1][3])));
        float tmax2 = fmaxf(fmaxf(fmaxf(s[2][0], s[2][1]), fmaxf(s[2][2], s[2][3])),
                            fmaxf(fmaxf(s[3][0], s[3][1]), fmaxf(s[3][2], s[3][3])));
        tmax = fmaxf(tmax, tmax2);
        tmax = fmaxf(tmax, __shfl_xor(tmax, 16));
        tmax = fmaxf(tmax, __shfl_xor(tmax, 32));
        float mnew = fmaxf(m_run, tmax);
        float corr = exp2f(m_run - mnew);
        m_run = mnew;

        // ---- P = exp2(s - m), L accum, P -> LDS[i][j] ----
        float lsum = 0.f;
        #pragma unroll
        for (int sub = 0; sub < 4; sub++) {
            float4 p;
            p.x = exp2f(s[sub][0] - mnew);
            p.y = exp2f(s[sub][1] - mnew);
            p.z = exp2f(s[sub][2] - mnew);
            p.w = exp2f(s[sub][3] - mnew);
            lsum += (p.x + p.y) + (p.z + p.w);
            *(float4*)(wr_base + sub * 16) = p;
        }
        Lacc = Lacc * corr + lsum;

        // ---- O rescale: corr transposed to O's row index i = q*4+r ----
        float c0 = __shfl(corr, q * 4 + 0);
        float c1 = __shfl(corr, q * 4 + 1);
        float c2 = __shfl(corr, q * 4 + 2);
        float c3 = __shfl(corr, q * 4 + 3);
        #pragma unroll
        for (int cs = 0; cs < 4; cs++) {
            O[cs][0] *= c0; O[cs][1] *= c1; O[cs][2] *= c2; O[cs][3] *= c3;
        }

        // ---- A-frag for PV: lane i reads its 8 contiguous j, pack to bf16 ----
        short8 pf[2];
        #pragma unroll
        for (int kc = 0; kc < 2; kc++) {
            const float* rp = rd_base + kc * 32;
            float4 f0 = *(const float4*)rp;
            float4 f1 = *(const float4*)(rp + 4);
            pf[kc] = pack8(f0, f1);
        }

        // ---- O += P V ----
        #pragma unroll
        for (int sub = 0; sub < 4; sub++) {
            O[sub] = __builtin_amdgcn_mfma_f32_16x16x32_bf16(pf[0], va[sub], O[sub], 0, 0, 0);
            O[sub] = __builtin_amdgcn_mfma_f32_16x16x32_bf16(pf[1], vb_[sub], O[sub], 0, 0, 0);
        }
    }

    // ---- store partials ----
    size_t base = (size_t)(b * NJ + jc) * NN + i0;
    Lacc += __shfl_xor(Lacc, 16);
    Lacc += __shfl_xor(Lacc, 32);
    if (q == 0) {
        pL[base + lane15] = Lacc;
        pM[base + lane15] = m_run;
    }
    #pragma unroll
    for (int cs = 0; cs < 4; cs++)
        #pragma unroll
        for (int r = 0; r < 4; r++)
            pAcc[(base + q * 4 + r) * 64 + cs * 16 + lane15] = f2bf(O[cs][r]);
}

// ---------------- Merged flash kernel (TSA blocks 0..63, GSA blocks 64..127) ----------------
__global__ __launch_bounds__(256, 4) void k_flash(const ushortT* __restrict__ Qb,
                                                  const ushortT* __restrict__ Kb,
                                                  const ushortT* __restrict__ Vtb,
                                                  const ushortT* __restrict__ Mtb,
                                                  const ushortT* __restrict__ Ntb,
                                                  const ushortT* __restrict__ Wvtb,
                                                  float* __restrict__ pMt, float* __restrict__ pLt,
                                                  ushortT* __restrict__ pAccT,
                                                  float* __restrict__ pMg, float* __restrict__ pLg,
                                                  ushortT* __restrict__ pAccG) {
    __shared__ float sPf[4][16 * PST];
    int t = threadIdx.x, w = t >> 6, l = t & 63;
    int b = blockIdx.z, jc = blockIdx.y;
    if (blockIdx.x < 64)
        flash_body<64>(blockIdx.x, jc, b, w, l, Qb, Kb, Vtb, pMt, pLt, pAccT, sPf[w]);
    else
        flash_body<8>(blockIdx.x - 64, jc, b, w, l, Mtb, Ntb, Wvtb, pMg, pLg, pAccG, sPf[w]);
}

// ---------------- Reduce both partial sets (max-merge) + fused epilogue ----------------
__device__ __forceinline__ void reduce_set(const float* __restrict__ pM,
                                           const float* __restrict__ pL,
                                           const ushortT* __restrict__ pAcc,
                                           int b, int n, int seg, float* v) {
    float mv[NJ], M = -3e38f;
    #pragma unroll
    for (int jcc = 0; jcc < NJ; jcc++) {
        mv[jcc] = pM[(size_t)(b * NJ + jcc) * NN + n];
        M = fmaxf(M, mv[jcc]);
    }
    float L = 0.f;
    #pragma unroll
    for (int e = 0; e < 8; e++) v[e] = 0.f;
    #pragma unroll
    for (int jcc = 0; jcc < NJ; jcc++) {
        size_t rb = (size_t)(b * NJ + jcc) * NN + n;
        float wgt = exp2f(mv[jcc] - M);
        L += pL[rb] * wgt;
        short8 x0 = *(const short8*)(pAcc + rb * 64 + seg * 8);
        #pragma unroll
        for (int e = 0; e < 8; e++) v[e] += wgt * bf2f(x0[e]);
    }
    float invL = 1.f / L;
    #pragma unroll
    for (int e = 0; e < 8; e++) v[e] *= invL;
}

__global__ __launch_bounds__(256) void k_reduce(const float* __restrict__ pMt,
                                                const float* __restrict__ pLt,
                                                const ushortT* __restrict__ pAccT,
                                                const float* __restrict__ pMg,
                                                const float* __restrict__ pLg,
                                                const ushortT* __restrict__ pAccG,
                                                const float* __restrict__ xpe,
                                                const float* __restrict__ lam1,
                                                const float* __restrict__ lam2,
                                                float* __restrict__ out) {
    __shared__ float sT[32][65];
    __shared__ float sG[32][65];
    int t = threadIdx.x;
    int b = blockIdx.y;
    int n0 = blockIdx.x * 32;
    int pp = t >> 3, seg = t & 7;
    int n = n0 + pp;

    float vt[8], vg[8];
    reduce_set(pMt, pLt, pAccT, b, n, seg, vt);
    reduce_set(pMg, pLg, pAccG, b, n, seg, vg);
    #pragma unroll
    for (int e = 0; e < 8; e++) {
        sT[pp][seg * 8 + e] = vt[e];
        sG[pp][seg * 8 + e] = vg[e];
    }
    __syncthreads();

    int c = t >> 2, ns = (t & 3) * 8;
    float la1 = lam1[0], la2 = lam2[0];
    size_t ob = ((size_t)(b * 64 + c)) * NN + n0 + ns;
    const float* xp = xpe + ob;
    #pragma unroll
    for (int j = 0; j < 8; j += 4) {
        float4 ov;
        ov.x = la1 * sT[ns + j + 0][c] + la2 * sG[ns + j + 0][c] + xp[j + 0];
        ov.y = la1 * sT[ns + j + 1][c] + la2 * sG[ns + j + 1][c] + xp[j + 1];
        ov.z = la1 * sT[ns + j + 2][c] + la2 * sG[ns + j + 2][c] + xp[j + 2];
        ov.w = la1 * sT[ns + j + 3][c] + la2 * sG[ns + j + 3][c] + xp[j + 3];
        *(float4*)(out + ob + j) = ov;
    }
}

extern "C" void kernel_launch(void* const* d_in, const int* in_sizes, int n_in,
                              void* d_out, int out_size, void* d_ws, size_t ws_size,
                              hipStream_t stream) {
    const float* x    = (const float*)d_in[0];
    const float* Wq   = (const float*)d_in[1];
    const float* Wk   = (const float*)d_in[2];
    const float* Wv   = (const float*)d_in[3];
    const float* qw   = (const float*)d_in[4];
    const float* qb   = (const float*)d_in[5];
    const float* kw   = (const float*)d_in[6];
    const float* kb   = (const float*)d_in[7];
    const float* vw   = (const float*)d_in[8];
    const float* vb   = (const float*)d_in[9];
    const float* lam1 = (const float*)d_in[10];
    const float* lam2 = (const float*)d_in[11];
    float* out = (float*)d_out;

    char* W = (char*)d_ws;
    float*   xpe   = (float*)(W);                               // 2 MB
    ushortT* Qb    = (ushortT*)(W + (2u << 20));                // 1 MB
    ushortT* Kb    = (ushortT*)(W + (3u << 20));                // 1 MB
    ushortT* Vtb   = (ushortT*)(W + (4u << 20));                // 1 MB
    ushortT* Mtb   = (ushortT*)(W + (5u << 20));                // 128 KB
    ushortT* Ntb   = (ushortT*)(W + (5u << 20) + (1u << 17));   // 128 KB
    ushortT* Wvtb  = (ushortT*)(W + (5u << 20) + (2u << 17));   // 1 MB
    ushortT* Xt    = (ushortT*)(W + (6u << 20) + (2u << 17));   // ~1.0 MB
    ushortT* Wr    = (ushortT*)(W + (7u << 20) + (1u << 19));   // ~0.3 MB
    float*   pLt   = (float*)(W + (8u << 20));                  // 128 KB
    float*   pLg   = (float*)(W + (8u << 20) + (1u << 17));     // 128 KB
    float*   pMt   = (float*)(W + (8u << 20) + (2u << 17));     // 128 KB
    float*   pMg   = (float*)(W + (8u << 20) + (3u << 17));     // 128 KB
    ushortT* pAccT = (ushortT*)(W + (8u << 20) + (4u << 17));   // 4 MB
    ushortT* pAccG = (ushortT*)(W + (12u << 20) + (4u << 17));  // 4 MB (ends 16.5 MB)

    // 1. x_pe + Xt transpose + weight reorg (one launch)
    k_pre<<<dim3(256 + (WQKV_OFF + 3 * 64 * 64 + 255) / 256), dim3(256), 0, stream>>>(
        x, qw, kw, vw, Wq, Wk, Wv, xpe, Xt, Wr);
    // 2. QKV + conv producers (one launch)
    k_prod<<<dim3(64, 8, BB), dim3(256), 0, stream>>>(
        Xt, Wr, qb, kb, vb, Qb, Kb, Vtb, Mtb, Ntb, Wvtb);
    // 3. merged TSA+GSA flash (online softmax, S^T layout)
    k_flash<<<dim3(128, NJ, BB), dim3(256), 0, stream>>>(
        Qb, Kb, Vtb, Mtb, Ntb, Wvtb, pMt, pLt, pAccT, pMg, pLg, pAccG);
    // 4. merged reduce + epilogue
    k_reduce<<<dim3(NN / 32, BB), dim3(256), 0, stream>>>(
        pMt, pLt, pAccT, pMg, pLg, pAccG, xpe, lam1, lam2, out);
}

// Round 7
// 167.732 us; speedup vs baseline: 1.4749x; 1.4749x over previous
//
#include <hip/hip_runtime.h>
#include <math.h>

// Problem constants
#define BB 2
#define CC 64
#define NN 4096      // 16*16*16
#define CN (CC*NN)
#define NJ 4         // j-split chunks for flash partials
#define NT ((NN/NJ)/64)   // 16 j-tiles per chunk

#define LOG2E 1.4426950408889634f
#define QSCALE 0.18033688011112042f   // log2e / sqrt(64)

#define XT_ROWS 4097                  // row 0 = zero guard row
#define WQKV_OFF (27*80*64)           // offset of transposed QKV weights inside Wr

typedef __attribute__((ext_vector_type(8))) short short8;
typedef __attribute__((ext_vector_type(4))) float float4v;
typedef unsigned short ushortT;

__device__ __forceinline__ ushortT f2bf(float x) {
    union { float f; unsigned u; } v; v.f = x;
    unsigned r = v.u + 0x7FFF + ((v.u >> 16) & 1);   // RNE
    return (ushortT)(r >> 16);
}
__device__ __forceinline__ float bf2f(short s) {
    union { unsigned u; float f; } v;
    v.u = ((unsigned)(unsigned short)s) << 16;
    return v.f;
}
// pack 2 fp32 -> 1 VGPR holding 2 bf16: low16 = bf(a), high16 = bf(b)
__device__ __forceinline__ unsigned pk2(float a, float b) {
    unsigned ua = __float_as_uint(a) + 0x8000u;
    unsigned ub = __float_as_uint(b) + 0x8000u;
    return __builtin_amdgcn_perm(ub, ua, 0x07060302);
}

// ---------------- PE table value: global channel c (0..63), coord 0..15 ----------------
__device__ __forceinline__ float pe_tab_val(int c, int pos) {
    int c2 = (c < 22) ? c : (c < 44) ? (c - 22) : (c - 44);
    int is_cos = (c2 >= 11);
    int k = c2 - (is_cos ? 11 : 0);
    float freq = exp2f(-1.2079738526863135f * (float)k);
    float arg = (float)pos * freq;
    return is_cos ? cosf(arg) : sinf(arg);
}

// ---------------- Merged: x_pe + Xt transpose (blocks 0..255) | weight reorg (blocks 256..) ----------------
__global__ __launch_bounds__(256) void k_pre(const float* __restrict__ x,
                                             const float* __restrict__ qw,
                                             const float* __restrict__ kw,
                                             const float* __restrict__ vw,
                                             const float* __restrict__ Wq,
                                             const float* __restrict__ Wk,
                                             const float* __restrict__ Wv,
                                             float* __restrict__ xpe,
                                             ushortT* __restrict__ Xt,
                                             ushortT* __restrict__ Wr) {
    int blk = blockIdx.x, t = threadIdx.x;
    if (blk < 256) {
        __shared__ float sPE[64][17];
        __shared__ float sT[64][33];
        int b = blk >> 7, pos0 = (blk & 127) * 32;
        #pragma unroll
        for (int k = 0; k < 4; k++) {
            int e = t + k * 256;            // 0..1023
            int c = e >> 4, coord = e & 15;
            sPE[c][coord] = pe_tab_val(c, coord);
        }
        __syncthreads();
        int pin = t & 31, cg = t >> 5;
        #pragma unroll
        for (int pass = 0; pass < 8; pass++) {
            int c = pass * 8 + cg;
            int pos = pos0 + pin;
            int coord = (c < 22) ? (pos >> 8) : (c < 44) ? ((pos >> 4) & 15) : (pos & 15);
            size_t gi = (size_t)(b * 64 + c) * NN + pos;
            float v = x[gi] + sPE[c][coord];
            xpe[gi] = v;
            sT[c][pin] = v;
        }
        __syncthreads();
        int icn = t & 63, pg = t >> 6;
        #pragma unroll
        for (int pass = 0; pass < 8; pass++) {
            int po = pass * 4 + pg;
            Xt[((size_t)b * XT_ROWS + pos0 + po + 1) * 64 + icn] = f2bf(sT[icn][po]);
        }
        if ((blk & 127) == 0 && t < 64)
            Xt[((size_t)b * XT_ROWS) * 64 + t] = 0;   // zero guard row
    } else {
        int idx = (blk - 256) * 256 + t;
        if (idx < WQKV_OFF) {
            int ic = idx & 63;
            int oc = (idx >> 6) % 80;
            int tap = idx / 5120;
            float v;
            if (oc < 8)       v = qw[(oc * 64 + ic) * 27 + tap] * LOG2E;
            else if (oc < 16) v = kw[((oc - 8) * 64 + ic) * 27 + tap];
            else              v = vw[((oc - 16) * 64 + ic) * 27 + tap];
            Wr[idx] = f2bf(v);
        } else if (idx < WQKV_OFF + 3 * 64 * 64) {
            int idx2 = idx - WQKV_OFF;
            int c = idx2 & 63, d = (idx2 >> 6) & 63, mat = idx2 >> 12;
            const float* Wm = (mat == 0) ? Wq : (mat == 1) ? Wk : Wv;
            float v = Wm[c * 64 + d] * ((mat == 0) ? QSCALE : 1.f);
            Wr[idx] = f2bf(v);
        }
    }
}

// ---------------- Merged producers: QKV (y=0..2) + conv (y=3..7) ----------------
__global__ __launch_bounds__(256) void k_prod(const ushortT* __restrict__ Xt,
                                              const ushortT* __restrict__ Wr,
                                              const float* __restrict__ qb,
                                              const float* __restrict__ kb,
                                              const float* __restrict__ vb,
                                              ushortT* __restrict__ Qb,
                                              ushortT* __restrict__ Kb,
                                              ushortT* __restrict__ Vtb,
                                              ushortT* __restrict__ Mt,
                                              ushortT* __restrict__ Nt,
                                              ushortT* __restrict__ Wvt) {
    int t = threadIdx.x, w = t >> 6, l = t & 63;
    int lane15 = l & 15, q = l >> 4;
    int b = blockIdx.z, y = blockIdx.y;
    if (y < 3) {
        // ---- QKV via MFMA: wave = 16 rows x 64 cols, K=64 ----
        int mat = y;
        int i0 = blockIdx.x * 64 + w * 16;
        const ushortT* Wt = Wr + WQKV_OFF + mat * 4096;
        const ushortT* xrow = Xt + ((size_t)b * XT_ROWS + i0 + lane15 + 1) * 64;
        short8 a0 = *(const short8*)(xrow + q * 8);
        short8 a1 = *(const short8*)(xrow + 32 + q * 8);
        float4v acc[4];
        #pragma unroll
        for (int cg = 0; cg < 4; cg++) {
            const ushortT* wrow = Wt + (cg * 16 + lane15) * 64;
            short8 b0 = *(const short8*)(wrow + q * 8);
            short8 b1 = *(const short8*)(wrow + 32 + q * 8);
            float4v a = (float4v)0.f;
            a = __builtin_amdgcn_mfma_f32_16x16x32_bf16(a0, b0, a, 0, 0, 0);
            a = __builtin_amdgcn_mfma_f32_16x16x32_bf16(a1, b1, a, 0, 0, 0);
            acc[cg] = a;
        }
        if (mat < 2) {
            ushortT* o = (mat == 0) ? Qb : Kb;
            #pragma unroll
            for (int cg = 0; cg < 4; cg++)
                #pragma unroll
                for (int r = 0; r < 4; r++)
                    o[((size_t)(b * NN + i0 + q * 4 + r)) * 64 + cg * 16 + lane15] = f2bf(acc[cg][r]);
        } else {
            #pragma unroll
            for (int cg = 0; cg < 4; cg++)
                #pragma unroll
                for (int r = 0; r < 4; r++)
                    Vtb[((size_t)(b * 64 + cg * 16 + lane15)) * NN + i0 + q * 4 + r] = f2bf(acc[cg][r]);
        }
    } else {
        // ---- conv via per-tap MFMA implicit GEMM: wave = 16 pos x 16 oc ----
        int ocg = y - 3;
        int pos0 = blockIdx.x * 64 + w * 16;
        const ushortT* xb = Xt + (size_t)b * XT_ROWS * 64;
        int pos = pos0 + lane15;
        int dz = pos & 15, wy = (pos >> 4) & 15, hx = pos >> 8;
        float4v acc = (float4v)0.f;
        #pragma unroll
        for (int tap = 0; tap < 27; tap++) {
            const int dh = tap / 9 - 1, dw = (tap / 3) % 3 - 1, dd = tap % 3 - 1;
            const int shift = dh * 256 + dw * 16 + dd;
            const ushortT* wrow = Wr + ((size_t)tap * 80 + ocg * 16 + lane15) * 64 + q * 8;
            short8 a0 = *(const short8*)(wrow);
            short8 a1 = *(const short8*)(wrow + 32);
            bool ok = ((unsigned)(hx + dh) < 16u) &&
                      ((unsigned)(wy + dw) < 16u) &&
                      ((unsigned)(dz + dd) < 16u);
            int row = ok ? (pos + shift + 1) : 0;
            const ushortT* xrow = xb + (size_t)row * 64 + q * 8;
            short8 b0 = *(const short8*)xrow;
            short8 b1 = *(const short8*)(xrow + 32);
            acc = __builtin_amdgcn_mfma_f32_16x16x32_bf16(a0, b0, acc, 0, 0, 0);
            acc = __builtin_amdgcn_mfma_f32_16x16x32_bf16(a1, b1, acc, 0, 0, 0);
        }
        if (ocg == 0) {
            #pragma unroll
            for (int r = 0; r < 4; r++) {
                int ol = q * 4 + r;
                float v = acc[r];
                if (ol < 8)
                    Mt[((size_t)(b * NN + pos)) * 8 + ol] = f2bf(v + qb[ol] * LOG2E);
                else
                    Nt[((size_t)(b * NN + pos)) * 8 + (ol - 8)] = f2bf(v + kb[ol - 8]);
            }
        } else {
            #pragma unroll
            for (int r = 0; r < 4; r++) {
                int oc = (ocg - 1) * 16 + q * 4 + r;
                Wvt[((size_t)(b * 64 + oc)) * NN + pos] = f2bf(acc[r] + vb[oc]);
            }
        }
    }
}

// ---------------- LDS staging helpers for flash ----------------
// K tile: 64 rows x 64 ch bf16 (GSA: only ch group 0). XOR-swizzled 16B groups:
//   element row j, group g lives at ushort offset j*64 + ((g ^ (j&7))*8).
// V tile: rows c (0..63), 64 j: offset c*64 + ((gj ^ (c&7))*8).
template<int IS_TSA>
__device__ __forceinline__ void stage_load(short8* kst, short8* vst,
                                           const ushortT* __restrict__ Km,
                                           const ushortT* __restrict__ Vt,
                                           int b, int jb, int t) {
    if (IS_TSA) {
        #pragma unroll
        for (int ps = 0; ps < 2; ps++) {
            int idx = ps * 256 + t, j = idx >> 3, g = idx & 7;
            kst[ps] = *(const short8*)(Km + ((size_t)(b * NN + jb + j)) * 64 + g * 8);
        }
    } else {
        if (t < 64)
            kst[0] = *(const short8*)(Km + ((size_t)(b * NN + jb + t)) * 8);
    }
    #pragma unroll
    for (int ps = 0; ps < 2; ps++) {
        int idx = ps * 256 + t, c = idx >> 3, gj = idx & 7;
        vst[ps] = *(const short8*)(Vt + ((size_t)(b * 64 + c)) * NN + jb + gj * 8);
    }
}

template<int IS_TSA>
__device__ __forceinline__ void stage_write(const short8* kst, const short8* vst,
                                            ushortT* sK, ushortT* sV, int t) {
    if (IS_TSA) {
        #pragma unroll
        for (int ps = 0; ps < 2; ps++) {
            int idx = ps * 256 + t, j = idx >> 3, g = idx & 7;
            *(short8*)(sK + j * 64 + ((g ^ (j & 7)) * 8)) = kst[ps];
        }
    } else {
        if (t < 64)
            *(short8*)(sK + t * 64 + ((t & 7) * 8)) = kst[0];
    }
    #pragma unroll
    for (int ps = 0; ps < 2; ps++) {
        int idx = ps * 256 + t, c = idx >> 3, gj = idx & 7;
        *(short8*)(sV + c * 64 + ((gj ^ (c & 7)) * 8)) = vst[ps];
    }
}

// ---------------- MFMA flash body: LDS-staged K/V, online softmax (lazy rescale) ----------------
template<int IS_TSA>
__device__ __forceinline__ void flash_body(int it, int jc, int b, int t,
                                           const ushortT* __restrict__ Qm,
                                           const ushortT* __restrict__ Km,
                                           const ushortT* __restrict__ Vt,
                                           float* __restrict__ pM,
                                           float* __restrict__ pL,
                                           ushortT* __restrict__ pAcc,
                                           ushortT* __restrict__ sKb,
                                           ushortT* __restrict__ sVb,
                                           ushortT* __restrict__ sPall) {
    constexpr int KCH = IS_TSA ? 2 : 1;
    constexpr int DQ  = IS_TSA ? 64 : 8;
    int w = t >> 6, l = t & 63;
    int lane15 = l & 15, q = l >> 4;
    int i0 = it * 64 + w * 16;
    ushortT* myP = sPall + w * (16 * 64);

    // Q fragments (B-operand: lane n = query i = lane15, k = channel)
    short8 qf[KCH];
    {
        const ushortT* qrow = Qm + ((size_t)(b * NN + i0 + lane15)) * DQ;
        if (IS_TSA) {
            qf[0] = *(const short8*)(qrow + q * 8);
            qf[1] = *(const short8*)(qrow + 32 + q * 8);
        } else {
            short8 z = (short8)0;
            if (q == 0) z = *(const short8*)qrow;
            qf[0] = z;
        }
    }

    float m_run = -3e38f, Lacc = 0.f;
    float4v O[4];
    #pragma unroll
    for (int cs = 0; cs < 4; cs++) O[cs] = (float4v)0.f;

    const int jbase0 = jc * (NN / NJ);

    // preload + stage tile 0
    short8 kst[2], vst[2];
    stage_load<IS_TSA>(kst, vst, Km, Vt, b, jbase0, t);
    stage_write<IS_TSA>(kst, vst, sKb, sVb, t);
    __syncthreads();

    for (int jt = 0; jt < NT; jt++) {
        int cur = jt & 1;
        ushortT* cK = sKb + cur * 4096;
        ushortT* cV = sVb + cur * 4096;
        bool more = (jt + 1 < NT);

        // issue next tile's global loads (consumed at end of iteration)
        if (more) stage_load<IS_TSA>(kst, vst, Km, Vt, b, jbase0 + (jt + 1) * 64, t);

        // ---- K fragments from LDS (A-operand: m = j row) ----
        short8 kf[4][KCH];
        #pragma unroll
        for (int sub = 0; sub < 4; sub++) {
            int jr = sub * 16 + lane15;
            if (IS_TSA) {
                kf[sub][0] = *(const short8*)(cK + jr * 64 + (((0 * 4 + q) ^ (lane15 & 7)) * 8));
                kf[sub][1] = *(const short8*)(cK + jr * 64 + (((1 * 4 + q) ^ (lane15 & 7)) * 8));
            } else {
                short8 z = (short8)0;
                if (q == 0) z = *(const short8*)(cK + jr * 64 + ((lane15 & 7) * 8));
                kf[sub][0] = z;
            }
        }

        // ---- S^T = K Q^T: lane col i = lane15, rows j = sub*16 + q*4 + r ----
        float4v s[4];
        #pragma unroll
        for (int sub = 0; sub < 4; sub++) {
            float4v acc = (float4v)0.f;
            #pragma unroll
            for (int kc = 0; kc < KCH; kc++)
                acc = __builtin_amdgcn_mfma_f32_16x16x32_bf16(kf[sub][kc], qf[kc], acc, 0, 0, 0);
            s[sub] = acc;
        }

        // ---- V fragments from LDS (B-operand for PV: n = channel c, k = j) ----
        short8 va[4], vbf[4];
        #pragma unroll
        for (int sub = 0; sub < 4; sub++) {
            int cr = sub * 16 + lane15;
            va[sub]  = *(const short8*)(cV + cr * 64 + ((q ^ (lane15 & 7)) * 8));
            vbf[sub] = *(const short8*)(cV + cr * 64 + (((4 + q) ^ (lane15 & 7)) * 8));
        }

        // ---- online softmax: row max for query lane15 (2 shfls) ----
        float tmax = fmaxf(fmaxf(fmaxf(s[0][0], s[0][1]), fmaxf(s[0][2], s[0][3])),
                           fmaxf(fmaxf(s[1][0], s[1][1]), fmaxf(s[1][2], s[1][3])));
        float tmax2 = fmaxf(fmaxf(fmaxf(s[2][0], s[2][1]), fmaxf(s[2][2], s[2][3])),
                            fmaxf(fmaxf(s[3][0], s[3][1]), fmaxf(s[3][2], s[3][3])));
        tmax = fmaxf(tmax, tmax2);
        tmax = fmaxf(tmax, __shfl_xor(tmax, 16));
        tmax = fmaxf(tmax, __shfl_xor(tmax, 32));
        float mnew = fmaxf(m_run, tmax);

        // lazy rescale: only when some row's max actually increased
        if (__any(mnew > m_run)) {
            float corr = exp2f(m_run - mnew);
            Lacc *= corr;
            float c0 = __shfl(corr, q * 4 + 0);
            float c1 = __shfl(corr, q * 4 + 1);
            float c2 = __shfl(corr, q * 4 + 2);
            float c3 = __shfl(corr, q * 4 + 3);
            #pragma unroll
            for (int cs = 0; cs < 4; cs++) {
                O[cs][0] *= c0; O[cs][1] *= c1; O[cs][2] *= c2; O[cs][3] *= c3;
            }
        }
        m_run = mnew;

        // ---- P = exp2(s - m), L accum, P (bf16) -> per-wave LDS tile ----
        // store P[j][i] at ushort offset i*64 + ((j>>3)^(i&7))*8 + (j&7)
        #pragma unroll
        for (int sub = 0; sub < 4; sub++) {
            float p0 = exp2f(s[sub][0] - mnew);
            float p1 = exp2f(s[sub][1] - mnew);
            float p2 = exp2f(s[sub][2] - mnew);
            float p3 = exp2f(s[sub][3] - mnew);
            Lacc += (p0 + p1) + (p2 + p3);
            unsigned lo = pk2(p0, p1), hi = pk2(p2, p3);
            int g = sub * 2 + (q >> 1);
            unsigned* wp = (unsigned*)(myP + lane15 * 64 + ((g ^ (lane15 & 7)) * 8) + (q & 1) * 4);
            wp[0] = lo; wp[1] = hi;
        }

        // ---- A-frag for PV: lane m = i = lane15, k = j = (kc*32)+q*8+e ----
        short8 pf0 = *(const short8*)(myP + lane15 * 64 + (((0 * 4 + q) ^ (lane15 & 7)) * 8));
        short8 pf1 = *(const short8*)(myP + lane15 * 64 + (((1 * 4 + q) ^ (lane15 & 7)) * 8));

        // ---- O += P V ----
        #pragma unroll
        for (int sub = 0; sub < 4; sub++) {
            O[sub] = __builtin_amdgcn_mfma_f32_16x16x32_bf16(pf0, va[sub], O[sub], 0, 0, 0);
            O[sub] = __builtin_amdgcn_mfma_f32_16x16x32_bf16(pf1, vbf[sub], O[sub], 0, 0, 0);
        }

        // ---- write staged next tile into the other buffer ----
        if (more)
            stage_write<IS_TSA>(kst, vst, sKb + (cur ^ 1) * 4096, sVb + (cur ^ 1) * 4096, t);
        __syncthreads();
    }

    // ---- store partials ----
    size_t base = (size_t)(b * NJ + jc) * NN + i0;
    Lacc += __shfl_xor(Lacc, 16);
    Lacc += __shfl_xor(Lacc, 32);
    if (q == 0) {
        pL[base + lane15] = Lacc;
        pM[base + lane15] = m_run;
    }
    #pragma unroll
    for (int cs = 0; cs < 4; cs++)
        #pragma unroll
        for (int r = 0; r < 4; r++)
            pAcc[(base + q * 4 + r) * 64 + cs * 16 + lane15] = f2bf(O[cs][r]);
}

// ---------------- Merged flash kernel (TSA blocks 0..63, GSA blocks 64..127) ----------------
__global__ __launch_bounds__(256, 4) void k_flash(const ushortT* __restrict__ Qb,
                                                  const ushortT* __restrict__ Kb,
                                                  const ushortT* __restrict__ Vtb,
                                                  const ushortT* __restrict__ Mtb,
                                                  const ushortT* __restrict__ Ntb,
                                                  const ushortT* __restrict__ Wvtb,
                                                  float* __restrict__ pMt, float* __restrict__ pLt,
                                                  ushortT* __restrict__ pAccT,
                                                  float* __restrict__ pMg, float* __restrict__ pLg,
                                                  ushortT* __restrict__ pAccG) {
    __shared__ ushortT sK[2][64 * 64];   // 16 KB
    __shared__ ushortT sV[2][64 * 64];   // 16 KB
    __shared__ ushortT sP[4][16 * 64];   // 8 KB (per-wave P tiles)
    int t = threadIdx.x;
    int b = blockIdx.z, jc = blockIdx.y;
    if (blockIdx.x < 64)
        flash_body<1>(blockIdx.x, jc, b, t, Qb, Kb, Vtb, pMt, pLt, pAccT,
                      &sK[0][0], &sV[0][0], &sP[0][0]);
    else
        flash_body<0>(blockIdx.x - 64, jc, b, t, Mtb, Ntb, Wvtb, pMg, pLg, pAccG,
                      &sK[0][0], &sV[0][0], &sP[0][0]);
}

// ---------------- Reduce both partial sets (max-merge) + fused epilogue ----------------
__device__ __forceinline__ void reduce_set(const float* __restrict__ pM,
                                           const float* __restrict__ pL,
                                           const ushortT* __restrict__ pAcc,
                                           int b, int n, int seg, float* v) {
    float mv[NJ], M = -3e38f;
    #pragma unroll
    for (int jcc = 0; jcc < NJ; jcc++) {
        mv[jcc] = pM[(size_t)(b * NJ + jcc) * NN + n];
        M = fmaxf(M, mv[jcc]);
    }
    float L = 0.f;
    #pragma unroll
    for (int e = 0; e < 8; e++) v[e] = 0.f;
    #pragma unroll
    for (int jcc = 0; jcc < NJ; jcc++) {
        size_t rb = (size_t)(b * NJ + jcc) * NN + n;
        float wgt = exp2f(mv[jcc] - M);
        L += pL[rb] * wgt;
        short8 x0 = *(const short8*)(pAcc + rb * 64 + seg * 8);
        #pragma unroll
        for (int e = 0; e < 8; e++) v[e] += wgt * bf2f(x0[e]);
    }
    float invL = 1.f / L;
    #pragma unroll
    for (int e = 0; e < 8; e++) v[e] *= invL;
}

__global__ __launch_bounds__(256) void k_reduce(const float* __restrict__ pMt,
                                                const float* __restrict__ pLt,
                                                const ushortT* __restrict__ pAccT,
                                                const float* __restrict__ pMg,
                                                const float* __restrict__ pLg,
                                                const ushortT* __restrict__ pAccG,
                                                const float* __restrict__ xpe,
                                                const float* __restrict__ lam1,
                                                const float* __restrict__ lam2,
                                                float* __restrict__ out) {
    __shared__ float sT[32][65];
    __shared__ float sG[32][65];
    int t = threadIdx.x;
    int b = blockIdx.y;
    int n0 = blockIdx.x * 32;
    int pp = t >> 3, seg = t & 7;
    int n = n0 + pp;

    float vt[8], vg[8];
    reduce_set(pMt, pLt, pAccT, b, n, seg, vt);
    reduce_set(pMg, pLg, pAccG, b, n, seg, vg);
    #pragma unroll
    for (int e = 0; e < 8; e++) {
        sT[pp][seg * 8 + e] = vt[e];
        sG[pp][seg * 8 + e] = vg[e];
    }
    __syncthreads();

    int c = t >> 2, ns = (t & 3) * 8;
    float la1 = lam1[0], la2 = lam2[0];
    size_t ob = ((size_t)(b * 64 + c)) * NN + n0 + ns;
    const float* xp = xpe + ob;
    #pragma unroll
    for (int j = 0; j < 8; j += 4) {
        float4 ov;
        ov.x = la1 * sT[ns + j + 0][c] + la2 * sG[ns + j + 0][c] + xp[j + 0];
        ov.y = la1 * sT[ns + j + 1][c] + la2 * sG[ns + j + 1][c] + xp[j + 1];
        ov.z = la1 * sT[ns + j + 2][c] + la2 * sG[ns + j + 2][c] + xp[j + 2];
        ov.w = la1 * sT[ns + j + 3][c] + la2 * sG[ns + j + 3][c] + xp[j + 3];
        *(float4*)(out + ob + j) = ov;
    }
}

extern "C" void kernel_launch(void* const* d_in, const int* in_sizes, int n_in,
                              void* d_out, int out_size, void* d_ws, size_t ws_size,
                              hipStream_t stream) {
    const float* x    = (const float*)d_in[0];
    const float* Wq   = (const float*)d_in[1];
    const float* Wk   = (const float*)d_in[2];
    const float* Wv   = (const float*)d_in[3];
    const float* qw   = (const float*)d_in[4];
    const float* qb   = (const float*)d_in[5];
    const float* kw   = (const float*)d_in[6];
    const float* kb   = (const float*)d_in[7];
    const float* vw   = (const float*)d_in[8];
    const float* vb   = (const float*)d_in[9];
    const float* lam1 = (const float*)d_in[10];
    const float* lam2 = (const float*)d_in[11];
    float* out = (float*)d_out;

    char* W = (char*)d_ws;
    float*   xpe   = (float*)(W);                               // 2 MB
    ushortT* Qb    = (ushortT*)(W + (2u << 20));                // 1 MB
    ushortT* Kb    = (ushortT*)(W + (3u << 20));                // 1 MB
    ushortT* Vtb   = (ushortT*)(W + (4u << 20));                // 1 MB
    ushortT* Mtb   = (ushortT*)(W + (5u << 20));                // 128 KB
    ushortT* Ntb   = (ushortT*)(W + (5u << 20) + (1u << 17));   // 128 KB
    ushortT* Wvtb  = (ushortT*)(W + (5u << 20) + (2u << 17));   // 1 MB
    ushortT* Xt    = (ushortT*)(W + (6u << 20) + (2u << 17));   // ~1.0 MB
    ushortT* Wr    = (ushortT*)(W + (7u << 20) + (1u << 19));   // ~0.3 MB
    float*   pLt   = (float*)(W + (8u << 20));                  // 128 KB
    float*   pLg   = (float*)(W + (8u << 20) + (1u << 17));     // 128 KB
    float*   pMt   = (float*)(W + (8u << 20) + (2u << 17));     // 128 KB
    float*   pMg   = (float*)(W + (8u << 20) + (3u << 17));     // 128 KB
    ushortT* pAccT = (ushortT*)(W + (8u << 20) + (4u << 17));   // 4 MB
    ushortT* pAccG = (ushortT*)(W + (12u << 20) + (4u << 17));  // 4 MB (ends 16.5 MB)

    // 1. x_pe + Xt transpose + weight reorg (one launch)
    k_pre<<<dim3(256 + (WQKV_OFF + 3 * 64 * 64 + 255) / 256), dim3(256), 0, stream>>>(
        x, qw, kw, vw, Wq, Wk, Wv, xpe, Xt, Wr);
    // 2. QKV + conv producers (one launch)
    k_prod<<<dim3(64, 8, BB), dim3(256), 0, stream>>>(
        Xt, Wr, qb, kb, vb, Qb, Kb, Vtb, Mtb, Ntb, Wvtb);
    // 3. merged TSA+GSA flash (LDS-staged K/V, online softmax)
    k_flash<<<dim3(128, NJ, BB), dim3(256), 0, stream>>>(
        Qb, Kb, Vtb, Mtb, Ntb, Wvtb, pMt, pLt, pAccT, pMg, pLg, pAccG);
    // 4. merged reduce + epilogue
    k_reduce<<<dim3(NN / 32, BB), dim3(256), 0, stream>>>(
        pMt, pLt, pAccT, pMg, pLg, pAccG, xpe, lam1, lam2, out);
}

// Round 8
// 159.142 us; speedup vs baseline: 1.5545x; 1.0540x over previous
//
#include <hip/hip_runtime.h>
#include <math.h>

// Problem constants
#define BB 2
#define CC 64
#define NN 4096      // 16*16*16
#define CN (CC*NN)
#define NJ 4         // j-split chunks for flash partials
#define NT ((NN/NJ)/64)   // 16 j-tiles per chunk

#define LOG2E 1.4426950408889634f
#define QSCALE 0.18033688011112042f   // log2e / sqrt(64)

#define XT_ROWS 4097                  // row 0 = zero guard row
#define WQKV_OFF (27*80*64)           // offset of transposed QKV weights inside Wr

typedef __attribute__((ext_vector_type(8))) short short8;
typedef __attribute__((ext_vector_type(4))) float float4v;
typedef unsigned short ushortT;

__device__ __forceinline__ ushortT f2bf(float x) {
    union { float f; unsigned u; } v; v.f = x;
    unsigned r = v.u + 0x7FFF + ((v.u >> 16) & 1);   // RNE
    return (ushortT)(r >> 16);
}
__device__ __forceinline__ float bf2f(short s) {
    union { unsigned u; float f; } v;
    v.u = ((unsigned)(unsigned short)s) << 16;
    return v.f;
}
// pack 2 fp32 -> 1 VGPR holding 2 bf16: low16 = bf(a), high16 = bf(b)
__device__ __forceinline__ unsigned pk2(float a, float b) {
    unsigned ua = __float_as_uint(a) + 0x8000u;
    unsigned ub = __float_as_uint(b) + 0x8000u;
    return __builtin_amdgcn_perm(ub, ua, 0x07060302);
}

// ---------------- PE table value: global channel c (0..63), coord 0..15 ----------------
__device__ __forceinline__ float pe_tab_val(int c, int pos) {
    int c2 = (c < 22) ? c : (c < 44) ? (c - 22) : (c - 44);
    int is_cos = (c2 >= 11);
    int k = c2 - (is_cos ? 11 : 0);
    float freq = exp2f(-1.2079738526863135f * (float)k);
    float arg = (float)pos * freq;
    return is_cos ? cosf(arg) : sinf(arg);
}

// ---------------- Merged: x_pe + Xt transpose (blocks 0..255) | weight reorg (blocks 256..) ----------------
__global__ __launch_bounds__(256) void k_pre(const float* __restrict__ x,
                                             const float* __restrict__ qw,
                                             const float* __restrict__ kw,
                                             const float* __restrict__ vw,
                                             const float* __restrict__ Wq,
                                             const float* __restrict__ Wk,
                                             const float* __restrict__ Wv,
                                             float* __restrict__ xpe,
                                             ushortT* __restrict__ Xt,
                                             ushortT* __restrict__ Wr) {
    int blk = blockIdx.x, t = threadIdx.x;
    if (blk < 256) {
        __shared__ float sPE[64][17];
        __shared__ float sT[64][33];
        int b = blk >> 7, pos0 = (blk & 127) * 32;
        #pragma unroll
        for (int k = 0; k < 4; k++) {
            int e = t + k * 256;            // 0..1023
            int c = e >> 4, coord = e & 15;
            sPE[c][coord] = pe_tab_val(c, coord);
        }
        __syncthreads();
        int pin = t & 31, cg = t >> 5;
        #pragma unroll
        for (int pass = 0; pass < 8; pass++) {
            int c = pass * 8 + cg;
            int pos = pos0 + pin;
            int coord = (c < 22) ? (pos >> 8) : (c < 44) ? ((pos >> 4) & 15) : (pos & 15);
            size_t gi = (size_t)(b * 64 + c) * NN + pos;
            float v = x[gi] + sPE[c][coord];
            xpe[gi] = v;
            sT[c][pin] = v;
        }
        __syncthreads();
        int icn = t & 63, pg = t >> 6;
        #pragma unroll
        for (int pass = 0; pass < 8; pass++) {
            int po = pass * 4 + pg;
            Xt[((size_t)b * XT_ROWS + pos0 + po + 1) * 64 + icn] = f2bf(sT[icn][po]);
        }
        if ((blk & 127) == 0 && t < 64)
            Xt[((size_t)b * XT_ROWS) * 64 + t] = 0;   // zero guard row
    } else {
        int idx = (blk - 256) * 256 + t;
        if (idx < WQKV_OFF) {
            int ic = idx & 63;
            int oc = (idx >> 6) % 80;
            int tap = idx / 5120;
            float v;
            if (oc < 8)       v = qw[(oc * 64 + ic) * 27 + tap] * LOG2E;
            else if (oc < 16) v = kw[((oc - 8) * 64 + ic) * 27 + tap];
            else              v = vw[((oc - 16) * 64 + ic) * 27 + tap];
            Wr[idx] = f2bf(v);
        } else if (idx < WQKV_OFF + 3 * 64 * 64) {
            int idx2 = idx - WQKV_OFF;
            int c = idx2 & 63, d = (idx2 >> 6) & 63, mat = idx2 >> 12;
            const float* Wm = (mat == 0) ? Wq : (mat == 1) ? Wk : Wv;
            float v = Wm[c * 64 + d] * ((mat == 0) ? QSCALE : 1.f);
            Wr[idx] = f2bf(v);
        }
    }
}

// ---------------- Merged producers: QKV (y=0..2) + conv (y=3..7) ----------------
__global__ __launch_bounds__(256) void k_prod(const ushortT* __restrict__ Xt,
                                              const ushortT* __restrict__ Wr,
                                              const float* __restrict__ qb,
                                              const float* __restrict__ kb,
                                              const float* __restrict__ vb,
                                              ushortT* __restrict__ Qb,
                                              ushortT* __restrict__ Kb,
                                              ushortT* __restrict__ Vtb,
                                              ushortT* __restrict__ Mt,
                                              ushortT* __restrict__ Nt,
                                              ushortT* __restrict__ Wvt) {
    int t = threadIdx.x, w = t >> 6, l = t & 63;
    int lane15 = l & 15, q = l >> 4;
    int b = blockIdx.z, y = blockIdx.y;
    if (y < 3) {
        // ---- QKV via MFMA: wave = 16 rows x 64 cols, K=64 ----
        int mat = y;
        int i0 = blockIdx.x * 64 + w * 16;
        const ushortT* Wt = Wr + WQKV_OFF + mat * 4096;
        const ushortT* xrow = Xt + ((size_t)b * XT_ROWS + i0 + lane15 + 1) * 64;
        short8 a0 = *(const short8*)(xrow + q * 8);
        short8 a1 = *(const short8*)(xrow + 32 + q * 8);
        float4v acc[4];
        #pragma unroll
        for (int cg = 0; cg < 4; cg++) {
            const ushortT* wrow = Wt + (cg * 16 + lane15) * 64;
            short8 b0 = *(const short8*)(wrow + q * 8);
            short8 b1 = *(const short8*)(wrow + 32 + q * 8);
            float4v a = (float4v)0.f;
            a = __builtin_amdgcn_mfma_f32_16x16x32_bf16(a0, b0, a, 0, 0, 0);
            a = __builtin_amdgcn_mfma_f32_16x16x32_bf16(a1, b1, a, 0, 0, 0);
            acc[cg] = a;
        }
        if (mat < 2) {
            ushortT* o = (mat == 0) ? Qb : Kb;
            #pragma unroll
            for (int cg = 0; cg < 4; cg++)
                #pragma unroll
                for (int r = 0; r < 4; r++)
                    o[((size_t)(b * NN + i0 + q * 4 + r)) * 64 + cg * 16 + lane15] = f2bf(acc[cg][r]);
        } else {
            #pragma unroll
            for (int cg = 0; cg < 4; cg++)
                #pragma unroll
                for (int r = 0; r < 4; r++)
                    Vtb[((size_t)(b * 64 + cg * 16 + lane15)) * NN + i0 + q * 4 + r] = f2bf(acc[cg][r]);
        }
    } else {
        // ---- conv via per-tap MFMA implicit GEMM: wave = 16 pos x 16 oc ----
        // 4-way K-split accumulators + explicit depth-4 load pipeline (r8 latency fix)
        int ocg = y - 3;
        int pos0 = blockIdx.x * 64 + w * 16;
        const ushortT* xb = Xt + (size_t)b * XT_ROWS * 64;
        int pos = pos0 + lane15;
        int dz = pos & 15, wy = (pos >> 4) & 15, hx = pos >> 8;

        float4v acc[4];
        #pragma unroll
        for (int a = 0; a < 4; a++) acc[a] = (float4v)0.f;

        constexpr int PD = 4;
        short8 pa0[PD], pa1[PD], pb0[PD], pb1[PD];

        auto ldtap = [&](int tap, int s) {
            const int dh = tap / 9 - 1, dw = (tap / 3) % 3 - 1, dd = tap % 3 - 1;
            const int shift = dh * 256 + dw * 16 + dd;
            const ushortT* wrow = Wr + ((size_t)tap * 80 + ocg * 16 + lane15) * 64 + q * 8;
            pa0[s] = *(const short8*)(wrow);
            pa1[s] = *(const short8*)(wrow + 32);
            bool ok = ((unsigned)(hx + dh) < 16u) &&
                      ((unsigned)(wy + dw) < 16u) &&
                      ((unsigned)(dz + dd) < 16u);
            int row = ok ? (pos + shift + 1) : 0;
            const ushortT* xrow = xb + (size_t)row * 64 + q * 8;
            pb0[s] = *(const short8*)xrow;
            pb1[s] = *(const short8*)(xrow + 32);
        };

        #pragma unroll
        for (int s = 0; s < PD; s++) ldtap(s, s);
        #pragma unroll
        for (int tap = 0; tap < 27; tap++) {
            int s = tap % PD;
            short8 A0 = pa0[s], A1 = pa1[s], B0 = pb0[s], B1 = pb1[s];
            if (tap + PD < 27) ldtap(tap + PD, s);
            acc[(2 * tap) & 3]     = __builtin_amdgcn_mfma_f32_16x16x32_bf16(A0, B0, acc[(2 * tap) & 3], 0, 0, 0);
            acc[(2 * tap + 1) & 3] = __builtin_amdgcn_mfma_f32_16x16x32_bf16(A1, B1, acc[(2 * tap + 1) & 3], 0, 0, 0);
        }
        float4v accT = (acc[0] + acc[1]) + (acc[2] + acc[3]);

        if (ocg == 0) {
            #pragma unroll
            for (int r = 0; r < 4; r++) {
                int ol = q * 4 + r;
                float v = accT[r];
                if (ol < 8)
                    Mt[((size_t)(b * NN + pos)) * 8 + ol] = f2bf(v + qb[ol] * LOG2E);
                else
                    Nt[((size_t)(b * NN + pos)) * 8 + (ol - 8)] = f2bf(v + kb[ol - 8]);
            }
        } else {
            #pragma unroll
            for (int r = 0; r < 4; r++) {
                int oc = (ocg - 1) * 16 + q * 4 + r;
                Wvt[((size_t)(b * 64 + oc)) * NN + pos] = f2bf(accT[r] + vb[oc]);
            }
        }
    }
}

// ---------------- LDS staging helpers for flash ----------------
template<int IS_TSA>
__device__ __forceinline__ void stage_load(short8* kst, short8* vst,
                                           const ushortT* __restrict__ Km,
                                           const ushortT* __restrict__ Vt,
                                           int b, int jb, int t) {
    if (IS_TSA) {
        #pragma unroll
        for (int ps = 0; ps < 2; ps++) {
            int idx = ps * 256 + t, j = idx >> 3, g = idx & 7;
            kst[ps] = *(const short8*)(Km + ((size_t)(b * NN + jb + j)) * 64 + g * 8);
        }
    } else {
        if (t < 64)
            kst[0] = *(const short8*)(Km + ((size_t)(b * NN + jb + t)) * 8);
    }
    #pragma unroll
    for (int ps = 0; ps < 2; ps++) {
        int idx = ps * 256 + t, c = idx >> 3, gj = idx & 7;
        vst[ps] = *(const short8*)(Vt + ((size_t)(b * 64 + c)) * NN + jb + gj * 8);
    }
}

template<int IS_TSA>
__device__ __forceinline__ void stage_write(const short8* kst, const short8* vst,
                                            ushortT* sK, ushortT* sV, int t) {
    if (IS_TSA) {
        #pragma unroll
        for (int ps = 0; ps < 2; ps++) {
            int idx = ps * 256 + t, j = idx >> 3, g = idx & 7;
            *(short8*)(sK + j * 64 + ((g ^ (j & 7)) * 8)) = kst[ps];
        }
    } else {
        if (t < 64)
            *(short8*)(sK + t * 64 + ((t & 7) * 8)) = kst[0];
    }
    #pragma unroll
    for (int ps = 0; ps < 2; ps++) {
        int idx = ps * 256 + t, c = idx >> 3, gj = idx & 7;
        *(short8*)(sV + c * 64 + ((gj ^ (c & 7)) * 8)) = vst[ps];
    }
}

// ---------------- MFMA flash body: LDS-staged K/V, online softmax (lazy rescale) ----------------
template<int IS_TSA>
__device__ __forceinline__ void flash_body(int it, int jc, int b, int t,
                                           const ushortT* __restrict__ Qm,
                                           const ushortT* __restrict__ Km,
                                           const ushortT* __restrict__ Vt,
                                           float* __restrict__ pM,
                                           float* __restrict__ pL,
                                           ushortT* __restrict__ pAcc,
                                           ushortT* __restrict__ sKb,
                                           ushortT* __restrict__ sVb,
                                           ushortT* __restrict__ sPall) {
    constexpr int KCH = IS_TSA ? 2 : 1;
    constexpr int DQ  = IS_TSA ? 64 : 8;
    int w = t >> 6, l = t & 63;
    int lane15 = l & 15, q = l >> 4;
    int i0 = it * 64 + w * 16;
    ushortT* myP = sPall + w * (16 * 64);

    short8 qf[KCH];
    {
        const ushortT* qrow = Qm + ((size_t)(b * NN + i0 + lane15)) * DQ;
        if (IS_TSA) {
            qf[0] = *(const short8*)(qrow + q * 8);
            qf[1] = *(const short8*)(qrow + 32 + q * 8);
        } else {
            short8 z = (short8)0;
            if (q == 0) z = *(const short8*)qrow;
            qf[0] = z;
        }
    }

    float m_run = -3e38f, Lacc = 0.f;
    float4v O[4];
    #pragma unroll
    for (int cs = 0; cs < 4; cs++) O[cs] = (float4v)0.f;

    const int jbase0 = jc * (NN / NJ);

    short8 kst[2], vst[2];
    stage_load<IS_TSA>(kst, vst, Km, Vt, b, jbase0, t);
    stage_write<IS_TSA>(kst, vst, sKb, sVb, t);
    __syncthreads();

    for (int jt = 0; jt < NT; jt++) {
        int cur = jt & 1;
        ushortT* cK = sKb + cur * 4096;
        ushortT* cV = sVb + cur * 4096;
        bool more = (jt + 1 < NT);

        if (more) stage_load<IS_TSA>(kst, vst, Km, Vt, b, jbase0 + (jt + 1) * 64, t);

        short8 kf[4][KCH];
        #pragma unroll
        for (int sub = 0; sub < 4; sub++) {
            int jr = sub * 16 + lane15;
            if (IS_TSA) {
                kf[sub][0] = *(const short8*)(cK + jr * 64 + (((0 * 4 + q) ^ (lane15 & 7)) * 8));
                kf[sub][1] = *(const short8*)(cK + jr * 64 + (((1 * 4 + q) ^ (lane15 & 7)) * 8));
            } else {
                short8 z = (short8)0;
                if (q == 0) z = *(const short8*)(cK + jr * 64 + ((lane15 & 7) * 8));
                kf[sub][0] = z;
            }
        }

        float4v s[4];
        #pragma unroll
        for (int sub = 0; sub < 4; sub++) {
            float4v acc = (float4v)0.f;
            #pragma unroll
            for (int kc = 0; kc < KCH; kc++)
                acc = __builtin_amdgcn_mfma_f32_16x16x32_bf16(kf[sub][kc], qf[kc], acc, 0, 0, 0);
            s[sub] = acc;
        }

        short8 va[4], vbf[4];
        #pragma unroll
        for (int sub = 0; sub < 4; sub++) {
            int cr = sub * 16 + lane15;
            va[sub]  = *(const short8*)(cV + cr * 64 + ((q ^ (lane15 & 7)) * 8));
            vbf[sub] = *(const short8*)(cV + cr * 64 + (((4 + q) ^ (lane15 & 7)) * 8));
        }

        float tmax = fmaxf(fmaxf(fmaxf(s[0][0], s[0][1]), fmaxf(s[0][2], s[0][3])),
                           fmaxf(fmaxf(s[1][0], s[1][1]), fmaxf(s[1][2], s[1][3])));
        float tmax2 = fmaxf(fmaxf(fmaxf(s[2][0], s[2][1]), fmaxf(s[2][2], s[2][3])),
                            fmaxf(fmaxf(s[3][0], s[3][1]), fmaxf(s[3][2], s[3][3])));
        tmax = fmaxf(tmax, tmax2);
        tmax = fmaxf(tmax, __shfl_xor(tmax, 16));
        tmax = fmaxf(tmax, __shfl_xor(tmax, 32));
        float mnew = fmaxf(m_run, tmax);

        if (__any(mnew > m_run)) {
            float corr = exp2f(m_run - mnew);
            Lacc *= corr;
            float c0 = __shfl(corr, q * 4 + 0);
            float c1 = __shfl(corr, q * 4 + 1);
            float c2 = __shfl(corr, q * 4 + 2);
            float c3 = __shfl(corr, q * 4 + 3);
            #pragma unroll
            for (int cs = 0; cs < 4; cs++) {
                O[cs][0] *= c0; O[cs][1] *= c1; O[cs][2] *= c2; O[cs][3] *= c3;
            }
        }
        m_run = mnew;

        #pragma unroll
        for (int sub = 0; sub < 4; sub++) {
            float p0 = exp2f(s[sub][0] - mnew);
            float p1 = exp2f(s[sub][1] - mnew);
            float p2 = exp2f(s[sub][2] - mnew);
            float p3 = exp2f(s[sub][3] - mnew);
            Lacc += (p0 + p1) + (p2 + p3);
            unsigned lo = pk2(p0, p1), hi = pk2(p2, p3);
            int g = sub * 2 + (q >> 1);
            unsigned* wp = (unsigned*)(myP + lane15 * 64 + ((g ^ (lane15 & 7)) * 8) + (q & 1) * 4);
            wp[0] = lo; wp[1] = hi;
        }

        short8 pf0 = *(const short8*)(myP + lane15 * 64 + (((0 * 4 + q) ^ (lane15 & 7)) * 8));
        short8 pf1 = *(const short8*)(myP + lane15 * 64 + (((1 * 4 + q) ^ (lane15 & 7)) * 8));

        #pragma unroll
        for (int sub = 0; sub < 4; sub++) {
            O[sub] = __builtin_amdgcn_mfma_f32_16x16x32_bf16(pf0, va[sub], O[sub], 0, 0, 0);
            O[sub] = __builtin_amdgcn_mfma_f32_16x16x32_bf16(pf1, vbf[sub], O[sub], 0, 0, 0);
        }

        if (more)
            stage_write<IS_TSA>(kst, vst, sKb + (cur ^ 1) * 4096, sVb + (cur ^ 1) * 4096, t);
        __syncthreads();
    }

    size_t base = (size_t)(b * NJ + jc) * NN + i0;
    Lacc += __shfl_xor(Lacc, 16);
    Lacc += __shfl_xor(Lacc, 32);
    if (q == 0) {
        pL[base + lane15] = Lacc;
        pM[base + lane15] = m_run;
    }
    #pragma unroll
    for (int cs = 0; cs < 4; cs++)
        #pragma unroll
        for (int r = 0; r < 4; r++)
            pAcc[(base + q * 4 + r) * 64 + cs * 16 + lane15] = f2bf(O[cs][r]);
}

// ---------------- Merged flash kernel (TSA blocks 0..63, GSA blocks 64..127) ----------------
__global__ __launch_bounds__(256, 4) void k_flash(const ushortT* __restrict__ Qb,
                                                  const ushortT* __restrict__ Kb,
                                                  const ushortT* __restrict__ Vtb,
                                                  const ushortT* __restrict__ Mtb,
                                                  const ushortT* __restrict__ Ntb,
                                                  const ushortT* __restrict__ Wvtb,
                                                  float* __restrict__ pMt, float* __restrict__ pLt,
                                                  ushortT* __restrict__ pAccT,
                                                  float* __restrict__ pMg, float* __restrict__ pLg,
                                                  ushortT* __restrict__ pAccG) {
    __shared__ ushortT sK[2][64 * 64];   // 16 KB
    __shared__ ushortT sV[2][64 * 64];   // 16 KB
    __shared__ ushortT sP[4][16 * 64];   // 8 KB (per-wave P tiles)
    int t = threadIdx.x;
    int b = blockIdx.z, jc = blockIdx.y;
    if (blockIdx.x < 64)
        flash_body<1>(blockIdx.x, jc, b, t, Qb, Kb, Vtb, pMt, pLt, pAccT,
                      &sK[0][0], &sV[0][0], &sP[0][0]);
    else
        flash_body<0>(blockIdx.x - 64, jc, b, t, Mtb, Ntb, Wvtb, pMg, pLg, pAccG,
                      &sK[0][0], &sV[0][0], &sP[0][0]);
}

// ---------------- Reduce both partial sets (max-merge) + fused epilogue ----------------
__device__ __forceinline__ void reduce_set(const float* __restrict__ pM,
                                           const float* __restrict__ pL,
                                           const ushortT* __restrict__ pAcc,
                                           int b, int n, int seg, float* v) {
    float mv[NJ], M = -3e38f;
    #pragma unroll
    for (int jcc = 0; jcc < NJ; jcc++) {
        mv[jcc] = pM[(size_t)(b * NJ + jcc) * NN + n];
        M = fmaxf(M, mv[jcc]);
    }
    float L = 0.f;
    #pragma unroll
    for (int e = 0; e < 8; e++) v[e] = 0.f;
    #pragma unroll
    for (int jcc = 0; jcc < NJ; jcc++) {
        size_t rb = (size_t)(b * NJ + jcc) * NN + n;
        float wgt = exp2f(mv[jcc] - M);
        L += pL[rb] * wgt;
        short8 x0 = *(const short8*)(pAcc + rb * 64 + seg * 8);
        #pragma unroll
        for (int e = 0; e < 8; e++) v[e] += wgt * bf2f(x0[e]);
    }
    float invL = 1.f / L;
    #pragma unroll
    for (int e = 0; e < 8; e++) v[e] *= invL;
}

__global__ __launch_bounds__(256) void k_reduce(const float* __restrict__ pMt,
                                                const float* __restrict__ pLt,
                                                const ushortT* __restrict__ pAccT,
                                                const float* __restrict__ pMg,
                                                const float* __restrict__ pLg,
                                                const ushortT* __restrict__ pAccG,
                                                const float* __restrict__ xpe,
                                                const float* __restrict__ lam1,
                                                const float* __restrict__ lam2,
                                                float* __restrict__ out) {
    __shared__ float sT[32][65];
    __shared__ float sG[32][65];
    int t = threadIdx.x;
    int b = blockIdx.y;
    int n0 = blockIdx.x * 32;
    int pp = t >> 3, seg = t & 7;
    int n = n0 + pp;

    float vt[8], vg[8];
    reduce_set(pMt, pLt, pAccT, b, n, seg, vt);
    reduce_set(pMg, pLg, pAccG, b, n, seg, vg);
    #pragma unroll
    for (int e = 0; e < 8; e++) {
        sT[pp][seg * 8 + e] = vt[e];
        sG[pp][seg * 8 + e] = vg[e];
    }
    __syncthreads();

    int c = t >> 2, ns = (t & 3) * 8;
    float la1 = lam1[0], la2 = lam2[0];
    size_t ob = ((size_t)(b * 64 + c)) * NN + n0 + ns;
    const float* xp = xpe + ob;
    #pragma unroll
    for (int j = 0; j < 8; j += 4) {
        float4 ov;
        ov.x = la1 * sT[ns + j + 0][c] + la2 * sG[ns + j + 0][c] + xp[j + 0];
        ov.y = la1 * sT[ns + j + 1][c] + la2 * sG[ns + j + 1][c] + xp[j + 1];
        ov.z = la1 * sT[ns + j + 2][c] + la2 * sG[ns + j + 2][c] + xp[j + 2];
        ov.w = la1 * sT[ns + j + 3][c] + la2 * sG[ns + j + 3][c] + xp[j + 3];
        *(float4*)(out + ob + j) = ov;
    }
}

extern "C" void kernel_launch(void* const* d_in, const int* in_sizes, int n_in,
                              void* d_out, int out_size, void* d_ws, size_t ws_size,
                              hipStream_t stream) {
    const float* x    = (const float*)d_in[0];
    const float* Wq   = (const float*)d_in[1];
    const float* Wk   = (const float*)d_in[2];
    const float* Wv   = (const float*)d_in[3];
    const float* qw   = (const float*)d_in[4];
    const float* qb   = (const float*)d_in[5];
    const float* kw   = (const float*)d_in[6];
    const float* kb   = (const float*)d_in[7];
    const float* vw   = (const float*)d_in[8];
    const float* vb   = (const float*)d_in[9];
    const float* lam1 = (const float*)d_in[10];
    const float* lam2 = (const float*)d_in[11];
    float* out = (float*)d_out;

    char* W = (char*)d_ws;
    float*   xpe   = (float*)(W);                               // 2 MB
    ushortT* Qb    = (ushortT*)(W + (2u << 20));                // 1 MB
    ushortT* Kb    = (ushortT*)(W + (3u << 20));                // 1 MB
    ushortT* Vtb   = (ushortT*)(W + (4u << 20));                // 1 MB
    ushortT* Mtb   = (ushortT*)(W + (5u << 20));                // 128 KB
    ushortT* Ntb   = (ushortT*)(W + (5u << 20) + (1u << 17));   // 128 KB
    ushortT* Wvtb  = (ushortT*)(W + (5u << 20) + (2u << 17));   // 1 MB
    ushortT* Xt    = (ushortT*)(W + (6u << 20) + (2u << 17));   // ~1.0 MB
    ushortT* Wr    = (ushortT*)(W + (7u << 20) + (1u << 19));   // ~0.3 MB
    float*   pLt   = (float*)(W + (8u << 20));                  // 128 KB
    float*   pLg   = (float*)(W + (8u << 20) + (1u << 17));     // 128 KB
    float*   pMt   = (float*)(W + (8u << 20) + (2u << 17));     // 128 KB
    float*   pMg   = (float*)(W + (8u << 20) + (3u << 17));     // 128 KB
    ushortT* pAccT = (ushortT*)(W + (8u << 20) + (4u << 17));   // 4 MB
    ushortT* pAccG = (ushortT*)(W + (12u << 20) + (4u << 17));  // 4 MB (ends 16.5 MB)

    // 1. x_pe + Xt transpose + weight reorg (one launch)
    k_pre<<<dim3(256 + (WQKV_OFF + 3 * 64 * 64 + 255) / 256), dim3(256), 0, stream>>>(
        x, qw, kw, vw, Wq, Wk, Wv, xpe, Xt, Wr);
    // 2. QKV + conv producers (one launch)
    k_prod<<<dim3(64, 8, BB), dim3(256), 0, stream>>>(
        Xt, Wr, qb, kb, vb, Qb, Kb, Vtb, Mtb, Ntb, Wvtb);
    // 3. merged TSA+GSA flash (LDS-staged K/V, online softmax)
    k_flash<<<dim3(128, NJ, BB), dim3(256), 0, stream>>>(
        Qb, Kb, Vtb, Mtb, Ntb, Wvtb, pMt, pLt, pAccT, pMg, pLg, pAccG);
    // 4. merged reduce + epilogue
    k_reduce<<<dim3(NN / 32, BB), dim3(256), 0, stream>>>(
        pMt, pLt, pAccT, pMg, pLg, pAccG, xpe, lam1, lam2, out);
}

// Round 9
// 153.192 us; speedup vs baseline: 1.6148x; 1.0388x over previous
//
#include <hip/hip_runtime.h>
#include <math.h>

// Problem constants
#define BB 2
#define CC 64
#define NN 4096      // 16*16*16
#define CN (CC*NN)
#define NJ 4         // j-split chunks for flash partials
#define NT ((NN/NJ)/64)   // 16 j-tiles per chunk

#define LOG2E 1.4426950408889634f
#define QSCALE 0.18033688011112042f   // log2e / sqrt(64)

#define XT_ROWS 4097                  // row 0 = zero guard row
#define WQKV_OFF (27*80*64)           // offset of transposed QKV weights inside Wr

typedef __attribute__((ext_vector_type(8))) short short8;
typedef __attribute__((ext_vector_type(4))) float float4v;
typedef unsigned short ushortT;

__device__ __forceinline__ ushortT f2bf(float x) {
    union { float f; unsigned u; } v; v.f = x;
    unsigned r = v.u + 0x7FFF + ((v.u >> 16) & 1);   // RNE
    return (ushortT)(r >> 16);
}
__device__ __forceinline__ float bf2f(short s) {
    union { unsigned u; float f; } v;
    v.u = ((unsigned)(unsigned short)s) << 16;
    return v.f;
}
// pack 2 fp32 -> 1 VGPR holding 2 bf16: low16 = bf(a), high16 = bf(b)
__device__ __forceinline__ unsigned pk2(float a, float b) {
    unsigned ua = __float_as_uint(a) + 0x8000u;
    unsigned ub = __float_as_uint(b) + 0x8000u;
    return __builtin_amdgcn_perm(ub, ua, 0x07060302);
}

// ---------------- PE table value: global channel c (0..63), coord 0..15 ----------------
__device__ __forceinline__ float pe_tab_val(int c, int pos) {
    int c2 = (c < 22) ? c : (c < 44) ? (c - 22) : (c - 44);
    int is_cos = (c2 >= 11);
    int k = c2 - (is_cos ? 11 : 0);
    float freq = exp2f(-1.2079738526863135f * (float)k);
    float arg = (float)pos * freq;
    return is_cos ? cosf(arg) : sinf(arg);
}

// ---------------- Merged: x_pe + Xt transpose (blocks 0..255) | weight reorg (blocks 256..) ----------------
__global__ __launch_bounds__(256) void k_pre(const float* __restrict__ x,
                                             const float* __restrict__ qw,
                                             const float* __restrict__ kw,
                                             const float* __restrict__ vw,
                                             const float* __restrict__ Wq,
                                             const float* __restrict__ Wk,
                                             const float* __restrict__ Wv,
                                             float* __restrict__ xpe,
                                             ushortT* __restrict__ Xt,
                                             ushortT* __restrict__ Wr) {
    int blk = blockIdx.x, t = threadIdx.x;
    if (blk < 256) {
        __shared__ float sPE[64][17];
        __shared__ float sT[64][33];
        int b = blk >> 7, pos0 = (blk & 127) * 32;
        #pragma unroll
        for (int k = 0; k < 4; k++) {
            int e = t + k * 256;            // 0..1023
            int c = e >> 4, coord = e & 15;
            sPE[c][coord] = pe_tab_val(c, coord);
        }
        __syncthreads();
        int pin = t & 31, cg = t >> 5;
        #pragma unroll
        for (int pass = 0; pass < 8; pass++) {
            int c = pass * 8 + cg;
            int pos = pos0 + pin;
            int coord = (c < 22) ? (pos >> 8) : (c < 44) ? ((pos >> 4) & 15) : (pos & 15);
            size_t gi = (size_t)(b * 64 + c) * NN + pos;
            float v = x[gi] + sPE[c][coord];
            xpe[gi] = v;
            sT[c][pin] = v;
        }
        __syncthreads();
        int icn = t & 63, pg = t >> 6;
        #pragma unroll
        for (int pass = 0; pass < 8; pass++) {
            int po = pass * 4 + pg;
            Xt[((size_t)b * XT_ROWS + pos0 + po + 1) * 64 + icn] = f2bf(sT[icn][po]);
        }
        if ((blk & 127) == 0 && t < 64)
            Xt[((size_t)b * XT_ROWS) * 64 + t] = 0;   // zero guard row
    } else {
        int idx = (blk - 256) * 256 + t;
        if (idx < WQKV_OFF) {
            int ic = idx & 63;
            int oc = (idx >> 6) % 80;
            int tap = idx / 5120;
            float v;
            if (oc < 8)       v = qw[(oc * 64 + ic) * 27 + tap] * LOG2E;
            else if (oc < 16) v = kw[((oc - 8) * 64 + ic) * 27 + tap];
            else              v = vw[((oc - 16) * 64 + ic) * 27 + tap];
            Wr[idx] = f2bf(v);
        } else if (idx < WQKV_OFF + 3 * 64 * 64) {
            int idx2 = idx - WQKV_OFF;
            int c = idx2 & 63, d = (idx2 >> 6) & 63, mat = idx2 >> 12;
            const float* Wm = (mat == 0) ? Wq : (mat == 1) ? Wk : Wv;
            float v = Wm[c * 64 + d] * ((mat == 0) ? QSCALE : 1.f);
            Wr[idx] = f2bf(v);
        }
    }
}

// ---------------- QKV via MFMA (separate kernel); V transposed via LDS (coalesced stores) ----------------
__global__ __launch_bounds__(256) void k_qkv(const ushortT* __restrict__ Xt,
                                             const ushortT* __restrict__ Wr,
                                             ushortT* __restrict__ Qb,
                                             ushortT* __restrict__ Kb,
                                             ushortT* __restrict__ Vtb) {
    __shared__ ushortT sVt[64][72];   // 9 KB; row stride 144B (16B-aligned)
    int t = threadIdx.x, w = t >> 6, l = t & 63;
    int lane15 = l & 15, q = l >> 4;
    int mat = blockIdx.y, b = blockIdx.z;
    int i0 = blockIdx.x * 64 + w * 16;

    const ushortT* Wt = Wr + WQKV_OFF + mat * 4096;
    const ushortT* xrow = Xt + ((size_t)b * XT_ROWS + i0 + lane15 + 1) * 64;
    short8 a0 = *(const short8*)(xrow + q * 8);
    short8 a1 = *(const short8*)(xrow + 32 + q * 8);
    float4v acc[4];
    #pragma unroll
    for (int cg = 0; cg < 4; cg++) {
        const ushortT* wrow = Wt + (cg * 16 + lane15) * 64;
        short8 b0 = *(const short8*)(wrow + q * 8);
        short8 b1 = *(const short8*)(wrow + 32 + q * 8);
        float4v a = (float4v)0.f;
        a = __builtin_amdgcn_mfma_f32_16x16x32_bf16(a0, b0, a, 0, 0, 0);
        a = __builtin_amdgcn_mfma_f32_16x16x32_bf16(a1, b1, a, 0, 0, 0);
        acc[cg] = a;
    }
    if (mat < 2) {
        ushortT* o = (mat == 0) ? Qb : Kb;
        #pragma unroll
        for (int cg = 0; cg < 4; cg++)
            #pragma unroll
            for (int r = 0; r < 4; r++)
                o[((size_t)(b * NN + i0 + q * 4 + r)) * 64 + cg * 16 + lane15] = f2bf(acc[cg][r]);
    } else {
        // V: LDS transpose -> coalesced (b,c,n) stores
        int il = w * 16 + q * 4;   // local row base
        #pragma unroll
        for (int cg = 0; cg < 4; cg++)
            #pragma unroll
            for (int r = 0; r < 4; r++)
                sVt[cg * 16 + lane15][il + r] = f2bf(acc[cg][r]);
        __syncthreads();
        int c2 = t >> 2, seg = t & 3;
        short8 v0 = *(const short8*)&sVt[c2][seg * 16];
        short8 v1 = *(const short8*)&sVt[c2][seg * 16 + 8];
        size_t base = ((size_t)(b * 64 + c2)) * NN + blockIdx.x * 64 + seg * 16;
        *(short8*)(Vtb + base) = v0;
        *(short8*)(Vtb + base + 8) = v1;
    }
}

// ---------------- LDS staging helpers for flash ----------------
template<int IS_TSA>
__device__ __forceinline__ void stage_load(short8* kst, short8* vst,
                                           const ushortT* __restrict__ Km,
                                           const ushortT* __restrict__ Vt,
                                           int b, int jb, int t) {
    if (IS_TSA) {
        #pragma unroll
        for (int ps = 0; ps < 2; ps++) {
            int idx = ps * 256 + t, j = idx >> 3, g = idx & 7;
            kst[ps] = *(const short8*)(Km + ((size_t)(b * NN + jb + j)) * 64 + g * 8);
        }
    } else {
        if (t < 64)
            kst[0] = *(const short8*)(Km + ((size_t)(b * NN + jb + t)) * 8);
    }
    #pragma unroll
    for (int ps = 0; ps < 2; ps++) {
        int idx = ps * 256 + t, c = idx >> 3, gj = idx & 7;
        vst[ps] = *(const short8*)(Vt + ((size_t)(b * 64 + c)) * NN + jb + gj * 8);
    }
}

template<int IS_TSA>
__device__ __forceinline__ void stage_write(const short8* kst, const short8* vst,
                                            ushortT* sK, ushortT* sV, int t) {
    if (IS_TSA) {
        #pragma unroll
        for (int ps = 0; ps < 2; ps++) {
            int idx = ps * 256 + t, j = idx >> 3, g = idx & 7;
            *(short8*)(sK + j * 64 + ((g ^ (j & 7)) * 8)) = kst[ps];
        }
    } else {
        if (t < 64)
            *(short8*)(sK + t * 64 + ((t & 7) * 8)) = kst[0];
    }
    #pragma unroll
    for (int ps = 0; ps < 2; ps++) {
        int idx = ps * 256 + t, c = idx >> 3, gj = idx & 7;
        *(short8*)(sV + c * 64 + ((gj ^ (c & 7)) * 8)) = vst[ps];
    }
}

// ---------------- MFMA flash body: LDS-staged K/V, online softmax (lazy rescale) ----------------
template<int IS_TSA>
__device__ __forceinline__ void flash_body(int it, int jc, int b, int t,
                                           const ushortT* __restrict__ Qm,
                                           const ushortT* __restrict__ Km,
                                           const ushortT* __restrict__ Vt,
                                           float* __restrict__ pM,
                                           float* __restrict__ pL,
                                           ushortT* __restrict__ pAcc,
                                           ushortT* __restrict__ sKb,
                                           ushortT* __restrict__ sVb,
                                           ushortT* __restrict__ sPall) {
    constexpr int KCH = IS_TSA ? 2 : 1;
    constexpr int DQ  = IS_TSA ? 64 : 8;
    int w = t >> 6, l = t & 63;
    int lane15 = l & 15, q = l >> 4;
    int i0 = it * 64 + w * 16;
    ushortT* myP = sPall + w * (16 * 64);

    short8 qf[KCH];
    {
        const ushortT* qrow = Qm + ((size_t)(b * NN + i0 + lane15)) * DQ;
        if (IS_TSA) {
            qf[0] = *(const short8*)(qrow + q * 8);
            qf[1] = *(const short8*)(qrow + 32 + q * 8);
        } else {
            short8 z = (short8)0;
            if (q == 0) z = *(const short8*)qrow;
            qf[0] = z;
        }
    }

    float m_run = -3e38f, Lacc = 0.f;
    float4v O[4];
    #pragma unroll
    for (int cs = 0; cs < 4; cs++) O[cs] = (float4v)0.f;

    const int jbase0 = jc * (NN / NJ);

    short8 kst[2], vst[2];
    stage_load<IS_TSA>(kst, vst, Km, Vt, b, jbase0, t);
    stage_write<IS_TSA>(kst, vst, sKb, sVb, t);
    __syncthreads();

    for (int jt = 0; jt < NT; jt++) {
        int cur = jt & 1;
        ushortT* cK = sKb + cur * 4096;
        ushortT* cV = sVb + cur * 4096;
        bool more = (jt + 1 < NT);

        if (more) stage_load<IS_TSA>(kst, vst, Km, Vt, b, jbase0 + (jt + 1) * 64, t);

        short8 kf[4][KCH];
        #pragma unroll
        for (int sub = 0; sub < 4; sub++) {
            int jr = sub * 16 + lane15;
            if (IS_TSA) {
                kf[sub][0] = *(const short8*)(cK + jr * 64 + (((0 * 4 + q) ^ (lane15 & 7)) * 8));
                kf[sub][1] = *(const short8*)(cK + jr * 64 + (((1 * 4 + q) ^ (lane15 & 7)) * 8));
            } else {
                short8 z = (short8)0;
                if (q == 0) z = *(const short8*)(cK + jr * 64 + ((lane15 & 7) * 8));
                kf[sub][0] = z;
            }
        }

        float4v s[4];
        #pragma unroll
        for (int sub = 0; sub < 4; sub++) {
            float4v acc = (float4v)0.f;
            #pragma unroll
            for (int kc = 0; kc < KCH; kc++)
                acc = __builtin_amdgcn_mfma_f32_16x16x32_bf16(kf[sub][kc], qf[kc], acc, 0, 0, 0);
            s[sub] = acc;
        }

        short8 va[4], vbf[4];
        #pragma unroll
        for (int sub = 0; sub < 4; sub++) {
            int cr = sub * 16 + lane15;
            va[sub]  = *(const short8*)(cV + cr * 64 + ((q ^ (lane15 & 7)) * 8));
            vbf[sub] = *(const short8*)(cV + cr * 64 + (((4 + q) ^ (lane15 & 7)) * 8));
        }

        float tmax = fmaxf(fmaxf(fmaxf(s[0][0], s[0][1]), fmaxf(s[0][2], s[0][3])),
                           fmaxf(fmaxf(s[1][0], s[1][1]), fmaxf(s[1][2], s[1][3])));
        float tmax2 = fmaxf(fmaxf(fmaxf(s[2][0], s[2][1]), fmaxf(s[2][2], s[2][3])),
                            fmaxf(fmaxf(s[3][0], s[3][1]), fmaxf(s[3][2], s[3][3])));
        tmax = fmaxf(tmax, tmax2);
        tmax = fmaxf(tmax, __shfl_xor(tmax, 16));
        tmax = fmaxf(tmax, __shfl_xor(tmax, 32));
        float mnew = fmaxf(m_run, tmax);

        if (__any(mnew > m_run)) {
            float corr = exp2f(m_run - mnew);
            Lacc *= corr;
            float c0 = __shfl(corr, q * 4 + 0);
            float c1 = __shfl(corr, q * 4 + 1);
            float c2 = __shfl(corr, q * 4 + 2);
            float c3 = __shfl(corr, q * 4 + 3);
            #pragma unroll
            for (int cs = 0; cs < 4; cs++) {
                O[cs][0] *= c0; O[cs][1] *= c1; O[cs][2] *= c2; O[cs][3] *= c3;
            }
        }
        m_run = mnew;

        #pragma unroll
        for (int sub = 0; sub < 4; sub++) {
            float p0 = exp2f(s[sub][0] - mnew);
            float p1 = exp2f(s[sub][1] - mnew);
            float p2 = exp2f(s[sub][2] - mnew);
            float p3 = exp2f(s[sub][3] - mnew);
            Lacc += (p0 + p1) + (p2 + p3);
            unsigned lo = pk2(p0, p1), hi = pk2(p2, p3);
            int g = sub * 2 + (q >> 1);
            unsigned* wp = (unsigned*)(myP + lane15 * 64 + ((g ^ (lane15 & 7)) * 8) + (q & 1) * 4);
            wp[0] = lo; wp[1] = hi;
        }

        short8 pf0 = *(const short8*)(myP + lane15 * 64 + (((0 * 4 + q) ^ (lane15 & 7)) * 8));
        short8 pf1 = *(const short8*)(myP + lane15 * 64 + (((1 * 4 + q) ^ (lane15 & 7)) * 8));

        #pragma unroll
        for (int sub = 0; sub < 4; sub++) {
            O[sub] = __builtin_amdgcn_mfma_f32_16x16x32_bf16(pf0, va[sub], O[sub], 0, 0, 0);
            O[sub] = __builtin_amdgcn_mfma_f32_16x16x32_bf16(pf1, vbf[sub], O[sub], 0, 0, 0);
        }

        if (more)
            stage_write<IS_TSA>(kst, vst, sKb + (cur ^ 1) * 4096, sVb + (cur ^ 1) * 4096, t);
        __syncthreads();
    }

    size_t base = (size_t)(b * NJ + jc) * NN + i0;
    Lacc += __shfl_xor(Lacc, 16);
    Lacc += __shfl_xor(Lacc, 32);
    if (q == 0) {
        pL[base + lane15] = Lacc;
        pM[base + lane15] = m_run;
    }
    #pragma unroll
    for (int cs = 0; cs < 4; cs++)
        #pragma unroll
        for (int r = 0; r < 4; r++)
            pAcc[(base + q * 4 + r) * 64 + cs * 16 + lane15] = f2bf(O[cs][r]);
}

// ---------------- Fused: TSA flash (blocks 0..511) + conv (blocks 512..1151) ----------------
__global__ __launch_bounds__(256, 4) void k_tsacv(const ushortT* __restrict__ Qb,
                                                  const ushortT* __restrict__ Kb,
                                                  const ushortT* __restrict__ Vtb,
                                                  const ushortT* __restrict__ Xt,
                                                  const ushortT* __restrict__ Wr,
                                                  const float* __restrict__ qb,
                                                  const float* __restrict__ kb,
                                                  const float* __restrict__ vb,
                                                  ushortT* __restrict__ Mt,
                                                  ushortT* __restrict__ Nt,
                                                  ushortT* __restrict__ Wvt,
                                                  float* __restrict__ pMt, float* __restrict__ pLt,
                                                  ushortT* __restrict__ pAccT) {
    __shared__ ushortT sK[2][64 * 64];   // 16 KB
    __shared__ ushortT sV[2][64 * 64];   // 16 KB
    __shared__ ushortT sP[4][16 * 64];   // 8 KB
    int bx = blockIdx.x, t = threadIdx.x;
    if (bx < 512) {
        int it = bx & 63, jc = (bx >> 6) & 3, b = bx >> 8;
        flash_body<1>(it, jc, b, t, Qb, Kb, Vtb, pMt, pLt, pAccT,
                      &sK[0][0], &sV[0][0], &sP[0][0]);
    } else {
        // ---- conv via per-tap MFMA implicit GEMM: wave = 16 pos x 16 oc ----
        int cv = bx - 512;
        int tile = cv & 63, rest = cv >> 6;
        int ocg = rest % 5, b = rest / 5;
        int w = t >> 6, l = t & 63, lane15 = l & 15, q = l >> 4;
        int pos0 = tile * 64 + w * 16;
        const ushortT* xb = Xt + (size_t)b * XT_ROWS * 64;
        int pos = pos0 + lane15;
        int dz = pos & 15, wy = (pos >> 4) & 15, hx = pos >> 8;
        float4v acc0 = (float4v)0.f, acc1 = (float4v)0.f;
        #pragma unroll
        for (int tap = 0; tap < 27; tap++) {
            const int dh = tap / 9 - 1, dw = (tap / 3) % 3 - 1, dd = tap % 3 - 1;
            const int shift = dh * 256 + dw * 16 + dd;
            const ushortT* wrow = Wr + ((size_t)tap * 80 + ocg * 16 + lane15) * 64 + q * 8;
            short8 a0 = *(const short8*)(wrow);
            short8 a1 = *(const short8*)(wrow + 32);
            bool ok = ((unsigned)(hx + dh) < 16u) &&
                      ((unsigned)(wy + dw) < 16u) &&
                      ((unsigned)(dz + dd) < 16u);
            int row = ok ? (pos + shift + 1) : 0;
            const ushortT* xrow = xb + (size_t)row * 64 + q * 8;
            short8 b0 = *(const short8*)xrow;
            short8 b1 = *(const short8*)(xrow + 32);
            acc0 = __builtin_amdgcn_mfma_f32_16x16x32_bf16(a0, b0, acc0, 0, 0, 0);
            acc1 = __builtin_amdgcn_mfma_f32_16x16x32_bf16(a1, b1, acc1, 0, 0, 0);
        }
        float4v accT = acc0 + acc1;
        if (ocg == 0) {
            #pragma unroll
            for (int r = 0; r < 4; r++) {
                int ol = q * 4 + r;
                float v = accT[r];
                if (ol < 8)
                    Mt[((size_t)(b * NN + pos)) * 8 + ol] = f2bf(v + qb[ol] * LOG2E);
                else
                    Nt[((size_t)(b * NN + pos)) * 8 + (ol - 8)] = f2bf(v + kb[ol - 8]);
            }
        } else {
            #pragma unroll
            for (int r = 0; r < 4; r++) {
                int oc = (ocg - 1) * 16 + q * 4 + r;
                Wvt[((size_t)(b * 64 + oc)) * NN + pos] = f2bf(accT[r] + vb[oc]);
            }
        }
    }
}

// ---------------- GSA flash kernel ----------------
__global__ __launch_bounds__(256, 4) void k_gsa(const ushortT* __restrict__ Mtb,
                                                const ushortT* __restrict__ Ntb,
                                                const ushortT* __restrict__ Wvtb,
                                                float* __restrict__ pMg, float* __restrict__ pLg,
                                                ushortT* __restrict__ pAccG) {
    __shared__ ushortT sK[2][64 * 64];
    __shared__ ushortT sV[2][64 * 64];
    __shared__ ushortT sP[4][16 * 64];
    int t = threadIdx.x;
    flash_body<0>(blockIdx.x, blockIdx.y, blockIdx.z, t, Mtb, Ntb, Wvtb, pMg, pLg, pAccG,
                  &sK[0][0], &sV[0][0], &sP[0][0]);
}

// ---------------- Reduce both partial sets (max-merge) + fused epilogue ----------------
__device__ __forceinline__ void reduce_set(const float* __restrict__ pM,
                                           const float* __restrict__ pL,
                                           const ushortT* __restrict__ pAcc,
                                           int b, int n, int seg, float* v) {
    float mv[NJ], M = -3e38f;
    #pragma unroll
    for (int jcc = 0; jcc < NJ; jcc++) {
        mv[jcc] = pM[(size_t)(b * NJ + jcc) * NN + n];
        M = fmaxf(M, mv[jcc]);
    }
    float L = 0.f;
    #pragma unroll
    for (int e = 0; e < 8; e++) v[e] = 0.f;
    #pragma unroll
    for (int jcc = 0; jcc < NJ; jcc++) {
        size_t rb = (size_t)(b * NJ + jcc) * NN + n;
        float wgt = exp2f(mv[jcc] - M);
        L += pL[rb] * wgt;
        short8 x0 = *(const short8*)(pAcc + rb * 64 + seg * 8);
        #pragma unroll
        for (int e = 0; e < 8; e++) v[e] += wgt * bf2f(x0[e]);
    }
    float invL = 1.f / L;
    #pragma unroll
    for (int e = 0; e < 8; e++) v[e] *= invL;
}

__global__ __launch_bounds__(256) void k_reduce(const float* __restrict__ pMt,
                                                const float* __restrict__ pLt,
                                                const ushortT* __restrict__ pAccT,
                                                const float* __restrict__ pMg,
                                                const float* __restrict__ pLg,
                                                const ushortT* __restrict__ pAccG,
                                                const float* __restrict__ xpe,
                                                const float* __restrict__ lam1,
                                                const float* __restrict__ lam2,
                                                float* __restrict__ out) {
    __shared__ float sT[32][65];
    __shared__ float sG[32][65];
    int t = threadIdx.x;
    int b = blockIdx.y;
    int n0 = blockIdx.x * 32;
    int pp = t >> 3, seg = t & 7;
    int n = n0 + pp;

    float vt[8], vg[8];
    reduce_set(pMt, pLt, pAccT, b, n, seg, vt);
    reduce_set(pMg, pLg, pAccG, b, n, seg, vg);
    #pragma unroll
    for (int e = 0; e < 8; e++) {
        sT[pp][seg * 8 + e] = vt[e];
        sG[pp][seg * 8 + e] = vg[e];
    }
    __syncthreads();

    int c = t >> 2, ns = (t & 3) * 8;
    float la1 = lam1[0], la2 = lam2[0];
    size_t ob = ((size_t)(b * 64 + c)) * NN + n0 + ns;
    const float* xp = xpe + ob;
    #pragma unroll
    for (int j = 0; j < 8; j += 4) {
        float4 ov;
        ov.x = la1 * sT[ns + j + 0][c] + la2 * sG[ns + j + 0][c] + xp[j + 0];
        ov.y = la1 * sT[ns + j + 1][c] + la2 * sG[ns + j + 1][c] + xp[j + 1];
        ov.z = la1 * sT[ns + j + 2][c] + la2 * sG[ns + j + 2][c] + xp[j + 2];
        ov.w = la1 * sT[ns + j + 3][c] + la2 * sG[ns + j + 3][c] + xp[j + 3];
        *(float4*)(out + ob + j) = ov;
    }
}

extern "C" void kernel_launch(void* const* d_in, const int* in_sizes, int n_in,
                              void* d_out, int out_size, void* d_ws, size_t ws_size,
                              hipStream_t stream) {
    const float* x    = (const float*)d_in[0];
    const float* Wq   = (const float*)d_in[1];
    const float* Wk   = (const float*)d_in[2];
    const float* Wv   = (const float*)d_in[3];
    const float* qw   = (const float*)d_in[4];
    const float* qb   = (const float*)d_in[5];
    const float* kw   = (const float*)d_in[6];
    const float* kb   = (const float*)d_in[7];
    const float* vw   = (const float*)d_in[8];
    const float* vb   = (const float*)d_in[9];
    const float* lam1 = (const float*)d_in[10];
    const float* lam2 = (const float*)d_in[11];
    float* out = (float*)d_out;

    char* W = (char*)d_ws;
    float*   xpe   = (float*)(W);                               // 2 MB
    ushortT* Qb    = (ushortT*)(W + (2u << 20));                // 1 MB
    ushortT* Kb    = (ushortT*)(W + (3u << 20));                // 1 MB
    ushortT* Vtb   = (ushortT*)(W + (4u << 20));                // 1 MB
    ushortT* Mtb   = (ushortT*)(W + (5u << 20));                // 128 KB
    ushortT* Ntb   = (ushortT*)(W + (5u << 20) + (1u << 17));   // 128 KB
    ushortT* Wvtb  = (ushortT*)(W + (5u << 20) + (2u << 17));   // 1 MB
    ushortT* Xt    = (ushortT*)(W + (6u << 20) + (2u << 17));   // ~1.0 MB
    ushortT* Wr    = (ushortT*)(W + (7u << 20) + (1u << 19));   // ~0.3 MB
    float*   pLt   = (float*)(W + (8u << 20));                  // 128 KB
    float*   pLg   = (float*)(W + (8u << 20) + (1u << 17));     // 128 KB
    float*   pMt   = (float*)(W + (8u << 20) + (2u << 17));     // 128 KB
    float*   pMg   = (float*)(W + (8u << 20) + (3u << 17));     // 128 KB
    ushortT* pAccT = (ushortT*)(W + (8u << 20) + (4u << 17));   // 4 MB
    ushortT* pAccG = (ushortT*)(W + (12u << 20) + (4u << 17));  // 4 MB (ends 16.5 MB)

    // 1. x_pe + Xt transpose + weight reorg
    k_pre<<<dim3(256 + (WQKV_OFF + 3 * 64 * 64 + 255) / 256), dim3(256), 0, stream>>>(
        x, qw, kw, vw, Wq, Wk, Wv, xpe, Xt, Wr);
    // 2. QKV (V via LDS transpose, coalesced stores)
    k_qkv<<<dim3(64, 3, BB), dim3(256), 0, stream>>>(Xt, Wr, Qb, Kb, Vtb);
    // 3. fused TSA flash + conv (conv stalls absorbed by flash waves)
    k_tsacv<<<dim3(512 + 640), dim3(256), 0, stream>>>(
        Qb, Kb, Vtb, Xt, Wr, qb, kb, vb, Mtb, Ntb, Wvtb, pMt, pLt, pAccT);
    // 4. GSA flash
    k_gsa<<<dim3(64, NJ, BB), dim3(256), 0, stream>>>(
        Mtb, Ntb, Wvtb, pMg, pLg, pAccG);
    // 5. merged reduce + epilogue
    k_reduce<<<dim3(NN / 32, BB), dim3(256), 0, stream>>>(
        pMt, pLt, pAccT, pMg, pLg, pAccG, xpe, lam1, lam2, out);
}

// Round 10
// 137.816 us; speedup vs baseline: 1.7950x; 1.1116x over previous
//
#include <hip/hip_runtime.h>
#include <math.h>

// Problem constants
#define BB 2
#define CC 64
#define NN 4096      // 16*16*16
#define CN (CC*NN)
#define NJ 4         // j-split chunks for flash partials
#define NT ((NN/NJ)/64)   // 16 j-tiles per chunk

#define LOG2E 1.4426950408889634f
#define QSCALE 0.18033688011112042f   // log2e / sqrt(64)

#define XT_ROWS 4097                  // row 0 = zero guard row
#define WQKV_OFF (27*80*64)           // offset of transposed QKV weights inside Wr

typedef __attribute__((ext_vector_type(8))) short short8;
typedef __attribute__((ext_vector_type(4))) float float4v;
typedef unsigned short ushortT;

__device__ __forceinline__ ushortT f2bf(float x) {
    union { float f; unsigned u; } v; v.f = x;
    unsigned r = v.u + 0x7FFF + ((v.u >> 16) & 1);   // RNE
    return (ushortT)(r >> 16);
}
__device__ __forceinline__ float bf2f(short s) {
    union { unsigned u; float f; } v;
    v.u = ((unsigned)(unsigned short)s) << 16;
    return v.f;
}
// pack 2 fp32 -> 1 VGPR holding 2 bf16: low16 = bf(a), high16 = bf(b)
__device__ __forceinline__ unsigned pk2(float a, float b) {
    unsigned ua = __float_as_uint(a) + 0x8000u;
    unsigned ub = __float_as_uint(b) + 0x8000u;
    return __builtin_amdgcn_perm(ub, ua, 0x07060302);
}

// ---------------- PE table value: global channel c (0..63), coord 0..15 ----------------
__device__ __forceinline__ float pe_tab_val(int c, int pos) {
    int c2 = (c < 22) ? c : (c < 44) ? (c - 22) : (c - 44);
    int is_cos = (c2 >= 11);
    int k = c2 - (is_cos ? 11 : 0);
    float freq = exp2f(-1.2079738526863135f * (float)k);
    float arg = (float)pos * freq;
    return is_cos ? cosf(arg) : sinf(arg);
}

// ---------------- Merged: x_pe + Xt transpose (blocks 0..255) | weight reorg (blocks 256..) ----------------
__global__ __launch_bounds__(256) void k_pre(const float* __restrict__ x,
                                             const float* __restrict__ qw,
                                             const float* __restrict__ kw,
                                             const float* __restrict__ vw,
                                             const float* __restrict__ Wq,
                                             const float* __restrict__ Wk,
                                             const float* __restrict__ Wv,
                                             float* __restrict__ xpe,
                                             ushortT* __restrict__ Xt,
                                             ushortT* __restrict__ Wr) {
    int blk = blockIdx.x, t = threadIdx.x;
    if (blk < 256) {
        __shared__ float sPE[64][17];
        __shared__ float sT[64][33];
        int b = blk >> 7, pos0 = (blk & 127) * 32;
        #pragma unroll
        for (int k = 0; k < 4; k++) {
            int e = t + k * 256;            // 0..1023
            int c = e >> 4, coord = e & 15;
            sPE[c][coord] = pe_tab_val(c, coord);
        }
        __syncthreads();
        int pin = t & 31, cg = t >> 5;
        #pragma unroll
        for (int pass = 0; pass < 8; pass++) {
            int c = pass * 8 + cg;
            int pos = pos0 + pin;
            int coord = (c < 22) ? (pos >> 8) : (c < 44) ? ((pos >> 4) & 15) : (pos & 15);
            size_t gi = (size_t)(b * 64 + c) * NN + pos;
            float v = x[gi] + sPE[c][coord];
            xpe[gi] = v;
            sT[c][pin] = v;
        }
        __syncthreads();
        int icn = t & 63, pg = t >> 6;
        #pragma unroll
        for (int pass = 0; pass < 8; pass++) {
            int po = pass * 4 + pg;
            Xt[((size_t)b * XT_ROWS + pos0 + po + 1) * 64 + icn] = f2bf(sT[icn][po]);
        }
        if ((blk & 127) == 0 && t < 64)
            Xt[((size_t)b * XT_ROWS) * 64 + t] = 0;   // zero guard row
    } else {
        int idx = (blk - 256) * 256 + t;
        if (idx < WQKV_OFF) {
            int ic = idx & 63;
            int oc = (idx >> 6) % 80;
            int tap = idx / 5120;
            float v;
            if (oc < 8)       v = qw[(oc * 64 + ic) * 27 + tap] * LOG2E;
            else if (oc < 16) v = kw[((oc - 8) * 64 + ic) * 27 + tap];
            else              v = vw[((oc - 16) * 64 + ic) * 27 + tap];
            Wr[idx] = f2bf(v);
        } else if (idx < WQKV_OFF + 3 * 64 * 64) {
            int idx2 = idx - WQKV_OFF;
            int c = idx2 & 63, d = (idx2 >> 6) & 63, mat = idx2 >> 12;
            const float* Wm = (mat == 0) ? Wq : (mat == 1) ? Wk : Wv;
            float v = Wm[c * 64 + d] * ((mat == 0) ? QSCALE : 1.f);
            Wr[idx] = f2bf(v);
        }
    }
}

// ---------------- QKV via MFMA; V transposed via LDS (coalesced stores) ----------------
__global__ __launch_bounds__(256) void k_qkv(const ushortT* __restrict__ Xt,
                                             const ushortT* __restrict__ Wr,
                                             ushortT* __restrict__ Qb,
                                             ushortT* __restrict__ Kb,
                                             ushortT* __restrict__ Vtb) {
    __shared__ ushortT sVt[64][72];   // 9 KB; row stride 144B (16B-aligned)
    int t = threadIdx.x, w = t >> 6, l = t & 63;
    int lane15 = l & 15, q = l >> 4;
    int mat = blockIdx.y, b = blockIdx.z;
    int i0 = blockIdx.x * 64 + w * 16;

    const ushortT* Wt = Wr + WQKV_OFF + mat * 4096;
    const ushortT* xrow = Xt + ((size_t)b * XT_ROWS + i0 + lane15 + 1) * 64;
    short8 a0 = *(const short8*)(xrow + q * 8);
    short8 a1 = *(const short8*)(xrow + 32 + q * 8);
    float4v acc[4];
    #pragma unroll
    for (int cg = 0; cg < 4; cg++) {
        const ushortT* wrow = Wt + (cg * 16 + lane15) * 64;
        short8 b0 = *(const short8*)(wrow + q * 8);
        short8 b1 = *(const short8*)(wrow + 32 + q * 8);
        float4v a = (float4v)0.f;
        a = __builtin_amdgcn_mfma_f32_16x16x32_bf16(a0, b0, a, 0, 0, 0);
        a = __builtin_amdgcn_mfma_f32_16x16x32_bf16(a1, b1, a, 0, 0, 0);
        acc[cg] = a;
    }
    if (mat < 2) {
        ushortT* o = (mat == 0) ? Qb : Kb;
        #pragma unroll
        for (int cg = 0; cg < 4; cg++)
            #pragma unroll
            for (int r = 0; r < 4; r++)
                o[((size_t)(b * NN + i0 + q * 4 + r)) * 64 + cg * 16 + lane15] = f2bf(acc[cg][r]);
    } else {
        // V: LDS transpose -> coalesced (b,c,n) stores
        int il = w * 16 + q * 4;
        #pragma unroll
        for (int cg = 0; cg < 4; cg++)
            #pragma unroll
            for (int r = 0; r < 4; r++)
                sVt[cg * 16 + lane15][il + r] = f2bf(acc[cg][r]);
        __syncthreads();
        int c2 = t >> 2, seg = t & 3;
        short8 v0 = *(const short8*)&sVt[c2][seg * 16];
        short8 v1 = *(const short8*)&sVt[c2][seg * 16 + 8];
        size_t base = ((size_t)(b * 64 + c2)) * NN + blockIdx.x * 64 + seg * 16;
        *(short8*)(Vtb + base) = v0;
        *(short8*)(Vtb + base + 8) = v1;
    }
}

// ---------------- LDS staging helpers for flash ----------------
template<int IS_TSA>
__device__ __forceinline__ void stage_load(short8* kst, short8* vst,
                                           const ushortT* __restrict__ Km,
                                           const ushortT* __restrict__ Vt,
                                           int b, int jb, int t) {
    if (IS_TSA) {
        #pragma unroll
        for (int ps = 0; ps < 2; ps++) {
            int idx = ps * 256 + t, j = idx >> 3, g = idx & 7;
            kst[ps] = *(const short8*)(Km + ((size_t)(b * NN + jb + j)) * 64 + g * 8);
        }
    } else {
        if (t < 64)
            kst[0] = *(const short8*)(Km + ((size_t)(b * NN + jb + t)) * 8);
    }
    #pragma unroll
    for (int ps = 0; ps < 2; ps++) {
        int idx = ps * 256 + t, c = idx >> 3, gj = idx & 7;
        vst[ps] = *(const short8*)(Vt + ((size_t)(b * 64 + c)) * NN + jb + gj * 8);
    }
}

template<int IS_TSA>
__device__ __forceinline__ void stage_write(const short8* kst, const short8* vst,
                                            ushortT* sK, ushortT* sV, int t) {
    if (IS_TSA) {
        #pragma unroll
        for (int ps = 0; ps < 2; ps++) {
            int idx = ps * 256 + t, j = idx >> 3, g = idx & 7;
            *(short8*)(sK + j * 64 + ((g ^ (j & 7)) * 8)) = kst[ps];
        }
    } else {
        if (t < 64)
            *(short8*)(sK + t * 64 + ((t & 7) * 8)) = kst[0];
    }
    #pragma unroll
    for (int ps = 0; ps < 2; ps++) {
        int idx = ps * 256 + t, c = idx >> 3, gj = idx & 7;
        *(short8*)(sV + c * 64 + ((gj ^ (c & 7)) * 8)) = vst[ps];
    }
}

// ---------------- MFMA flash body: LDS-staged K/V, online softmax (lazy rescale) ----------------
template<int IS_TSA>
__device__ __forceinline__ void flash_body(int it, int jc, int b, int t,
                                           const ushortT* __restrict__ Qm,
                                           const ushortT* __restrict__ Km,
                                           const ushortT* __restrict__ Vt,
                                           float* __restrict__ pM,
                                           float* __restrict__ pL,
                                           ushortT* __restrict__ pAcc,
                                           ushortT* __restrict__ sKb,
                                           ushortT* __restrict__ sVb,
                                           ushortT* __restrict__ sPall) {
    constexpr int KCH = IS_TSA ? 2 : 1;
    constexpr int DQ  = IS_TSA ? 64 : 8;
    int w = t >> 6, l = t & 63;
    int lane15 = l & 15, q = l >> 4;
    int i0 = it * 64 + w * 16;
    ushortT* myP = sPall + w * (16 * 64);

    short8 qf[KCH];
    {
        const ushortT* qrow = Qm + ((size_t)(b * NN + i0 + lane15)) * DQ;
        if (IS_TSA) {
            qf[0] = *(const short8*)(qrow + q * 8);
            qf[1] = *(const short8*)(qrow + 32 + q * 8);
        } else {
            short8 z = (short8)0;
            if (q == 0) z = *(const short8*)qrow;
            qf[0] = z;
        }
    }

    float m_run = -3e38f, Lacc = 0.f;
    float4v O[4];
    #pragma unroll
    for (int cs = 0; cs < 4; cs++) O[cs] = (float4v)0.f;

    const int jbase0 = jc * (NN / NJ);

    short8 kst[2], vst[2];
    stage_load<IS_TSA>(kst, vst, Km, Vt, b, jbase0, t);
    stage_write<IS_TSA>(kst, vst, sKb, sVb, t);
    __syncthreads();

    for (int jt = 0; jt < NT; jt++) {
        int cur = jt & 1;
        ushortT* cK = sKb + cur * 4096;
        ushortT* cV = sVb + cur * 4096;
        bool more = (jt + 1 < NT);

        if (more) stage_load<IS_TSA>(kst, vst, Km, Vt, b, jbase0 + (jt + 1) * 64, t);

        short8 kf[4][KCH];
        #pragma unroll
        for (int sub = 0; sub < 4; sub++) {
            int jr = sub * 16 + lane15;
            if (IS_TSA) {
                kf[sub][0] = *(const short8*)(cK + jr * 64 + (((0 * 4 + q) ^ (lane15 & 7)) * 8));
                kf[sub][1] = *(const short8*)(cK + jr * 64 + (((1 * 4 + q) ^ (lane15 & 7)) * 8));
            } else {
                short8 z = (short8)0;
                if (q == 0) z = *(const short8*)(cK + jr * 64 + ((lane15 & 7) * 8));
                kf[sub][0] = z;
            }
        }

        float4v s[4];
        #pragma unroll
        for (int sub = 0; sub < 4; sub++) {
            float4v acc = (float4v)0.f;
            #pragma unroll
            for (int kc = 0; kc < KCH; kc++)
                acc = __builtin_amdgcn_mfma_f32_16x16x32_bf16(kf[sub][kc], qf[kc], acc, 0, 0, 0);
            s[sub] = acc;
        }

        short8 va[4], vbf[4];
        #pragma unroll
        for (int sub = 0; sub < 4; sub++) {
            int cr = sub * 16 + lane15;
            va[sub]  = *(const short8*)(cV + cr * 64 + ((q ^ (lane15 & 7)) * 8));
            vbf[sub] = *(const short8*)(cV + cr * 64 + (((4 + q) ^ (lane15 & 7)) * 8));
        }

        float tmax = fmaxf(fmaxf(fmaxf(s[0][0], s[0][1]), fmaxf(s[0][2], s[0][3])),
                           fmaxf(fmaxf(s[1][0], s[1][1]), fmaxf(s[1][2], s[1][3])));
        float tmax2 = fmaxf(fmaxf(fmaxf(s[2][0], s[2][1]), fmaxf(s[2][2], s[2][3])),
                            fmaxf(fmaxf(s[3][0], s[3][1]), fmaxf(s[3][2], s[3][3])));
        tmax = fmaxf(tmax, tmax2);
        tmax = fmaxf(tmax, __shfl_xor(tmax, 16));
        tmax = fmaxf(tmax, __shfl_xor(tmax, 32));
        float mnew = fmaxf(m_run, tmax);

        if (__any(mnew > m_run)) {
            float corr = exp2f(m_run - mnew);
            Lacc *= corr;
            float c0 = __shfl(corr, q * 4 + 0);
            float c1 = __shfl(corr, q * 4 + 1);
            float c2 = __shfl(corr, q * 4 + 2);
            float c3 = __shfl(corr, q * 4 + 3);
            #pragma unroll
            for (int cs = 0; cs < 4; cs++) {
                O[cs][0] *= c0; O[cs][1] *= c1; O[cs][2] *= c2; O[cs][3] *= c3;
            }
        }
        m_run = mnew;

        #pragma unroll
        for (int sub = 0; sub < 4; sub++) {
            float p0 = exp2f(s[sub][0] - mnew);
            float p1 = exp2f(s[sub][1] - mnew);
            float p2 = exp2f(s[sub][2] - mnew);
            float p3 = exp2f(s[sub][3] - mnew);
            Lacc += (p0 + p1) + (p2 + p3);
            unsigned lo = pk2(p0, p1), hi = pk2(p2, p3);
            int g = sub * 2 + (q >> 1);
            unsigned* wp = (unsigned*)(myP + lane15 * 64 + ((g ^ (lane15 & 7)) * 8) + (q & 1) * 4);
            wp[0] = lo; wp[1] = hi;
        }

        short8 pf0 = *(const short8*)(myP + lane15 * 64 + (((0 * 4 + q) ^ (lane15 & 7)) * 8));
        short8 pf1 = *(const short8*)(myP + lane15 * 64 + (((1 * 4 + q) ^ (lane15 & 7)) * 8));

        #pragma unroll
        for (int sub = 0; sub < 4; sub++) {
            O[sub] = __builtin_amdgcn_mfma_f32_16x16x32_bf16(pf0, va[sub], O[sub], 0, 0, 0);
            O[sub] = __builtin_amdgcn_mfma_f32_16x16x32_bf16(pf1, vbf[sub], O[sub], 0, 0, 0);
        }

        if (more)
            stage_write<IS_TSA>(kst, vst, sKb + (cur ^ 1) * 4096, sVb + (cur ^ 1) * 4096, t);
        __syncthreads();
    }

    size_t base = (size_t)(b * NJ + jc) * NN + i0;
    Lacc += __shfl_xor(Lacc, 16);
    Lacc += __shfl_xor(Lacc, 32);
    if (q == 0) {
        pL[base + lane15] = Lacc;
        pM[base + lane15] = m_run;
    }
    #pragma unroll
    for (int cs = 0; cs < 4; cs++)
        #pragma unroll
        for (int r = 0; r < 4; r++)
            pAcc[(base + q * 4 + r) * 64 + cs * 16 + lane15] = f2bf(O[cs][r]);
}

// ---------------- Fused: TSA flash (blocks 0..511) + ocg-fused conv (blocks 512..639) ----------------
__global__ __launch_bounds__(256, 4) void k_tsacv(const ushortT* __restrict__ Qb,
                                                  const ushortT* __restrict__ Kb,
                                                  const ushortT* __restrict__ Vtb,
                                                  const ushortT* __restrict__ Xt,
                                                  const ushortT* __restrict__ Wr,
                                                  const float* __restrict__ qb,
                                                  const float* __restrict__ kb,
                                                  const float* __restrict__ vb,
                                                  ushortT* __restrict__ Mt,
                                                  ushortT* __restrict__ Nt,
                                                  ushortT* __restrict__ Wvt,
                                                  float* __restrict__ pMt, float* __restrict__ pLt,
                                                  ushortT* __restrict__ pAccT) {
    __shared__ ushortT sm[20480];   // 40 KB, shared carve: flash K/V/P  |  conv W double-buffer
    int bx = blockIdx.x, t = threadIdx.x;
    if (bx < 512) {
        int it = bx & 63, jc = (bx >> 6) & 3, b = bx >> 8;
        flash_body<1>(it, jc, b, t, Qb, Kb, Vtb, pMt, pLt, pAccT,
                      sm, sm + 8192, sm + 16384);
    } else {
        // ---- conv, ocg-fused: block = 64 pos x 80 oc; wave = 16 pos, loops 5 ocg ----
        // W(tap) staged in LDS (2x10 KB double-buffered); X frags loaded once/tap, reused 5x.
        int cv = bx - 512;                 // 0..127
        int tile = cv & 63, b = cv >> 6;
        int w = t >> 6, l = t & 63, lane15 = l & 15, q = l >> 4;
        int pos0 = tile * 64 + w * 16;
        const ushortT* xb = Xt + (size_t)b * XT_ROWS * 64;
        int pos = pos0 + lane15;
        int dz = pos & 15, wy = (pos >> 4) & 15, hx = pos >> 8;

        ushortT* sW = sm;                  // 2 x 5120 ushorts

        float4v accA[5], accB[5];
        #pragma unroll
        for (int o = 0; o < 5; o++) { accA[o] = (float4v)0.f; accB[o] = (float4v)0.f; }

        short8 ws[3];
        auto ldW = [&](int tap) {
            #pragma unroll
            for (int c3 = 0; c3 < 3; c3++) {
                int idx = t + c3 * 256;
                if (idx < 640)
                    ws[c3] = *(const short8*)(Wr + (size_t)tap * 5120 + idx * 8);
            }
        };
        auto wrW = [&](ushortT* buf) {
            #pragma unroll
            for (int c3 = 0; c3 < 3; c3++) {
                int idx = t + c3 * 256;
                if (idx < 640) {
                    int row = idx >> 3, g = idx & 7;
                    *(short8*)(buf + row * 64 + ((g ^ (row & 7)) * 8)) = ws[c3];
                }
            }
        };

        ldW(0);
        wrW(sW);
        __syncthreads();

        #pragma unroll
        for (int tap = 0; tap < 27; tap++) {
            const int dh = tap / 9 - 1, dw = (tap / 3) % 3 - 1, dd = tap % 3 - 1;
            const int shift = dh * 256 + dw * 16 + dd;
            ushortT* cW = sW + (tap & 1) * 5120;
            bool more = (tap + 1 < 27);

            if (more) ldW(tap + 1);

            // X frags (loaded once, reused for all 5 ocg)
            bool ok = ((unsigned)(hx + dh) < 16u) &&
                      ((unsigned)(wy + dw) < 16u) &&
                      ((unsigned)(dz + dd) < 16u);
            int row = ok ? (pos + shift + 1) : 0;
            const ushortT* xrow = xb + (size_t)row * 64 + q * 8;
            short8 b0 = *(const short8*)xrow;
            short8 b1 = *(const short8*)(xrow + 32);

            #pragma unroll
            for (int o = 0; o < 5; o++) {
                int wr2 = o * 16 + lane15;
                short8 a0 = *(const short8*)(cW + wr2 * 64 + ((q ^ (lane15 & 7)) * 8));
                short8 a1 = *(const short8*)(cW + wr2 * 64 + (((4 + q) ^ (lane15 & 7)) * 8));
                accA[o] = __builtin_amdgcn_mfma_f32_16x16x32_bf16(a0, b0, accA[o], 0, 0, 0);
                accB[o] = __builtin_amdgcn_mfma_f32_16x16x32_bf16(a1, b1, accB[o], 0, 0, 0);
            }

            if (more) wrW(sW + ((tap + 1) & 1) * 5120);
            __syncthreads();
        }

        #pragma unroll
        for (int o = 0; o < 5; o++) {
            float4v accT = accA[o] + accB[o];
            if (o == 0) {
                #pragma unroll
                for (int r = 0; r < 4; r++) {
                    int ol = q * 4 + r;
                    float v = accT[r];
                    if (ol < 8)
                        Mt[((size_t)(b * NN + pos)) * 8 + ol] = f2bf(v + qb[ol] * LOG2E);
                    else
                        Nt[((size_t)(b * NN + pos)) * 8 + (ol - 8)] = f2bf(v + kb[ol - 8]);
                }
            } else {
                #pragma unroll
                for (int r = 0; r < 4; r++) {
                    int oc = (o - 1) * 16 + q * 4 + r;
                    Wvt[((size_t)(b * 64 + oc)) * NN + pos] = f2bf(accT[r] + vb[oc]);
                }
            }
        }
    }
}

// ---------------- GSA flash kernel ----------------
__global__ __launch_bounds__(256, 4) void k_gsa(const ushortT* __restrict__ Mtb,
                                                const ushortT* __restrict__ Ntb,
                                                const ushortT* __restrict__ Wvtb,
                                                float* __restrict__ pMg, float* __restrict__ pLg,
                                                ushortT* __restrict__ pAccG) {
    __shared__ ushortT sK[2][64 * 64];
    __shared__ ushortT sV[2][64 * 64];
    __shared__ ushortT sP[4][16 * 64];
    int t = threadIdx.x;
    flash_body<0>(blockIdx.x, blockIdx.y, blockIdx.z, t, Mtb, Ntb, Wvtb, pMg, pLg, pAccG,
                  &sK[0][0], &sV[0][0], &sP[0][0]);
}

// ---------------- Reduce both partial sets (max-merge) + fused epilogue ----------------
__device__ __forceinline__ void reduce_set(const float* __restrict__ pM,
                                           const float* __restrict__ pL,
                                           const ushortT* __restrict__ pAcc,
                                           int b, int n, int seg, float* v) {
    float mv[NJ], M = -3e38f;
    #pragma unroll
    for (int jcc = 0; jcc < NJ; jcc++) {
        mv[jcc] = pM[(size_t)(b * NJ + jcc) * NN + n];
        M = fmaxf(M, mv[jcc]);
    }
    float L = 0.f;
    #pragma unroll
    for (int e = 0; e < 8; e++) v[e] = 0.f;
    #pragma unroll
    for (int jcc = 0; jcc < NJ; jcc++) {
        size_t rb = (size_t)(b * NJ + jcc) * NN + n;
        float wgt = exp2f(mv[jcc] - M);
        L += pL[rb] * wgt;
        short8 x0 = *(const short8*)(pAcc + rb * 64 + seg * 8);
        #pragma unroll
        for (int e = 0; e < 8; e++) v[e] += wgt * bf2f(x0[e]);
    }
    float invL = 1.f / L;
    #pragma unroll
    for (int e = 0; e < 8; e++) v[e] *= invL;
}

__global__ __launch_bounds__(256) void k_reduce(const float* __restrict__ pMt,
                                                const float* __restrict__ pLt,
                                                const ushortT* __restrict__ pAccT,
                                                const float* __restrict__ pMg,
                                                const float* __restrict__ pLg,
                                                const ushortT* __restrict__ pAccG,
                                                const float* __restrict__ xpe,
                                                const float* __restrict__ lam1,
                                                const float* __restrict__ lam2,
                                                float* __restrict__ out) {
    __shared__ float sT[32][65];
    __shared__ float sG[32][65];
    int t = threadIdx.x;
    int b = blockIdx.y;
    int n0 = blockIdx.x * 32;
    int pp = t >> 3, seg = t & 7;
    int n = n0 + pp;

    float vt[8], vg[8];
    reduce_set(pMt, pLt, pAccT, b, n, seg, vt);
    reduce_set(pMg, pLg, pAccG, b, n, seg, vg);
    #pragma unroll
    for (int e = 0; e < 8; e++) {
        sT[pp][seg * 8 + e] = vt[e];
        sG[pp][seg * 8 + e] = vg[e];
    }
    __syncthreads();

    int c = t >> 2, ns = (t & 3) * 8;
    float la1 = lam1[0], la2 = lam2[0];
    size_t ob = ((size_t)(b * 64 + c)) * NN + n0 + ns;
    const float* xp = xpe + ob;
    #pragma unroll
    for (int j = 0; j < 8; j += 4) {
        float4 ov;
        ov.x = la1 * sT[ns + j + 0][c] + la2 * sG[ns + j + 0][c] + xp[j + 0];
        ov.y = la1 * sT[ns + j + 1][c] + la2 * sG[ns + j + 1][c] + xp[j + 1];
        ov.z = la1 * sT[ns + j + 2][c] + la2 * sG[ns + j + 2][c] + xp[j + 2];
        ov.w = la1 * sT[ns + j + 3][c] + la2 * sG[ns + j + 3][c] + xp[j + 3];
        *(float4*)(out + ob + j) = ov;
    }
}

extern "C" void kernel_launch(void* const* d_in, const int* in_sizes, int n_in,
                              void* d_out, int out_size, void* d_ws, size_t ws_size,
                              hipStream_t stream) {
    const float* x    = (const float*)d_in[0];
    const float* Wq   = (const float*)d_in[1];
    const float* Wk   = (const float*)d_in[2];
    const float* Wv   = (const float*)d_in[3];
    const float* qw   = (const float*)d_in[4];
    const float* qb   = (const float*)d_in[5];
    const float* kw   = (const float*)d_in[6];
    const float* kb   = (const float*)d_in[7];
    const float* vw   = (const float*)d_in[8];
    const float* vb   = (const float*)d_in[9];
    const float* lam1 = (const float*)d_in[10];
    const float* lam2 = (const float*)d_in[11];
    float* out = (float*)d_out;

    char* W = (char*)d_ws;
    float*   xpe   = (float*)(W);                               // 2 MB
    ushortT* Qb    = (ushortT*)(W + (2u << 20));                // 1 MB
    ushortT* Kb    = (ushortT*)(W + (3u << 20));                // 1 MB
    ushortT* Vtb   = (ushortT*)(W + (4u << 20));                // 1 MB
    ushortT* Mtb   = (ushortT*)(W + (5u << 20));                // 128 KB
    ushortT* Ntb   = (ushortT*)(W + (5u << 20) + (1u << 17));   // 128 KB
    ushortT* Wvtb  = (ushortT*)(W + (5u << 20) + (2u << 17));   // 1 MB
    ushortT* Xt    = (ushortT*)(W + (6u << 20) + (2u << 17));   // ~1.0 MB
    ushortT* Wr    = (ushortT*)(W + (7u << 20) + (1u << 19));   // ~0.3 MB
    float*   pLt   = (float*)(W + (8u << 20));                  // 128 KB
    float*   pLg   = (float*)(W + (8u << 20) + (1u << 17));     // 128 KB
    float*   pMt   = (float*)(W + (8u << 20) + (2u << 17));     // 128 KB
    float*   pMg   = (float*)(W + (8u << 20) + (3u << 17));     // 128 KB
    ushortT* pAccT = (ushortT*)(W + (8u << 20) + (4u << 17));   // 4 MB
    ushortT* pAccG = (ushortT*)(W + (12u << 20) + (4u << 17));  // 4 MB (ends 16.5 MB)

    // 1. x_pe + Xt transpose + weight reorg
    k_pre<<<dim3(256 + (WQKV_OFF + 3 * 64 * 64 + 255) / 256), dim3(256), 0, stream>>>(
        x, qw, kw, vw, Wq, Wk, Wv, xpe, Xt, Wr);
    // 2. QKV (V via LDS transpose, coalesced stores)
    k_qkv<<<dim3(64, 3, BB), dim3(256), 0, stream>>>(Xt, Wr, Qb, Kb, Vtb);
    // 3. fused TSA flash + ocg-fused conv (W via LDS, X frags reused 5x)
    k_tsacv<<<dim3(512 + 128), dim3(256), 0, stream>>>(
        Qb, Kb, Vtb, Xt, Wr, qb, kb, vb, Mtb, Ntb, Wvtb, pMt, pLt, pAccT);
    // 4. GSA flash
    k_gsa<<<dim3(64, NJ, BB), dim3(256), 0, stream>>>(
        Mtb, Ntb, Wvtb, pMg, pLg, pAccG);
    // 5. merged reduce + epilogue
    k_reduce<<<dim3(NN / 32, BB), dim3(256), 0, stream>>>(
        pMt, pLt, pAccT, pMg, pLg, pAccG, xpe, lam1, lam2, out);
}

// Round 11
// 136.402 us; speedup vs baseline: 1.8136x; 1.0104x over previous
//
#include <hip/hip_runtime.h>
#include <math.h>

// Problem constants
#define BB 2
#define CC 64
#define NN 4096      // 16*16*16
#define CN (CC*NN)
#define NJ 8         // j-split chunks for flash partials (r11: 4->8 for occupancy)
#define NT ((NN/NJ)/64)   // 8 j-tiles per chunk

#define LOG2E 1.4426950408889634f
#define QSCALE 0.18033688011112042f   // log2e / sqrt(64)

#define XT_ROWS 4097                  // row 0 = zero guard row
#define WQKV_OFF (27*80*64)           // offset of transposed QKV weights inside Wr

typedef __attribute__((ext_vector_type(8))) short short8;
typedef __attribute__((ext_vector_type(4))) float float4v;
typedef unsigned short ushortT;

__device__ __forceinline__ ushortT f2bf(float x) {
    union { float f; unsigned u; } v; v.f = x;
    unsigned r = v.u + 0x7FFF + ((v.u >> 16) & 1);   // RNE
    return (ushortT)(r >> 16);
}
__device__ __forceinline__ float bf2f(short s) {
    union { unsigned u; float f; } v;
    v.u = ((unsigned)(unsigned short)s) << 16;
    return v.f;
}
// pack 2 fp32 -> 1 VGPR holding 2 bf16: low16 = bf(a), high16 = bf(b)
__device__ __forceinline__ unsigned pk2(float a, float b) {
    unsigned ua = __float_as_uint(a) + 0x8000u;
    unsigned ub = __float_as_uint(b) + 0x8000u;
    return __builtin_amdgcn_perm(ub, ua, 0x07060302);
}

// ---------------- PE table value: global channel c (0..63), coord 0..15 ----------------
__device__ __forceinline__ float pe_tab_val(int c, int pos) {
    int c2 = (c < 22) ? c : (c < 44) ? (c - 22) : (c - 44);
    int is_cos = (c2 >= 11);
    int k = c2 - (is_cos ? 11 : 0);
    float freq = exp2f(-1.2079738526863135f * (float)k);
    float arg = (float)pos * freq;
    return is_cos ? cosf(arg) : sinf(arg);
}

// ---------------- Merged: x_pe + Xt transpose (blocks 0..255) | weight reorg (blocks 256..) ----------------
__global__ __launch_bounds__(256) void k_pre(const float* __restrict__ x,
                                             const float* __restrict__ qw,
                                             const float* __restrict__ kw,
                                             const float* __restrict__ vw,
                                             const float* __restrict__ Wq,
                                             const float* __restrict__ Wk,
                                             const float* __restrict__ Wv,
                                             float* __restrict__ xpe,
                                             ushortT* __restrict__ Xt,
                                             ushortT* __restrict__ Wr) {
    int blk = blockIdx.x, t = threadIdx.x;
    if (blk < 256) {
        __shared__ float sPE[64][17];
        __shared__ float sT[64][33];
        int b = blk >> 7, pos0 = (blk & 127) * 32;
        #pragma unroll
        for (int k = 0; k < 4; k++) {
            int e = t + k * 256;            // 0..1023
            int c = e >> 4, coord = e & 15;
            sPE[c][coord] = pe_tab_val(c, coord);
        }
        __syncthreads();
        int pin = t & 31, cg = t >> 5;
        #pragma unroll
        for (int pass = 0; pass < 8; pass++) {
            int c = pass * 8 + cg;
            int pos = pos0 + pin;
            int coord = (c < 22) ? (pos >> 8) : (c < 44) ? ((pos >> 4) & 15) : (pos & 15);
            size_t gi = (size_t)(b * 64 + c) * NN + pos;
            float v = x[gi] + sPE[c][coord];
            xpe[gi] = v;
            sT[c][pin] = v;
        }
        __syncthreads();
        int icn = t & 63, pg = t >> 6;
        #pragma unroll
        for (int pass = 0; pass < 8; pass++) {
            int po = pass * 4 + pg;
            Xt[((size_t)b * XT_ROWS + pos0 + po + 1) * 64 + icn] = f2bf(sT[icn][po]);
        }
        if ((blk & 127) == 0 && t < 64)
            Xt[((size_t)b * XT_ROWS) * 64 + t] = 0;   // zero guard row
    } else {
        int idx = (blk - 256) * 256 + t;
        if (idx < WQKV_OFF) {
            int ic = idx & 63;
            int oc = (idx >> 6) % 80;
            int tap = idx / 5120;
            float v;
            if (oc < 8)       v = qw[(oc * 64 + ic) * 27 + tap] * LOG2E;
            else if (oc < 16) v = kw[((oc - 8) * 64 + ic) * 27 + tap];
            else              v = vw[((oc - 16) * 64 + ic) * 27 + tap];
            Wr[idx] = f2bf(v);
        } else if (idx < WQKV_OFF + 3 * 64 * 64) {
            int idx2 = idx - WQKV_OFF;
            int c = idx2 & 63, d = (idx2 >> 6) & 63, mat = idx2 >> 12;
            const float* Wm = (mat == 0) ? Wq : (mat == 1) ? Wk : Wv;
            float v = Wm[c * 64 + d] * ((mat == 0) ? QSCALE : 1.f);
            Wr[idx] = f2bf(v);
        }
    }
}

// ---------------- QKV via MFMA; V transposed via LDS (coalesced stores) ----------------
__global__ __launch_bounds__(256) void k_qkv(const ushortT* __restrict__ Xt,
                                             const ushortT* __restrict__ Wr,
                                             ushortT* __restrict__ Qb,
                                             ushortT* __restrict__ Kb,
                                             ushortT* __restrict__ Vtb) {
    __shared__ ushortT sVt[64][72];   // 9 KB; row stride 144B (16B-aligned)
    int t = threadIdx.x, w = t >> 6, l = t & 63;
    int lane15 = l & 15, q = l >> 4;
    int mat = blockIdx.y, b = blockIdx.z;
    int i0 = blockIdx.x * 64 + w * 16;

    const ushortT* Wt = Wr + WQKV_OFF + mat * 4096;
    const ushortT* xrow = Xt + ((size_t)b * XT_ROWS + i0 + lane15 + 1) * 64;
    short8 a0 = *(const short8*)(xrow + q * 8);
    short8 a1 = *(const short8*)(xrow + 32 + q * 8);
    float4v acc[4];
    #pragma unroll
    for (int cg = 0; cg < 4; cg++) {
        const ushortT* wrow = Wt + (cg * 16 + lane15) * 64;
        short8 b0 = *(const short8*)(wrow + q * 8);
        short8 b1 = *(const short8*)(wrow + 32 + q * 8);
        float4v a = (float4v)0.f;
        a = __builtin_amdgcn_mfma_f32_16x16x32_bf16(a0, b0, a, 0, 0, 0);
        a = __builtin_amdgcn_mfma_f32_16x16x32_bf16(a1, b1, a, 0, 0, 0);
        acc[cg] = a;
    }
    if (mat < 2) {
        ushortT* o = (mat == 0) ? Qb : Kb;
        #pragma unroll
        for (int cg = 0; cg < 4; cg++)
            #pragma unroll
            for (int r = 0; r < 4; r++)
                o[((size_t)(b * NN + i0 + q * 4 + r)) * 64 + cg * 16 + lane15] = f2bf(acc[cg][r]);
    } else {
        // V: LDS transpose -> coalesced (b,c,n) stores
        int il = w * 16 + q * 4;
        #pragma unroll
        for (int cg = 0; cg < 4; cg++)
            #pragma unroll
            for (int r = 0; r < 4; r++)
                sVt[cg * 16 + lane15][il + r] = f2bf(acc[cg][r]);
        __syncthreads();
        int c2 = t >> 2, seg = t & 3;
        short8 v0 = *(const short8*)&sVt[c2][seg * 16];
        short8 v1 = *(const short8*)&sVt[c2][seg * 16 + 8];
        size_t base = ((size_t)(b * 64 + c2)) * NN + blockIdx.x * 64 + seg * 16;
        *(short8*)(Vtb + base) = v0;
        *(short8*)(Vtb + base + 8) = v1;
    }
}

// ---------------- LDS staging helpers for flash ----------------
template<int IS_TSA>
__device__ __forceinline__ void stage_load(short8* kst, short8* vst,
                                           const ushortT* __restrict__ Km,
                                           const ushortT* __restrict__ Vt,
                                           int b, int jb, int t) {
    if (IS_TSA) {
        #pragma unroll
        for (int ps = 0; ps < 2; ps++) {
            int idx = ps * 256 + t, j = idx >> 3, g = idx & 7;
            kst[ps] = *(const short8*)(Km + ((size_t)(b * NN + jb + j)) * 64 + g * 8);
        }
    } else {
        if (t < 64)
            kst[0] = *(const short8*)(Km + ((size_t)(b * NN + jb + t)) * 8);
    }
    #pragma unroll
    for (int ps = 0; ps < 2; ps++) {
        int idx = ps * 256 + t, c = idx >> 3, gj = idx & 7;
        vst[ps] = *(const short8*)(Vt + ((size_t)(b * 64 + c)) * NN + jb + gj * 8);
    }
}

template<int IS_TSA>
__device__ __forceinline__ void stage_write(const short8* kst, const short8* vst,
                                            ushortT* sK, ushortT* sV, int t) {
    if (IS_TSA) {
        #pragma unroll
        for (int ps = 0; ps < 2; ps++) {
            int idx = ps * 256 + t, j = idx >> 3, g = idx & 7;
            *(short8*)(sK + j * 64 + ((g ^ (j & 7)) * 8)) = kst[ps];
        }
    } else {
        if (t < 64)
            *(short8*)(sK + t * 64 + ((t & 7) * 8)) = kst[0];
    }
    #pragma unroll
    for (int ps = 0; ps < 2; ps++) {
        int idx = ps * 256 + t, c = idx >> 3, gj = idx & 7;
        *(short8*)(sV + c * 64 + ((gj ^ (c & 7)) * 8)) = vst[ps];
    }
}

// ---------------- MFMA flash body: LDS-staged K/V, online softmax (lazy rescale) ----------------
template<int IS_TSA>
__device__ __forceinline__ void flash_body(int it, int jc, int b, int t,
                                           const ushortT* __restrict__ Qm,
                                           const ushortT* __restrict__ Km,
                                           const ushortT* __restrict__ Vt,
                                           float* __restrict__ pM,
                                           float* __restrict__ pL,
                                           ushortT* __restrict__ pAcc,
                                           ushortT* __restrict__ sKb,
                                           ushortT* __restrict__ sVb,
                                           ushortT* __restrict__ sPall) {
    constexpr int KCH = IS_TSA ? 2 : 1;
    constexpr int DQ  = IS_TSA ? 64 : 8;
    int w = t >> 6, l = t & 63;
    int lane15 = l & 15, q = l >> 4;
    int i0 = it * 64 + w * 16;
    ushortT* myP = sPall + w * (16 * 64);

    short8 qf[KCH];
    {
        const ushortT* qrow = Qm + ((size_t)(b * NN + i0 + lane15)) * DQ;
        if (IS_TSA) {
            qf[0] = *(const short8*)(qrow + q * 8);
            qf[1] = *(const short8*)(qrow + 32 + q * 8);
        } else {
            short8 z = (short8)0;
            if (q == 0) z = *(const short8*)qrow;
            qf[0] = z;
        }
    }

    float m_run = -3e38f, Lacc = 0.f;
    float4v O[4];
    #pragma unroll
    for (int cs = 0; cs < 4; cs++) O[cs] = (float4v)0.f;

    const int jbase0 = jc * (NN / NJ);

    short8 kst[2], vst[2];
    stage_load<IS_TSA>(kst, vst, Km, Vt, b, jbase0, t);
    stage_write<IS_TSA>(kst, vst, sKb, sVb, t);
    __syncthreads();

    for (int jt = 0; jt < NT; jt++) {
        int cur = jt & 1;
        ushortT* cK = sKb + cur * 4096;
        ushortT* cV = sVb + cur * 4096;
        bool more = (jt + 1 < NT);

        if (more) stage_load<IS_TSA>(kst, vst, Km, Vt, b, jbase0 + (jt + 1) * 64, t);

        short8 kf[4][KCH];
        #pragma unroll
        for (int sub = 0; sub < 4; sub++) {
            int jr = sub * 16 + lane15;
            if (IS_TSA) {
                kf[sub][0] = *(const short8*)(cK + jr * 64 + (((0 * 4 + q) ^ (lane15 & 7)) * 8));
                kf[sub][1] = *(const short8*)(cK + jr * 64 + (((1 * 4 + q) ^ (lane15 & 7)) * 8));
            } else {
                short8 z = (short8)0;
                if (q == 0) z = *(const short8*)(cK + jr * 64 + ((lane15 & 7) * 8));
                kf[sub][0] = z;
            }
        }

        float4v s[4];
        #pragma unroll
        for (int sub = 0; sub < 4; sub++) {
            float4v acc = (float4v)0.f;
            #pragma unroll
            for (int kc = 0; kc < KCH; kc++)
                acc = __builtin_amdgcn_mfma_f32_16x16x32_bf16(kf[sub][kc], qf[kc], acc, 0, 0, 0);
            s[sub] = acc;
        }

        short8 va[4], vbf[4];
        #pragma unroll
        for (int sub = 0; sub < 4; sub++) {
            int cr = sub * 16 + lane15;
            va[sub]  = *(const short8*)(cV + cr * 64 + ((q ^ (lane15 & 7)) * 8));
            vbf[sub] = *(const short8*)(cV + cr * 64 + (((4 + q) ^ (lane15 & 7)) * 8));
        }

        float tmax = fmaxf(fmaxf(fmaxf(s[0][0], s[0][1]), fmaxf(s[0][2], s[0][3])),
                           fmaxf(fmaxf(s[1][0], s[1][1]), fmaxf(s[1][2], s[1][3])));
        float tmax2 = fmaxf(fmaxf(fmaxf(s[2][0], s[2][1]), fmaxf(s[2][2], s[2][3])),
                            fmaxf(fmaxf(s[3][0], s[3][1]), fmaxf(s[3][2], s[3][3])));
        tmax = fmaxf(tmax, tmax2);
        tmax = fmaxf(tmax, __shfl_xor(tmax, 16));
        tmax = fmaxf(tmax, __shfl_xor(tmax, 32));
        float mnew = fmaxf(m_run, tmax);

        if (__any(mnew > m_run)) {
            float corr = exp2f(m_run - mnew);
            Lacc *= corr;
            float c0 = __shfl(corr, q * 4 + 0);
            float c1 = __shfl(corr, q * 4 + 1);
            float c2 = __shfl(corr, q * 4 + 2);
            float c3 = __shfl(corr, q * 4 + 3);
            #pragma unroll
            for (int cs = 0; cs < 4; cs++) {
                O[cs][0] *= c0; O[cs][1] *= c1; O[cs][2] *= c2; O[cs][3] *= c3;
            }
        }
        m_run = mnew;

        #pragma unroll
        for (int sub = 0; sub < 4; sub++) {
            float p0 = exp2f(s[sub][0] - mnew);
            float p1 = exp2f(s[sub][1] - mnew);
            float p2 = exp2f(s[sub][2] - mnew);
            float p3 = exp2f(s[sub][3] - mnew);
            Lacc += (p0 + p1) + (p2 + p3);
            unsigned lo = pk2(p0, p1), hi = pk2(p2, p3);
            int g = sub * 2 + (q >> 1);
            unsigned* wp = (unsigned*)(myP + lane15 * 64 + ((g ^ (lane15 & 7)) * 8) + (q & 1) * 4);
            wp[0] = lo; wp[1] = hi;
        }

        short8 pf0 = *(const short8*)(myP + lane15 * 64 + (((0 * 4 + q) ^ (lane15 & 7)) * 8));
        short8 pf1 = *(const short8*)(myP + lane15 * 64 + (((1 * 4 + q) ^ (lane15 & 7)) * 8));

        #pragma unroll
        for (int sub = 0; sub < 4; sub++) {
            O[sub] = __builtin_amdgcn_mfma_f32_16x16x32_bf16(pf0, va[sub], O[sub], 0, 0, 0);
            O[sub] = __builtin_amdgcn_mfma_f32_16x16x32_bf16(pf1, vbf[sub], O[sub], 0, 0, 0);
        }

        if (more)
            stage_write<IS_TSA>(kst, vst, sKb + (cur ^ 1) * 4096, sVb + (cur ^ 1) * 4096, t);
        __syncthreads();
    }

    size_t base = (size_t)(b * NJ + jc) * NN + i0;
    Lacc += __shfl_xor(Lacc, 16);
    Lacc += __shfl_xor(Lacc, 32);
    if (q == 0) {
        pL[base + lane15] = Lacc;
        pM[base + lane15] = m_run;
    }
    #pragma unroll
    for (int cs = 0; cs < 4; cs++)
        #pragma unroll
        for (int r = 0; r < 4; r++)
            pAcc[(base + q * 4 + r) * 64 + cs * 16 + lane15] = f2bf(O[cs][r]);
}

// ---------------- Fused: conv (blocks 0..127) + TSA flash (blocks 128..1151) ----------------
__global__ __launch_bounds__(256, 4) void k_tsacv(const ushortT* __restrict__ Qb,
                                                  const ushortT* __restrict__ Kb,
                                                  const ushortT* __restrict__ Vtb,
                                                  const ushortT* __restrict__ Xt,
                                                  const ushortT* __restrict__ Wr,
                                                  const float* __restrict__ qb,
                                                  const float* __restrict__ kb,
                                                  const float* __restrict__ vb,
                                                  ushortT* __restrict__ Mt,
                                                  ushortT* __restrict__ Nt,
                                                  ushortT* __restrict__ Wvt,
                                                  float* __restrict__ pMt, float* __restrict__ pLt,
                                                  ushortT* __restrict__ pAccT) {
    __shared__ ushortT sm[20480];   // 40 KB: flash K/V/P | conv W double-buffer
    int bx = blockIdx.x, t = threadIdx.x;
    if (bx >= 128) {
        int fb = bx - 128;
        int it = fb & 63, jc = (fb >> 6) & 7, b = fb >> 9;
        flash_body<1>(it, jc, b, t, Qb, Kb, Vtb, pMt, pLt, pAccT,
                      sm, sm + 8192, sm + 16384);
    } else {
        // ---- conv, ocg-fused: block = 64 pos x 80 oc; wave = 16 pos, loops 5 ocg ----
        int cv = bx;                       // 0..127
        int tile = cv & 63, b = cv >> 6;
        int w = t >> 6, l = t & 63, lane15 = l & 15, q = l >> 4;
        int pos0 = tile * 64 + w * 16;
        const ushortT* xb = Xt + (size_t)b * XT_ROWS * 64;
        int pos = pos0 + lane15;
        int dz = pos & 15, wy = (pos >> 4) & 15, hx = pos >> 8;

        ushortT* sW = sm;                  // 2 x 5120 ushorts

        float4v accA[5], accB[5];
        #pragma unroll
        for (int o = 0; o < 5; o++) { accA[o] = (float4v)0.f; accB[o] = (float4v)0.f; }

        short8 ws[3];
        auto ldW = [&](int tap) {
            #pragma unroll
            for (int c3 = 0; c3 < 3; c3++) {
                int idx = t + c3 * 256;
                if (idx < 640)
                    ws[c3] = *(const short8*)(Wr + (size_t)tap * 5120 + idx * 8);
            }
        };
        auto wrW = [&](ushortT* buf) {
            #pragma unroll
            for (int c3 = 0; c3 < 3; c3++) {
                int idx = t + c3 * 256;
                if (idx < 640) {
                    int row = idx >> 3, g = idx & 7;
                    *(short8*)(buf + row * 64 + ((g ^ (row & 7)) * 8)) = ws[c3];
                }
            }
        };

        ldW(0);
        wrW(sW);
        __syncthreads();

        #pragma unroll
        for (int tap = 0; tap < 27; tap++) {
            const int dh = tap / 9 - 1, dw = (tap / 3) % 3 - 1, dd = tap % 3 - 1;
            const int shift = dh * 256 + dw * 16 + dd;
            ushortT* cW = sW + (tap & 1) * 5120;
            bool more = (tap + 1 < 27);

            if (more) ldW(tap + 1);

            bool ok = ((unsigned)(hx + dh) < 16u) &&
                      ((unsigned)(wy + dw) < 16u) &&
                      ((unsigned)(dz + dd) < 16u);
            int row = ok ? (pos + shift + 1) : 0;
            const ushortT* xrow = xb + (size_t)row * 64 + q * 8;
            short8 b0 = *(const short8*)xrow;
            short8 b1 = *(const short8*)(xrow + 32);

            #pragma unroll
            for (int o = 0; o < 5; o++) {
                int wr2 = o * 16 + lane15;
                short8 a0 = *(const short8*)(cW + wr2 * 64 + ((q ^ (lane15 & 7)) * 8));
                short8 a1 = *(const short8*)(cW + wr2 * 64 + (((4 + q) ^ (lane15 & 7)) * 8));
                accA[o] = __builtin_amdgcn_mfma_f32_16x16x32_bf16(a0, b0, accA[o], 0, 0, 0);
                accB[o] = __builtin_amdgcn_mfma_f32_16x16x32_bf16(a1, b1, accB[o], 0, 0, 0);
            }

            if (more) wrW(sW + ((tap + 1) & 1) * 5120);
            __syncthreads();
        }

        #pragma unroll
        for (int o = 0; o < 5; o++) {
            float4v accT = accA[o] + accB[o];
            if (o == 0) {
                #pragma unroll
                for (int r = 0; r < 4; r++) {
                    int ol = q * 4 + r;
                    float v = accT[r];
                    if (ol < 8)
                        Mt[((size_t)(b * NN + pos)) * 8 + ol] = f2bf(v + qb[ol] * LOG2E);
                    else
                        Nt[((size_t)(b * NN + pos)) * 8 + (ol - 8)] = f2bf(v + kb[ol - 8]);
                }
            } else {
                #pragma unroll
                for (int r = 0; r < 4; r++) {
                    int oc = (o - 1) * 16 + q * 4 + r;
                    Wvt[((size_t)(b * 64 + oc)) * NN + pos] = f2bf(accT[r] + vb[oc]);
                }
            }
        }
    }
}

// ---------------- GSA flash kernel ----------------
__global__ __launch_bounds__(256, 4) void k_gsa(const ushortT* __restrict__ Mtb,
                                                const ushortT* __restrict__ Ntb,
                                                const ushortT* __restrict__ Wvtb,
                                                float* __restrict__ pMg, float* __restrict__ pLg,
                                                ushortT* __restrict__ pAccG) {
    __shared__ ushortT sK[2][64 * 64];
    __shared__ ushortT sV[2][64 * 64];
    __shared__ ushortT sP[4][16 * 64];
    int t = threadIdx.x;
    flash_body<0>(blockIdx.x, blockIdx.y, blockIdx.z, t, Mtb, Ntb, Wvtb, pMg, pLg, pAccG,
                  &sK[0][0], &sV[0][0], &sP[0][0]);
}

// ---------------- Reduce both partial sets (max-merge) + fused epilogue ----------------
__device__ __forceinline__ void reduce_set(const float* __restrict__ pM,
                                           const float* __restrict__ pL,
                                           const ushortT* __restrict__ pAcc,
                                           int b, int n, int seg, float* v) {
    float mv[NJ], M = -3e38f;
    #pragma unroll
    for (int jcc = 0; jcc < NJ; jcc++) {
        mv[jcc] = pM[(size_t)(b * NJ + jcc) * NN + n];
        M = fmaxf(M, mv[jcc]);
    }
    float L = 0.f;
    #pragma unroll
    for (int e = 0; e < 8; e++) v[e] = 0.f;
    #pragma unroll
    for (int jcc = 0; jcc < NJ; jcc++) {
        size_t rb = (size_t)(b * NJ + jcc) * NN + n;
        float wgt = exp2f(mv[jcc] - M);
        L += pL[rb] * wgt;
        short8 x0 = *(const short8*)(pAcc + rb * 64 + seg * 8);
        #pragma unroll
        for (int e = 0; e < 8; e++) v[e] += wgt * bf2f(x0[e]);
    }
    float invL = 1.f / L;
    #pragma unroll
    for (int e = 0; e < 8; e++) v[e] *= invL;
}

__global__ __launch_bounds__(256) void k_reduce(const float* __restrict__ pMt,
                                                const float* __restrict__ pLt,
                                                const ushortT* __restrict__ pAccT,
                                                const float* __restrict__ pMg,
                                                const float* __restrict__ pLg,
                                                const ushortT* __restrict__ pAccG,
                                                const float* __restrict__ xpe,
                                                const float* __restrict__ lam1,
                                                const float* __restrict__ lam2,
                                                float* __restrict__ out) {
    __shared__ float sT[32][65];
    __shared__ float sG[32][65];
    int t = threadIdx.x;
    int b = blockIdx.y;
    int n0 = blockIdx.x * 32;
    int pp = t >> 3, seg = t & 7;
    int n = n0 + pp;

    float vt[8], vg[8];
    reduce_set(pMt, pLt, pAccT, b, n, seg, vt);
    reduce_set(pMg, pLg, pAccG, b, n, seg, vg);
    #pragma unroll
    for (int e = 0; e < 8; e++) {
        sT[pp][seg * 8 + e] = vt[e];
        sG[pp][seg * 8 + e] = vg[e];
    }
    __syncthreads();

    int c = t >> 2, ns = (t & 3) * 8;
    float la1 = lam1[0], la2 = lam2[0];
    size_t ob = ((size_t)(b * 64 + c)) * NN + n0 + ns;
    const float* xp = xpe + ob;
    #pragma unroll
    for (int j = 0; j < 8; j += 4) {
        float4 ov;
        ov.x = la1 * sT[ns + j + 0][c] + la2 * sG[ns + j + 0][c] + xp[j + 0];
        ov.y = la1 * sT[ns + j + 1][c] + la2 * sG[ns + j + 1][c] + xp[j + 1];
        ov.z = la1 * sT[ns + j + 2][c] + la2 * sG[ns + j + 2][c] + xp[j + 2];
        ov.w = la1 * sT[ns + j + 3][c] + la2 * sG[ns + j + 3][c] + xp[j + 3];
        *(float4*)(out + ob + j) = ov;
    }
}

extern "C" void kernel_launch(void* const* d_in, const int* in_sizes, int n_in,
                              void* d_out, int out_size, void* d_ws, size_t ws_size,
                              hipStream_t stream) {
    const float* x    = (const float*)d_in[0];
    const float* Wq   = (const float*)d_in[1];
    const float* Wk   = (const float*)d_in[2];
    const float* Wv   = (const float*)d_in[3];
    const float* qw   = (const float*)d_in[4];
    const float* qb   = (const float*)d_in[5];
    const float* kw   = (const float*)d_in[6];
    const float* kb   = (const float*)d_in[7];
    const float* vw   = (const float*)d_in[8];
    const float* vb   = (const float*)d_in[9];
    const float* lam1 = (const float*)d_in[10];
    const float* lam2 = (const float*)d_in[11];
    float* out = (float*)d_out;

    char* W = (char*)d_ws;
    float*   xpe   = (float*)(W);                               // 2 MB
    ushortT* Qb    = (ushortT*)(W + (2u << 20));                // 1 MB
    ushortT* Kb    = (ushortT*)(W + (3u << 20));                // 1 MB
    ushortT* Vtb   = (ushortT*)(W + (4u << 20));                // 1 MB
    ushortT* Mtb   = (ushortT*)(W + (5u << 20));                // 128 KB
    ushortT* Ntb   = (ushortT*)(W + (5u << 20) + (1u << 17));   // 128 KB
    ushortT* Wvtb  = (ushortT*)(W + (5u << 20) + (2u << 17));   // 1 MB
    ushortT* Xt    = (ushortT*)(W + (6u << 20) + (2u << 17));   // ~1.0 MB
    ushortT* Wr    = (ushortT*)(W + (7u << 20) + (1u << 19));   // ~0.3 MB
    float*   pLt   = (float*)(W + (8u << 20));                  // 256 KB (NJ=8)
    float*   pLg   = (float*)(W + (8u << 20) + (1u << 18));     // 256 KB
    float*   pMt   = (float*)(W + (8u << 20) + (2u << 18));     // 256 KB
    float*   pMg   = (float*)(W + (8u << 20) + (3u << 18));     // 256 KB
    ushortT* pAccT = (ushortT*)(W + (9u << 20));                // 8 MB (NJ=8, bf16)
    ushortT* pAccG = (ushortT*)(W + (17u << 20));               // 8 MB (ends 25 MB)

    // 1. x_pe + Xt transpose + weight reorg
    k_pre<<<dim3(256 + (WQKV_OFF + 3 * 64 * 64 + 255) / 256), dim3(256), 0, stream>>>(
        x, qw, kw, vw, Wq, Wk, Wv, xpe, Xt, Wr);
    // 2. QKV (V via LDS transpose, coalesced stores)
    k_qkv<<<dim3(64, 3, BB), dim3(256), 0, stream>>>(Xt, Wr, Qb, Kb, Vtb);
    // 3. fused conv (first 128 blocks) + TSA flash (1024 blocks, NJ=8)
    k_tsacv<<<dim3(128 + 64 * NJ * BB), dim3(256), 0, stream>>>(
        Qb, Kb, Vtb, Xt, Wr, qb, kb, vb, Mtb, Ntb, Wvtb, pMt, pLt, pAccT);
    // 4. GSA flash (NJ=8 -> 1024 blocks)
    k_gsa<<<dim3(64, NJ, BB), dim3(256), 0, stream>>>(
        Mtb, Ntb, Wvtb, pMg, pLg, pAccG);
    // 5. merged reduce + epilogue
    k_reduce<<<dim3(NN / 32, BB), dim3(256), 0, stream>>>(
        pMt, pLt, pAccT, pMg, pLg, pAccG, xpe, lam1, lam2, out);
}

// Round 12
// 135.326 us; speedup vs baseline: 1.8280x; 1.0080x over previous
//
#include <hip/hip_runtime.h>
#include <math.h>

// Problem constants
#define BB 2
#define CC 64
#define NN 4096      // 16*16*16
#define CN (CC*NN)
#define NJ 8         // j-split chunks for flash partials
#define NT ((NN/NJ)/64)   // 8 j-tiles per chunk

#define LOG2E 1.4426950408889634f
#define QSCALE 0.18033688011112042f   // log2e / sqrt(64)

#define XT_ROWS 4097                  // row 0 = zero guard row
#define WQKV_OFF (27*80*64)           // offset of transposed QKV weights inside Wr

typedef __attribute__((ext_vector_type(8))) short short8;
typedef __attribute__((ext_vector_type(4))) float float4v;
typedef unsigned short ushortT;

__device__ __forceinline__ ushortT f2bf(float x) {
    union { float f; unsigned u; } v; v.f = x;
    unsigned r = v.u + 0x7FFF + ((v.u >> 16) & 1);   // RNE
    return (ushortT)(r >> 16);
}
__device__ __forceinline__ float bf2f(short s) {
    union { unsigned u; float f; } v;
    v.u = ((unsigned)(unsigned short)s) << 16;
    return v.f;
}
// pack 2 fp32 -> 1 VGPR holding 2 bf16: low16 = bf(a), high16 = bf(b)
__device__ __forceinline__ unsigned pk2(float a, float b) {
    unsigned ua = __float_as_uint(a) + 0x8000u;
    unsigned ub = __float_as_uint(b) + 0x8000u;
    return __builtin_amdgcn_perm(ub, ua, 0x07060302);
}

// ---------------- PE table value: global channel c (0..63), coord 0..15 ----------------
__device__ __forceinline__ float pe_tab_val(int c, int pos) {
    int c2 = (c < 22) ? c : (c < 44) ? (c - 22) : (c - 44);
    int is_cos = (c2 >= 11);
    int k = c2 - (is_cos ? 11 : 0);
    float freq = exp2f(-1.2079738526863135f * (float)k);
    float arg = (float)pos * freq;
    return is_cos ? cosf(arg) : sinf(arg);
}

// ---------------- Merged: x_pe + Xt transpose (blocks 0..255) | weight reorg (blocks 256..) ----------------
__global__ __launch_bounds__(256) void k_pre(const float* __restrict__ x,
                                             const float* __restrict__ qw,
                                             const float* __restrict__ kw,
                                             const float* __restrict__ vw,
                                             const float* __restrict__ Wq,
                                             const float* __restrict__ Wk,
                                             const float* __restrict__ Wv,
                                             float* __restrict__ xpe,
                                             ushortT* __restrict__ Xt,
                                             ushortT* __restrict__ Wr) {
    int blk = blockIdx.x, t = threadIdx.x;
    if (blk < 256) {
        __shared__ float sPE[64][17];
        __shared__ float sT[64][33];
        int b = blk >> 7, pos0 = (blk & 127) * 32;
        #pragma unroll
        for (int k = 0; k < 4; k++) {
            int e = t + k * 256;            // 0..1023
            int c = e >> 4, coord = e & 15;
            sPE[c][coord] = pe_tab_val(c, coord);
        }
        __syncthreads();
        int pin = t & 31, cg = t >> 5;
        #pragma unroll
        for (int pass = 0; pass < 8; pass++) {
            int c = pass * 8 + cg;
            int pos = pos0 + pin;
            int coord = (c < 22) ? (pos >> 8) : (c < 44) ? ((pos >> 4) & 15) : (pos & 15);
            size_t gi = (size_t)(b * 64 + c) * NN + pos;
            float v = x[gi] + sPE[c][coord];
            xpe[gi] = v;
            sT[c][pin] = v;
        }
        __syncthreads();
        int icn = t & 63, pg = t >> 6;
        #pragma unroll
        for (int pass = 0; pass < 8; pass++) {
            int po = pass * 4 + pg;
            Xt[((size_t)b * XT_ROWS + pos0 + po + 1) * 64 + icn] = f2bf(sT[icn][po]);
        }
        if ((blk & 127) == 0 && t < 64)
            Xt[((size_t)b * XT_ROWS) * 64 + t] = 0;   // zero guard row
    } else {
        int idx = (blk - 256) * 256 + t;
        if (idx < WQKV_OFF) {
            int ic = idx & 63;
            int oc = (idx >> 6) % 80;
            int tap = idx / 5120;
            float v;
            if (oc < 8)       v = qw[(oc * 64 + ic) * 27 + tap] * LOG2E;
            else if (oc < 16) v = kw[((oc - 8) * 64 + ic) * 27 + tap];
            else              v = vw[((oc - 16) * 64 + ic) * 27 + tap];
            Wr[idx] = f2bf(v);
        } else if (idx < WQKV_OFF + 3 * 64 * 64) {
            int idx2 = idx - WQKV_OFF;
            int c = idx2 & 63, d = (idx2 >> 6) & 63, mat = idx2 >> 12;
            const float* Wm = (mat == 0) ? Wq : (mat == 1) ? Wk : Wv;
            float v = Wm[c * 64 + d] * ((mat == 0) ? QSCALE : 1.f);
            Wr[idx] = f2bf(v);
        }
    }
}

// ---------------- QKV via MFMA; V transposed via LDS (coalesced stores) ----------------
__global__ __launch_bounds__(256) void k_qkv(const ushortT* __restrict__ Xt,
                                             const ushortT* __restrict__ Wr,
                                             ushortT* __restrict__ Qb,
                                             ushortT* __restrict__ Kb,
                                             ushortT* __restrict__ Vtb) {
    __shared__ ushortT sVt[64][72];   // 9 KB; row stride 144B (16B-aligned)
    int t = threadIdx.x, w = t >> 6, l = t & 63;
    int lane15 = l & 15, q = l >> 4;
    int mat = blockIdx.y, b = blockIdx.z;
    int i0 = blockIdx.x * 64 + w * 16;

    const ushortT* Wt = Wr + WQKV_OFF + mat * 4096;
    const ushortT* xrow = Xt + ((size_t)b * XT_ROWS + i0 + lane15 + 1) * 64;
    short8 a0 = *(const short8*)(xrow + q * 8);
    short8 a1 = *(const short8*)(xrow + 32 + q * 8);
    float4v acc[4];
    #pragma unroll
    for (int cg = 0; cg < 4; cg++) {
        const ushortT* wrow = Wt + (cg * 16 + lane15) * 64;
        short8 b0 = *(const short8*)(wrow + q * 8);
        short8 b1 = *(const short8*)(wrow + 32 + q * 8);
        float4v a = (float4v)0.f;
        a = __builtin_amdgcn_mfma_f32_16x16x32_bf16(a0, b0, a, 0, 0, 0);
        a = __builtin_amdgcn_mfma_f32_16x16x32_bf16(a1, b1, a, 0, 0, 0);
        acc[cg] = a;
    }
    if (mat < 2) {
        ushortT* o = (mat == 0) ? Qb : Kb;
        #pragma unroll
        for (int cg = 0; cg < 4; cg++)
            #pragma unroll
            for (int r = 0; r < 4; r++)
                o[((size_t)(b * NN + i0 + q * 4 + r)) * 64 + cg * 16 + lane15] = f2bf(acc[cg][r]);
    } else {
        // V: LDS transpose -> coalesced (b,c,n) stores
        int il = w * 16 + q * 4;
        #pragma unroll
        for (int cg = 0; cg < 4; cg++)
            #pragma unroll
            for (int r = 0; r < 4; r++)
                sVt[cg * 16 + lane15][il + r] = f2bf(acc[cg][r]);
        __syncthreads();
        int c2 = t >> 2, seg = t & 3;
        short8 v0 = *(const short8*)&sVt[c2][seg * 16];
        short8 v1 = *(const short8*)&sVt[c2][seg * 16 + 8];
        size_t base = ((size_t)(b * 64 + c2)) * NN + blockIdx.x * 64 + seg * 16;
        *(short8*)(Vtb + base) = v0;
        *(short8*)(Vtb + base + 8) = v1;
    }
}

// ---------------- LDS staging helpers for flash ----------------
template<int IS_TSA>
__device__ __forceinline__ void stage_load(short8* kst, short8* vst,
                                           const ushortT* __restrict__ Km,
                                           const ushortT* __restrict__ Vt,
                                           int b, int jb, int t) {
    if (IS_TSA) {
        #pragma unroll
        for (int ps = 0; ps < 2; ps++) {
            int idx = ps * 256 + t, j = idx >> 3, g = idx & 7;
            kst[ps] = *(const short8*)(Km + ((size_t)(b * NN + jb + j)) * 64 + g * 8);
        }
    } else {
        if (t < 64)
            kst[0] = *(const short8*)(Km + ((size_t)(b * NN + jb + t)) * 8);
    }
    #pragma unroll
    for (int ps = 0; ps < 2; ps++) {
        int idx = ps * 256 + t, c = idx >> 3, gj = idx & 7;
        vst[ps] = *(const short8*)(Vt + ((size_t)(b * 64 + c)) * NN + jb + gj * 8);
    }
}

template<int IS_TSA>
__device__ __forceinline__ void stage_write(const short8* kst, const short8* vst,
                                            ushortT* sK, ushortT* sV, int t) {
    if (IS_TSA) {
        #pragma unroll
        for (int ps = 0; ps < 2; ps++) {
            int idx = ps * 256 + t, j = idx >> 3, g = idx & 7;
            *(short8*)(sK + j * 64 + ((g ^ (j & 7)) * 8)) = kst[ps];
        }
    } else {
        if (t < 64)
            *(short8*)(sK + t * 64 + ((t & 7) * 8)) = kst[0];
    }
    #pragma unroll
    for (int ps = 0; ps < 2; ps++) {
        int idx = ps * 256 + t, c = idx >> 3, gj = idx & 7;
        *(short8*)(sV + c * 64 + ((gj ^ (c & 7)) * 8)) = vst[ps];
    }
}

// ---------------- MFMA flash body: 2 i-subtiles per wave (K/V fragment reuse) ----------------
// it indexes 128-query tiles. Wave w: queries it*128 + w*16 .. +15 and +64 .. +79.
template<int IS_TSA>
__device__ __forceinline__ void flash_body(int it, int jc, int b, int t,
                                           const ushortT* __restrict__ Qm,
                                           const ushortT* __restrict__ Km,
                                           const ushortT* __restrict__ Vt,
                                           float* __restrict__ pM,
                                           float* __restrict__ pL,
                                           ushortT* __restrict__ pAcc,
                                           ushortT* __restrict__ sKb,
                                           ushortT* __restrict__ sVb,
                                           ushortT* __restrict__ sPall) {
    constexpr int KCH = IS_TSA ? 2 : 1;
    constexpr int DQ  = IS_TSA ? 64 : 8;
    int w = t >> 6, l = t & 63;
    int lane15 = l & 15, q = l >> 4;
    int i0a = it * 128 + w * 16;
    ushortT* myP = sPall + w * (16 * 64);

    // Q fragments for both i-subtiles (B-operand: lane = query, k = channel)
    short8 qf[2][KCH];
    #pragma unroll
    for (int si = 0; si < 2; si++) {
        const ushortT* qrow = Qm + ((size_t)(b * NN + i0a + si * 64 + lane15)) * DQ;
        if (IS_TSA) {
            qf[si][0] = *(const short8*)(qrow + q * 8);
            qf[si][1] = *(const short8*)(qrow + 32 + q * 8);
        } else {
            short8 z = (short8)0;
            if (q == 0) z = *(const short8*)qrow;
            qf[si][0] = z;
        }
    }

    float m_run[2] = {-3e38f, -3e38f}, Lacc[2] = {0.f, 0.f};
    float4v O[2][4];
    #pragma unroll
    for (int si = 0; si < 2; si++)
        #pragma unroll
        for (int cs = 0; cs < 4; cs++) O[si][cs] = (float4v)0.f;

    const int jbase0 = jc * (NN / NJ);

    short8 kst[2], vst[2];
    stage_load<IS_TSA>(kst, vst, Km, Vt, b, jbase0, t);
    stage_write<IS_TSA>(kst, vst, sKb, sVb, t);
    __syncthreads();

    for (int jt = 0; jt < NT; jt++) {
        int cur = jt & 1;
        ushortT* cK = sKb + cur * 4096;
        ushortT* cV = sVb + cur * 4096;
        bool more = (jt + 1 < NT);

        if (more) stage_load<IS_TSA>(kst, vst, Km, Vt, b, jbase0 + (jt + 1) * 64, t);

        // ---- K fragments from LDS, reused for BOTH i-subtiles ----
        short8 kf[4][KCH];
        #pragma unroll
        for (int sub = 0; sub < 4; sub++) {
            int jr = sub * 16 + lane15;
            if (IS_TSA) {
                kf[sub][0] = *(const short8*)(cK + jr * 64 + (((0 * 4 + q) ^ (lane15 & 7)) * 8));
                kf[sub][1] = *(const short8*)(cK + jr * 64 + (((1 * 4 + q) ^ (lane15 & 7)) * 8));
            } else {
                short8 z = (short8)0;
                if (q == 0) z = *(const short8*)(cK + jr * 64 + ((lane15 & 7) * 8));
                kf[sub][0] = z;
            }
        }

        // ---- S^T for both subtiles (kf dies after this) ----
        float4v s[2][4];
        #pragma unroll
        for (int si = 0; si < 2; si++)
            #pragma unroll
            for (int sub = 0; sub < 4; sub++) {
                float4v acc = (float4v)0.f;
                #pragma unroll
                for (int kc = 0; kc < KCH; kc++)
                    acc = __builtin_amdgcn_mfma_f32_16x16x32_bf16(kf[sub][kc], qf[si][kc], acc, 0, 0, 0);
                s[si][sub] = acc;
            }

        // ---- V fragments from LDS, reused for BOTH i-subtiles ----
        short8 va[4], vbf[4];
        #pragma unroll
        for (int sub = 0; sub < 4; sub++) {
            int cr = sub * 16 + lane15;
            va[sub]  = *(const short8*)(cV + cr * 64 + ((q ^ (lane15 & 7)) * 8));
            vbf[sub] = *(const short8*)(cV + cr * 64 + (((4 + q) ^ (lane15 & 7)) * 8));
        }

        // ---- per-subtile: softmax, P, PV ----
        #pragma unroll
        for (int si = 0; si < 2; si++) {
            float tmax = fmaxf(fmaxf(fmaxf(s[si][0][0], s[si][0][1]), fmaxf(s[si][0][2], s[si][0][3])),
                               fmaxf(fmaxf(s[si][1][0], s[si][1][1]), fmaxf(s[si][1][2], s[si][1][3])));
            float tmax2 = fmaxf(fmaxf(fmaxf(s[si][2][0], s[si][2][1]), fmaxf(s[si][2][2], s[si][2][3])),
                                fmaxf(fmaxf(s[si][3][0], s[si][3][1]), fmaxf(s[si][3][2], s[si][3][3])));
            tmax = fmaxf(tmax, tmax2);
            tmax = fmaxf(tmax, __shfl_xor(tmax, 16));
            tmax = fmaxf(tmax, __shfl_xor(tmax, 32));
            float mnew = fmaxf(m_run[si], tmax);

            if (__any(mnew > m_run[si])) {
                float corr = exp2f(m_run[si] - mnew);
                Lacc[si] *= corr;
                float c0 = __shfl(corr, q * 4 + 0);
                float c1 = __shfl(corr, q * 4 + 1);
                float c2 = __shfl(corr, q * 4 + 2);
                float c3 = __shfl(corr, q * 4 + 3);
                #pragma unroll
                for (int cs = 0; cs < 4; cs++) {
                    O[si][cs][0] *= c0; O[si][cs][1] *= c1;
                    O[si][cs][2] *= c2; O[si][cs][3] *= c3;
                }
            }
            m_run[si] = mnew;

            #pragma unroll
            for (int sub = 0; sub < 4; sub++) {
                float p0 = exp2f(s[si][sub][0] - mnew);
                float p1 = exp2f(s[si][sub][1] - mnew);
                float p2 = exp2f(s[si][sub][2] - mnew);
                float p3 = exp2f(s[si][sub][3] - mnew);
                Lacc[si] += (p0 + p1) + (p2 + p3);
                unsigned lo = pk2(p0, p1), hi = pk2(p2, p3);
                int g = sub * 2 + (q >> 1);
                unsigned* wp = (unsigned*)(myP + lane15 * 64 + ((g ^ (lane15 & 7)) * 8) + (q & 1) * 4);
                wp[0] = lo; wp[1] = hi;
            }

            short8 pf0 = *(const short8*)(myP + lane15 * 64 + (((0 * 4 + q) ^ (lane15 & 7)) * 8));
            short8 pf1 = *(const short8*)(myP + lane15 * 64 + (((1 * 4 + q) ^ (lane15 & 7)) * 8));

            #pragma unroll
            for (int sub = 0; sub < 4; sub++) {
                O[si][sub] = __builtin_amdgcn_mfma_f32_16x16x32_bf16(pf0, va[sub], O[si][sub], 0, 0, 0);
                O[si][sub] = __builtin_amdgcn_mfma_f32_16x16x32_bf16(pf1, vbf[sub], O[si][sub], 0, 0, 0);
            }
        }

        if (more)
            stage_write<IS_TSA>(kst, vst, sKb + (cur ^ 1) * 4096, sVb + (cur ^ 1) * 4096, t);
        __syncthreads();
    }

    // ---- store partials for both subtiles ----
    #pragma unroll
    for (int si = 0; si < 2; si++) {
        size_t base = (size_t)(b * NJ + jc) * NN + i0a + si * 64;
        float Ls = Lacc[si];
        Ls += __shfl_xor(Ls, 16);
        Ls += __shfl_xor(Ls, 32);
        if (q == 0) {
            pL[base + lane15] = Ls;
            pM[base + lane15] = m_run[si];
        }
        #pragma unroll
        for (int cs = 0; cs < 4; cs++)
            #pragma unroll
            for (int r = 0; r < 4; r++)
                pAcc[(base + q * 4 + r) * 64 + cs * 16 + lane15] = f2bf(O[si][cs][r]);
    }
}

// ---------------- Fused: conv (blocks 0..127) + TSA flash (blocks 128..639) ----------------
__global__ __launch_bounds__(256, 3) void k_tsacv(const ushortT* __restrict__ Qb,
                                                  const ushortT* __restrict__ Kb,
                                                  const ushortT* __restrict__ Vtb,
                                                  const ushortT* __restrict__ Xt,
                                                  const ushortT* __restrict__ Wr,
                                                  const float* __restrict__ qb,
                                                  const float* __restrict__ kb,
                                                  const float* __restrict__ vb,
                                                  ushortT* __restrict__ Mt,
                                                  ushortT* __restrict__ Nt,
                                                  ushortT* __restrict__ Wvt,
                                                  float* __restrict__ pMt, float* __restrict__ pLt,
                                                  ushortT* __restrict__ pAccT) {
    __shared__ ushortT sm[20480];   // 40 KB: flash K/V/P | conv W double-buffer
    int bx = blockIdx.x, t = threadIdx.x;
    if (bx >= 128) {
        int fb = bx - 128;                 // 0..511
        int it = fb & 31, jc = (fb >> 5) & 7, b = fb >> 8;
        flash_body<1>(it, jc, b, t, Qb, Kb, Vtb, pMt, pLt, pAccT,
                      sm, sm + 8192, sm + 16384);
    } else {
        // ---- conv, ocg-fused: block = 64 pos x 80 oc; wave = 16 pos, loops 5 ocg ----
        int cv = bx;                       // 0..127
        int tile = cv & 63, b = cv >> 6;
        int w = t >> 6, l = t & 63, lane15 = l & 15, q = l >> 4;
        int pos0 = tile * 64 + w * 16;
        const ushortT* xb = Xt + (size_t)b * XT_ROWS * 64;
        int pos = pos0 + lane15;
        int dz = pos & 15, wy = (pos >> 4) & 15, hx = pos >> 8;

        ushortT* sW = sm;                  // 2 x 5120 ushorts

        float4v accA[5], accB[5];
        #pragma unroll
        for (int o = 0; o < 5; o++) { accA[o] = (float4v)0.f; accB[o] = (float4v)0.f; }

        short8 ws[3];
        auto ldW = [&](int tap) {
            #pragma unroll
            for (int c3 = 0; c3 < 3; c3++) {
                int idx = t + c3 * 256;
                if (idx < 640)
                    ws[c3] = *(const short8*)(Wr + (size_t)tap * 5120 + idx * 8);
            }
        };
        auto wrW = [&](ushortT* buf) {
            #pragma unroll
            for (int c3 = 0; c3 < 3; c3++) {
                int idx = t + c3 * 256;
                if (idx < 640) {
                    int row = idx >> 3, g = idx & 7;
                    *(short8*)(buf + row * 64 + ((g ^ (row & 7)) * 8)) = ws[c3];
                }
            }
        };

        ldW(0);
        wrW(sW);
        __syncthreads();

        #pragma unroll
        for (int tap = 0; tap < 27; tap++) {
            const int dh = tap / 9 - 1, dw = (tap / 3) % 3 - 1, dd = tap % 3 - 1;
            const int shift = dh * 256 + dw * 16 + dd;
            ushortT* cW = sW + (tap & 1) * 5120;
            bool more = (tap + 1 < 27);

            if (more) ldW(tap + 1);

            bool ok = ((unsigned)(hx + dh) < 16u) &&
                      ((unsigned)(wy + dw) < 16u) &&
                      ((unsigned)(dz + dd) < 16u);
            int row = ok ? (pos + shift + 1) : 0;
            const ushortT* xrow = xb + (size_t)row * 64 + q * 8;
            short8 b0 = *(const short8*)xrow;
            short8 b1 = *(const short8*)(xrow + 32);

            #pragma unroll
            for (int o = 0; o < 5; o++) {
                int wr2 = o * 16 + lane15;
                short8 a0 = *(const short8*)(cW + wr2 * 64 + ((q ^ (lane15 & 7)) * 8));
                short8 a1 = *(const short8*)(cW + wr2 * 64 + (((4 + q) ^ (lane15 & 7)) * 8));
                accA[o] = __builtin_amdgcn_mfma_f32_16x16x32_bf16(a0, b0, accA[o], 0, 0, 0);
                accB[o] = __builtin_amdgcn_mfma_f32_16x16x32_bf16(a1, b1, accB[o], 0, 0, 0);
            }

            if (more) wrW(sW + ((tap + 1) & 1) * 5120);
            __syncthreads();
        }

        #pragma unroll
        for (int o = 0; o < 5; o++) {
            float4v accT = accA[o] + accB[o];
            if (o == 0) {
                #pragma unroll
                for (int r = 0; r < 4; r++) {
                    int ol = q * 4 + r;
                    float v = accT[r];
                    if (ol < 8)
                        Mt[((size_t)(b * NN + pos)) * 8 + ol] = f2bf(v + qb[ol] * LOG2E);
                    else
                        Nt[((size_t)(b * NN + pos)) * 8 + (ol - 8)] = f2bf(v + kb[ol - 8]);
                }
            } else {
                #pragma unroll
                for (int r = 0; r < 4; r++) {
                    int oc = (o - 1) * 16 + q * 4 + r;
                    Wvt[((size_t)(b * 64 + oc)) * NN + pos] = f2bf(accT[r] + vb[oc]);
                }
            }
        }
    }
}

// ---------------- GSA flash kernel ----------------
__global__ __launch_bounds__(256, 3) void k_gsa(const ushortT* __restrict__ Mtb,
                                                const ushortT* __restrict__ Ntb,
                                                const ushortT* __restrict__ Wvtb,
                                                float* __restrict__ pMg, float* __restrict__ pLg,
                                                ushortT* __restrict__ pAccG) {
    __shared__ ushortT sK[2][64 * 64];
    __shared__ ushortT sV[2][64 * 64];
    __shared__ ushortT sP[4][16 * 64];
    int t = threadIdx.x;
    flash_body<0>(blockIdx.x, blockIdx.y, blockIdx.z, t, Mtb, Ntb, Wvtb, pMg, pLg, pAccG,
                  &sK[0][0], &sV[0][0], &sP[0][0]);
}

// ---------------- Reduce both partial sets (max-merge) + fused epilogue ----------------
__device__ __forceinline__ void reduce_set(const float* __restrict__ pM,
                                           const float* __restrict__ pL,
                                           const ushortT* __restrict__ pAcc,
                                           int b, int n, int seg, float* v) {
    float mv[NJ], M = -3e38f;
    #pragma unroll
    for (int jcc = 0; jcc < NJ; jcc++) {
        mv[jcc] = pM[(size_t)(b * NJ + jcc) * NN + n];
        M = fmaxf(M, mv[jcc]);
    }
    float L = 0.f;
    #pragma unroll
    for (int e = 0; e < 8; e++) v[e] = 0.f;
    #pragma unroll
    for (int jcc = 0; jcc < NJ; jcc++) {
        size_t rb = (size_t)(b * NJ + jcc) * NN + n;
        float wgt = exp2f(mv[jcc] - M);
        L += pL[rb] * wgt;
        short8 x0 = *(const short8*)(pAcc + rb * 64 + seg * 8);
        #pragma unroll
        for (int e = 0; e < 8; e++) v[e] += wgt * bf2f(x0[e]);
    }
    float invL = 1.f / L;
    #pragma unroll
    for (int e = 0; e < 8; e++) v[e] *= invL;
}

__global__ __launch_bounds__(256) void k_reduce(const float* __restrict__ pMt,
                                                const float* __restrict__ pLt,
                                                const ushortT* __restrict__ pAccT,
                                                const float* __restrict__ pMg,
                                                const float* __restrict__ pLg,
                                                const ushortT* __restrict__ pAccG,
                                                const float* __restrict__ xpe,
                                                const float* __restrict__ lam1,
                                                const float* __restrict__ lam2,
                                                float* __restrict__ out) {
    __shared__ float sT[32][65];
    __shared__ float sG[32][65];
    int t = threadIdx.x;
    int b = blockIdx.y;
    int n0 = blockIdx.x * 32;
    int pp = t >> 3, seg = t & 7;
    int n = n0 + pp;

    float vt[8], vg[8];
    reduce_set(pMt, pLt, pAccT, b, n, seg, vt);
    reduce_set(pMg, pLg, pAccG, b, n, seg, vg);
    #pragma unroll
    for (int e = 0; e < 8; e++) {
        sT[pp][seg * 8 + e] = vt[e];
        sG[pp][seg * 8 + e] = vg[e];
    }
    __syncthreads();

    int c = t >> 2, ns = (t & 3) * 8;
    float la1 = lam1[0], la2 = lam2[0];
    size_t ob = ((size_t)(b * 64 + c)) * NN + n0 + ns;
    const float* xp = xpe + ob;
    #pragma unroll
    for (int j = 0; j < 8; j += 4) {
        float4 ov;
        ov.x = la1 * sT[ns + j + 0][c] + la2 * sG[ns + j + 0][c] + xp[j + 0];
        ov.y = la1 * sT[ns + j + 1][c] + la2 * sG[ns + j + 1][c] + xp[j + 1];
        ov.z = la1 * sT[ns + j + 2][c] + la2 * sG[ns + j + 2][c] + xp[j + 2];
        ov.w = la1 * sT[ns + j + 3][c] + la2 * sG[ns + j + 3][c] + xp[j + 3];
        *(float4*)(out + ob + j) = ov;
    }
}

extern "C" void kernel_launch(void* const* d_in, const int* in_sizes, int n_in,
                              void* d_out, int out_size, void* d_ws, size_t ws_size,
                              hipStream_t stream) {
    const float* x    = (const float*)d_in[0];
    const float* Wq   = (const float*)d_in[1];
    const float* Wk   = (const float*)d_in[2];
    const float* Wv   = (const float*)d_in[3];
    const float* qw   = (const float*)d_in[4];
    const float* qb   = (const float*)d_in[5];
    const float* kw   = (const float*)d_in[6];
    const float* kb   = (const float*)d_in[7];
    const float* vw   = (const float*)d_in[8];
    const float* vb   = (const float*)d_in[9];
    const float* lam1 = (const float*)d_in[10];
    const float* lam2 = (const float*)d_in[11];
    float* out = (float*)d_out;

    char* W = (char*)d_ws;
    float*   xpe   = (float*)(W);                               // 2 MB
    ushortT* Qb    = (ushortT*)(W + (2u << 20));                // 1 MB
    ushortT* Kb    = (ushortT*)(W + (3u << 20));                // 1 MB
    ushortT* Vtb   = (ushortT*)(W + (4u << 20));                // 1 MB
    ushortT* Mtb   = (ushortT*)(W + (5u << 20));                // 128 KB
    ushortT* Ntb   = (ushortT*)(W + (5u << 20) + (1u << 17));   // 128 KB
    ushortT* Wvtb  = (ushortT*)(W + (5u << 20) + (2u << 17));   // 1 MB
    ushortT* Xt    = (ushortT*)(W + (6u << 20) + (2u << 17));   // ~1.0 MB
    ushortT* Wr    = (ushortT*)(W + (7u << 20) + (1u << 19));   // ~0.3 MB
    float*   pLt   = (float*)(W + (8u << 20));                  // 256 KB (NJ=8)
    float*   pLg   = (float*)(W + (8u << 20) + (1u << 18));     // 256 KB
    float*   pMt   = (float*)(W + (8u << 20) + (2u << 18));     // 256 KB
    float*   pMg   = (float*)(W + (8u << 20) + (3u << 18));     // 256 KB
    ushortT* pAccT = (ushortT*)(W + (9u << 20));                // 8 MB (NJ=8, bf16)
    ushortT* pAccG = (ushortT*)(W + (17u << 20));               // 8 MB (ends 25 MB)

    // 1. x_pe + Xt transpose + weight reorg
    k_pre<<<dim3(256 + (WQKV_OFF + 3 * 64 * 64 + 255) / 256), dim3(256), 0, stream>>>(
        x, qw, kw, vw, Wq, Wk, Wv, xpe, Xt, Wr);
    // 2. QKV (V via LDS transpose, coalesced stores)
    k_qkv<<<dim3(64, 3, BB), dim3(256), 0, stream>>>(Xt, Wr, Qb, Kb, Vtb);
    // 3. fused conv (128 blocks) + TSA flash (512 blocks, 128 queries/block)
    k_tsacv<<<dim3(128 + 32 * NJ * BB), dim3(256), 0, stream>>>(
        Qb, Kb, Vtb, Xt, Wr, qb, kb, vb, Mtb, Ntb, Wvtb, pMt, pLt, pAccT);
    // 4. GSA flash (32 i-tiles x NJ x B = 512 blocks)
    k_gsa<<<dim3(32, NJ, BB), dim3(256), 0, stream>>>(
        Mtb, Ntb, Wvtb, pMg, pLg, pAccG);
    // 5. merged reduce + epilogue
    k_reduce<<<dim3(NN / 32, BB), dim3(256), 0, stream>>>(
        pMt, pLt, pAccT, pMg, pLg, pAccG, xpe, lam1, lam2, out);
}

// Round 13
// 135.017 us; speedup vs baseline: 1.8322x; 1.0023x over previous
//
#include <hip/hip_runtime.h>
#include <math.h>

// Problem constants
#define BB 2
#define CC 64
#define NN 4096      // 16*16*16
#define CN (CC*NN)
#define NJ 8         // j-split chunks for flash partials
#define NT ((NN/NJ)/64)   // 8 j-tiles per chunk

#define LOG2E 1.4426950408889634f
#define QSCALE 0.18033688011112042f   // log2e / sqrt(64)

#define XT_ROWS 4097                  // row 0 = zero guard row
#define WQKV_OFF (27*80*64)           // conv-tap reorg size (QKV weights now staged per-block)

typedef __attribute__((ext_vector_type(8))) short short8;
typedef __attribute__((ext_vector_type(4))) float float4v;
typedef unsigned short ushortT;

__device__ __forceinline__ ushortT f2bf(float x) {
    union { float f; unsigned u; } v; v.f = x;
    unsigned r = v.u + 0x7FFF + ((v.u >> 16) & 1);   // RNE
    return (ushortT)(r >> 16);
}
__device__ __forceinline__ float bf2f(short s) {
    union { unsigned u; float f; } v;
    v.u = ((unsigned)(unsigned short)s) << 16;
    return v.f;
}
// pack 2 fp32 -> 1 VGPR holding 2 bf16: low16 = bf(a), high16 = bf(b)
__device__ __forceinline__ unsigned pk2(float a, float b) {
    unsigned ua = __float_as_uint(a) + 0x8000u;
    unsigned ub = __float_as_uint(b) + 0x8000u;
    return __builtin_amdgcn_perm(ub, ua, 0x07060302);
}

// ---------------- PE table value: global channel c (0..63), coord 0..15 ----------------
__device__ __forceinline__ float pe_tab_val(int c, int pos) {
    int c2 = (c < 22) ? c : (c < 44) ? (c - 22) : (c - 44);
    int is_cos = (c2 >= 11);
    int k = c2 - (is_cos ? 11 : 0);
    float freq = exp2f(-1.2079738526863135f * (float)k);
    float arg = (float)pos * freq;
    return is_cos ? cosf(arg) : sinf(arg);
}

// ---------------- Merged: x_pe + Xt + QKV (blocks 0..127) | conv weight reorg (blocks 128..) ----------------
__global__ __launch_bounds__(256) void k_pre(const float* __restrict__ x,
                                             const float* __restrict__ qw,
                                             const float* __restrict__ kw,
                                             const float* __restrict__ vw,
                                             const float* __restrict__ Wq,
                                             const float* __restrict__ Wk,
                                             const float* __restrict__ Wv,
                                             float* __restrict__ xpe,
                                             ushortT* __restrict__ Xt,
                                             ushortT* __restrict__ Wr,
                                             ushortT* __restrict__ Qb,
                                             ushortT* __restrict__ Kb,
                                             ushortT* __restrict__ Vtb) {
    int blk = blockIdx.x, t = threadIdx.x;
    if (blk < 128) {
        __shared__ float sT[64][65];       // fp32 x_pe tile (ch-major)
        __shared__ float sPE[64][17];
        __shared__ ushortT sWt[64][72];    // transposed bf16 weights (d-major)
        __shared__ ushortT sVt[64][72];    // V transpose staging
        int b = blk >> 6, pos0 = (blk & 63) * 64;

        // PE table
        #pragma unroll
        for (int k = 0; k < 4; k++) {
            int e = t + k * 256;           // 0..1023
            int c = e >> 4, coord = e & 15;
            sPE[c][coord] = pe_tab_val(c, coord);
        }
        __syncthreads();

        // x + PE -> sT, xpe
        int pin = t & 63, cg0 = t >> 6;
        #pragma unroll
        for (int pass = 0; pass < 16; pass++) {
            int c = pass * 4 + cg0;
            int pos = pos0 + pin;
            int coord = (c < 22) ? (pos >> 8) : (c < 44) ? ((pos >> 4) & 15) : (pos & 15);
            size_t gi = (size_t)(b * 64 + c) * NN + pos;
            float v = x[gi] + sPE[c][coord];
            xpe[gi] = v;
            sT[c][pin] = v;
        }
        __syncthreads();

        // Xt store (transposed bf16, guard row)
        {
            int icn = t & 63, pg = t >> 6;
            #pragma unroll
            for (int pass = 0; pass < 16; pass++) {
                int po = pass * 4 + pg;
                Xt[((size_t)b * XT_ROWS + pos0 + po + 1) * 64 + icn] = f2bf(sT[icn][po]);
            }
            if ((blk & 63) == 0 && t < 64)
                Xt[((size_t)b * XT_ROWS) * 64 + t] = 0;
        }

        // A-frags (token rows) from sT
        int w = t >> 6, l = t & 63, lane15 = l & 15, q = l >> 4;
        int row = w * 16 + lane15;
        short8 a0, a1;
        {
            union { ushortT u[8]; short8 s; } t0, t1;
            #pragma unroll
            for (int e = 0; e < 8; e++) {
                t0.u[e] = f2bf(sT[q * 8 + e][row]);
                t1.u[e] = f2bf(sT[32 + q * 8 + e][row]);
            }
            a0 = t0.s; a1 = t1.s;
        }

        // QKV via MFMA, weights staged per mat
        #pragma unroll
        for (int mat = 0; mat < 3; mat++) {
            const float* Wm = (mat == 0) ? Wq : (mat == 1) ? Wk : Wv;
            float sc = (mat == 0) ? QSCALE : 1.f;
            __syncthreads();   // protect sWt/sVt reuse
            #pragma unroll
            for (int p = 0; p < 4; p++) {
                int idx = t + p * 256;     // 0..1023
                int c = idx >> 4, d4 = (idx & 15) * 4;
                float4 wv = *(const float4*)&Wm[c * 64 + d4];
                sWt[d4 + 0][c] = f2bf(wv.x * sc);
                sWt[d4 + 1][c] = f2bf(wv.y * sc);
                sWt[d4 + 2][c] = f2bf(wv.z * sc);
                sWt[d4 + 3][c] = f2bf(wv.w * sc);
            }
            __syncthreads();

            float4v acc[4];
            #pragma unroll
            for (int cg = 0; cg < 4; cg++) {
                const ushortT* wrow = &sWt[cg * 16 + lane15][0];
                short8 b0 = *(const short8*)(wrow + q * 8);
                short8 b1 = *(const short8*)(wrow + 32 + q * 8);
                float4v a = (float4v)0.f;
                a = __builtin_amdgcn_mfma_f32_16x16x32_bf16(a0, b0, a, 0, 0, 0);
                a = __builtin_amdgcn_mfma_f32_16x16x32_bf16(a1, b1, a, 0, 0, 0);
                acc[cg] = a;
            }
            if (mat < 2) {
                ushortT* o = (mat == 0) ? Qb : Kb;
                #pragma unroll
                for (int cg = 0; cg < 4; cg++)
                    #pragma unroll
                    for (int r = 0; r < 4; r++)
                        o[((size_t)(b * NN + pos0 + w * 16 + q * 4 + r)) * 64 + cg * 16 + lane15] = f2bf(acc[cg][r]);
            } else {
                #pragma unroll
                for (int cg = 0; cg < 4; cg++)
                    #pragma unroll
                    for (int r = 0; r < 4; r++)
                        sVt[cg * 16 + lane15][w * 16 + q * 4 + r] = f2bf(acc[cg][r]);
                __syncthreads();
                int c2 = t >> 2, seg = t & 3;
                short8 v0 = *(const short8*)&sVt[c2][seg * 16];
                short8 v1 = *(const short8*)&sVt[c2][seg * 16 + 8];
                size_t base = ((size_t)(b * 64 + c2)) * NN + pos0 + seg * 16;
                *(short8*)(Vtb + base) = v0;
                *(short8*)(Vtb + base + 8) = v1;
            }
        }
    } else {
        // conv-tap weight reorg: Wr[tap][oc(80)][ic]
        int idx = (blk - 128) * 256 + t;
        if (idx < WQKV_OFF) {
            int ic = idx & 63;
            int oc = (idx >> 6) % 80;
            int tap = idx / 5120;
            float v;
            if (oc < 8)       v = qw[(oc * 64 + ic) * 27 + tap] * LOG2E;
            else if (oc < 16) v = kw[((oc - 8) * 64 + ic) * 27 + tap];
            else              v = vw[((oc - 16) * 64 + ic) * 27 + tap];
            Wr[idx] = f2bf(v);
        }
    }
}

// ---------------- LDS staging helpers for flash ----------------
template<int IS_TSA>
__device__ __forceinline__ void stage_load(short8* kst, short8* vst,
                                           const ushortT* __restrict__ Km,
                                           const ushortT* __restrict__ Vt,
                                           int b, int jb, int t) {
    if (IS_TSA) {
        #pragma unroll
        for (int ps = 0; ps < 2; ps++) {
            int idx = ps * 256 + t, j = idx >> 3, g = idx & 7;
            kst[ps] = *(const short8*)(Km + ((size_t)(b * NN + jb + j)) * 64 + g * 8);
        }
    } else {
        if (t < 64)
            kst[0] = *(const short8*)(Km + ((size_t)(b * NN + jb + t)) * 8);
    }
    #pragma unroll
    for (int ps = 0; ps < 2; ps++) {
        int idx = ps * 256 + t, c = idx >> 3, gj = idx & 7;
        vst[ps] = *(const short8*)(Vt + ((size_t)(b * 64 + c)) * NN + jb + gj * 8);
    }
}

template<int IS_TSA>
__device__ __forceinline__ void stage_write(const short8* kst, const short8* vst,
                                            ushortT* sK, ushortT* sV, int t) {
    if (IS_TSA) {
        #pragma unroll
        for (int ps = 0; ps < 2; ps++) {
            int idx = ps * 256 + t, j = idx >> 3, g = idx & 7;
            *(short8*)(sK + j * 64 + ((g ^ (j & 7)) * 8)) = kst[ps];
        }
    } else {
        if (t < 64)
            *(short8*)(sK + t * 64 + ((t & 7) * 8)) = kst[0];
    }
    #pragma unroll
    for (int ps = 0; ps < 2; ps++) {
        int idx = ps * 256 + t, c = idx >> 3, gj = idx & 7;
        *(short8*)(sV + c * 64 + ((gj ^ (c & 7)) * 8)) = vst[ps];
    }
}

// ---------------- MFMA flash body: 2 i-subtiles per wave (r12, unchanged) ----------------
template<int IS_TSA>
__device__ __forceinline__ void flash_body(int it, int jc, int b, int t,
                                           const ushortT* __restrict__ Qm,
                                           const ushortT* __restrict__ Km,
                                           const ushortT* __restrict__ Vt,
                                           float* __restrict__ pM,
                                           float* __restrict__ pL,
                                           ushortT* __restrict__ pAcc,
                                           ushortT* __restrict__ sKb,
                                           ushortT* __restrict__ sVb,
                                           ushortT* __restrict__ sPall) {
    constexpr int KCH = IS_TSA ? 2 : 1;
    constexpr int DQ  = IS_TSA ? 64 : 8;
    int w = t >> 6, l = t & 63;
    int lane15 = l & 15, q = l >> 4;
    int i0a = it * 128 + w * 16;
    ushortT* myP = sPall + w * (16 * 64);

    short8 qf[2][KCH];
    #pragma unroll
    for (int si = 0; si < 2; si++) {
        const ushortT* qrow = Qm + ((size_t)(b * NN + i0a + si * 64 + lane15)) * DQ;
        if (IS_TSA) {
            qf[si][0] = *(const short8*)(qrow + q * 8);
            qf[si][1] = *(const short8*)(qrow + 32 + q * 8);
        } else {
            short8 z = (short8)0;
            if (q == 0) z = *(const short8*)qrow;
            qf[si][0] = z;
        }
    }

    float m_run[2] = {-3e38f, -3e38f}, Lacc[2] = {0.f, 0.f};
    float4v O[2][4];
    #pragma unroll
    for (int si = 0; si < 2; si++)
        #pragma unroll
        for (int cs = 0; cs < 4; cs++) O[si][cs] = (float4v)0.f;

    const int jbase0 = jc * (NN / NJ);

    short8 kst[2], vst[2];
    stage_load<IS_TSA>(kst, vst, Km, Vt, b, jbase0, t);
    stage_write<IS_TSA>(kst, vst, sKb, sVb, t);
    __syncthreads();

    for (int jt = 0; jt < NT; jt++) {
        int cur = jt & 1;
        ushortT* cK = sKb + cur * 4096;
        ushortT* cV = sVb + cur * 4096;
        bool more = (jt + 1 < NT);

        if (more) stage_load<IS_TSA>(kst, vst, Km, Vt, b, jbase0 + (jt + 1) * 64, t);

        short8 kf[4][KCH];
        #pragma unroll
        for (int sub = 0; sub < 4; sub++) {
            int jr = sub * 16 + lane15;
            if (IS_TSA) {
                kf[sub][0] = *(const short8*)(cK + jr * 64 + (((0 * 4 + q) ^ (lane15 & 7)) * 8));
                kf[sub][1] = *(const short8*)(cK + jr * 64 + (((1 * 4 + q) ^ (lane15 & 7)) * 8));
            } else {
                short8 z = (short8)0;
                if (q == 0) z = *(const short8*)(cK + jr * 64 + ((lane15 & 7) * 8));
                kf[sub][0] = z;
            }
        }

        float4v s[2][4];
        #pragma unroll
        for (int si = 0; si < 2; si++)
            #pragma unroll
            for (int sub = 0; sub < 4; sub++) {
                float4v acc = (float4v)0.f;
                #pragma unroll
                for (int kc = 0; kc < KCH; kc++)
                    acc = __builtin_amdgcn_mfma_f32_16x16x32_bf16(kf[sub][kc], qf[si][kc], acc, 0, 0, 0);
                s[si][sub] = acc;
            }

        short8 va[4], vbf[4];
        #pragma unroll
        for (int sub = 0; sub < 4; sub++) {
            int cr = sub * 16 + lane15;
            va[sub]  = *(const short8*)(cV + cr * 64 + ((q ^ (lane15 & 7)) * 8));
            vbf[sub] = *(const short8*)(cV + cr * 64 + (((4 + q) ^ (lane15 & 7)) * 8));
        }

        #pragma unroll
        for (int si = 0; si < 2; si++) {
            float tmax = fmaxf(fmaxf(fmaxf(s[si][0][0], s[si][0][1]), fmaxf(s[si][0][2], s[si][0][3])),
                               fmaxf(fmaxf(s[si][1][0], s[si][1][1]), fmaxf(s[si][1][2], s[si][1][3])));
            float tmax2 = fmaxf(fmaxf(fmaxf(s[si][2][0], s[si][2][1]), fmaxf(s[si][2][2], s[si][2][3])),
                                fmaxf(fmaxf(s[si][3][0], s[si][3][1]), fmaxf(s[si][3][2], s[si][3][3])));
            tmax = fmaxf(tmax, tmax2);
            tmax = fmaxf(tmax, __shfl_xor(tmax, 16));
            tmax = fmaxf(tmax, __shfl_xor(tmax, 32));
            float mnew = fmaxf(m_run[si], tmax);

            if (__any(mnew > m_run[si])) {
                float corr = exp2f(m_run[si] - mnew);
                Lacc[si] *= corr;
                float c0 = __shfl(corr, q * 4 + 0);
                float c1 = __shfl(corr, q * 4 + 1);
                float c2 = __shfl(corr, q * 4 + 2);
                float c3 = __shfl(corr, q * 4 + 3);
                #pragma unroll
                for (int cs = 0; cs < 4; cs++) {
                    O[si][cs][0] *= c0; O[si][cs][1] *= c1;
                    O[si][cs][2] *= c2; O[si][cs][3] *= c3;
                }
            }
            m_run[si] = mnew;

            #pragma unroll
            for (int sub = 0; sub < 4; sub++) {
                float p0 = exp2f(s[si][sub][0] - mnew);
                float p1 = exp2f(s[si][sub][1] - mnew);
                float p2 = exp2f(s[si][sub][2] - mnew);
                float p3 = exp2f(s[si][sub][3] - mnew);
                Lacc[si] += (p0 + p1) + (p2 + p3);
                unsigned lo = pk2(p0, p1), hi = pk2(p2, p3);
                int g = sub * 2 + (q >> 1);
                unsigned* wp = (unsigned*)(myP + lane15 * 64 + ((g ^ (lane15 & 7)) * 8) + (q & 1) * 4);
                wp[0] = lo; wp[1] = hi;
            }

            short8 pf0 = *(const short8*)(myP + lane15 * 64 + (((0 * 4 + q) ^ (lane15 & 7)) * 8));
            short8 pf1 = *(const short8*)(myP + lane15 * 64 + (((1 * 4 + q) ^ (lane15 & 7)) * 8));

            #pragma unroll
            for (int sub = 0; sub < 4; sub++) {
                O[si][sub] = __builtin_amdgcn_mfma_f32_16x16x32_bf16(pf0, va[sub], O[si][sub], 0, 0, 0);
                O[si][sub] = __builtin_amdgcn_mfma_f32_16x16x32_bf16(pf1, vbf[sub], O[si][sub], 0, 0, 0);
            }
        }

        if (more)
            stage_write<IS_TSA>(kst, vst, sKb + (cur ^ 1) * 4096, sVb + (cur ^ 1) * 4096, t);
        __syncthreads();
    }

    #pragma unroll
    for (int si = 0; si < 2; si++) {
        size_t base = (size_t)(b * NJ + jc) * NN + i0a + si * 64;
        float Ls = Lacc[si];
        Ls += __shfl_xor(Ls, 16);
        Ls += __shfl_xor(Ls, 32);
        if (q == 0) {
            pL[base + lane15] = Ls;
            pM[base + lane15] = m_run[si];
        }
        #pragma unroll
        for (int cs = 0; cs < 4; cs++)
            #pragma unroll
            for (int r = 0; r < 4; r++)
                pAcc[(base + q * 4 + r) * 64 + cs * 16 + lane15] = f2bf(O[si][cs][r]);
    }
}

// ---------------- Reduce one partial set ----------------
__device__ __forceinline__ void reduce_set(const float* __restrict__ pM,
                                           const float* __restrict__ pL,
                                           const ushortT* __restrict__ pAcc,
                                           int b, int n, int seg, float* v) {
    float mv[NJ], M = -3e38f;
    #pragma unroll
    for (int jcc = 0; jcc < NJ; jcc++) {
        mv[jcc] = pM[(size_t)(b * NJ + jcc) * NN + n];
        M = fmaxf(M, mv[jcc]);
    }
    float L = 0.f;
    #pragma unroll
    for (int e = 0; e < 8; e++) v[e] = 0.f;
    #pragma unroll
    for (int jcc = 0; jcc < NJ; jcc++) {
        size_t rb = (size_t)(b * NJ + jcc) * NN + n;
        float wgt = exp2f(mv[jcc] - M);
        L += pL[rb] * wgt;
        short8 x0 = *(const short8*)(pAcc + rb * 64 + seg * 8);
        #pragma unroll
        for (int e = 0; e < 8; e++) v[e] += wgt * bf2f(x0[e]);
    }
    float invL = 1.f / L;
    #pragma unroll
    for (int e = 0; e < 8; e++) v[e] *= invL;
}

// ---------------- Fused: conv (blocks 0..127) + TSA flash (blocks 128..639) (r12, unchanged) ----------------
__global__ __launch_bounds__(256, 3) void k_tsacv(const ushortT* __restrict__ Qb,
                                                  const ushortT* __restrict__ Kb,
                                                  const ushortT* __restrict__ Vtb,
                                                  const ushortT* __restrict__ Xt,
                                                  const ushortT* __restrict__ Wr,
                                                  const float* __restrict__ qb,
                                                  const float* __restrict__ kb,
                                                  const float* __restrict__ vb,
                                                  ushortT* __restrict__ Mt,
                                                  ushortT* __restrict__ Nt,
                                                  ushortT* __restrict__ Wvt,
                                                  float* __restrict__ pMt, float* __restrict__ pLt,
                                                  ushortT* __restrict__ pAccT) {
    __shared__ ushortT sm[20480];   // 40 KB: flash K/V/P | conv W double-buffer
    int bx = blockIdx.x, t = threadIdx.x;
    if (bx >= 128) {
        int fb = bx - 128;                 // 0..511
        int it = fb & 31, jc = (fb >> 5) & 7, b = fb >> 8;
        flash_body<1>(it, jc, b, t, Qb, Kb, Vtb, pMt, pLt, pAccT,
                      sm, sm + 8192, sm + 16384);
    } else {
        int cv = bx;                       // 0..127
        int tile = cv & 63, b = cv >> 6;
        int w = t >> 6, l = t & 63, lane15 = l & 15, q = l >> 4;
        int pos0 = tile * 64 + w * 16;
        const ushortT* xb = Xt + (size_t)b * XT_ROWS * 64;
        int pos = pos0 + lane15;
        int dz = pos & 15, wy = (pos >> 4) & 15, hx = pos >> 8;

        ushortT* sW = sm;                  // 2 x 5120 ushorts

        float4v accA[5], accB[5];
        #pragma unroll
        for (int o = 0; o < 5; o++) { accA[o] = (float4v)0.f; accB[o] = (float4v)0.f; }

        short8 ws[3];
        auto ldW = [&](int tap) {
            #pragma unroll
            for (int c3 = 0; c3 < 3; c3++) {
                int idx = t + c3 * 256;
                if (idx < 640)
                    ws[c3] = *(const short8*)(Wr + (size_t)tap * 5120 + idx * 8);
            }
        };
        auto wrW = [&](ushortT* buf) {
            #pragma unroll
            for (int c3 = 0; c3 < 3; c3++) {
                int idx = t + c3 * 256;
                if (idx < 640) {
                    int row = idx >> 3, g = idx & 7;
                    *(short8*)(buf + row * 64 + ((g ^ (row & 7)) * 8)) = ws[c3];
                }
            }
        };

        ldW(0);
        wrW(sW);
        __syncthreads();

        #pragma unroll
        for (int tap = 0; tap < 27; tap++) {
            const int dh = tap / 9 - 1, dw = (tap / 3) % 3 - 1, dd = tap % 3 - 1;
            const int shift = dh * 256 + dw * 16 + dd;
            ushortT* cW = sW + (tap & 1) * 5120;
            bool more = (tap + 1 < 27);

            if (more) ldW(tap + 1);

            bool ok = ((unsigned)(hx + dh) < 16u) &&
                      ((unsigned)(wy + dw) < 16u) &&
                      ((unsigned)(dz + dd) < 16u);
            int row = ok ? (pos + shift + 1) : 0;
            const ushortT* xrow = xb + (size_t)row * 64 + q * 8;
            short8 b0 = *(const short8*)xrow;
            short8 b1 = *(const short8*)(xrow + 32);

            #pragma unroll
            for (int o = 0; o < 5; o++) {
                int wr2 = o * 16 + lane15;
                short8 a0 = *(const short8*)(cW + wr2 * 64 + ((q ^ (lane15 & 7)) * 8));
                short8 a1 = *(const short8*)(cW + wr2 * 64 + (((4 + q) ^ (lane15 & 7)) * 8));
                accA[o] = __builtin_amdgcn_mfma_f32_16x16x32_bf16(a0, b0, accA[o], 0, 0, 0);
                accB[o] = __builtin_amdgcn_mfma_f32_16x16x32_bf16(a1, b1, accB[o], 0, 0, 0);
            }

            if (more) wrW(sW + ((tap + 1) & 1) * 5120);
            __syncthreads();
        }

        #pragma unroll
        for (int o = 0; o < 5; o++) {
            float4v accT = accA[o] + accB[o];
            if (o == 0) {
                #pragma unroll
                for (int r = 0; r < 4; r++) {
                    int ol = q * 4 + r;
                    float v = accT[r];
                    if (ol < 8)
                        Mt[((size_t)(b * NN + pos)) * 8 + ol] = f2bf(v + qb[ol] * LOG2E);
                    else
                        Nt[((size_t)(b * NN + pos)) * 8 + (ol - 8)] = f2bf(v + kb[ol - 8]);
                }
            } else {
                #pragma unroll
                for (int r = 0; r < 4; r++) {
                    int oc = (o - 1) * 16 + q * 4 + r;
                    Wvt[((size_t)(b * 64 + oc)) * NN + pos] = f2bf(accT[r] + vb[oc]);
                }
            }
        }
    }
}

// ---------------- GSA flash (blocks 0..511) + TSA-reduce tail (blocks 512..767) ----------------
__global__ __launch_bounds__(256, 3) void k_gsa(const ushortT* __restrict__ Mtb,
                                                const ushortT* __restrict__ Ntb,
                                                const ushortT* __restrict__ Wvtb,
                                                float* __restrict__ pMg, float* __restrict__ pLg,
                                                ushortT* __restrict__ pAccG,
                                                const float* __restrict__ pMt,
                                                const float* __restrict__ pLt,
                                                const ushortT* __restrict__ pAccT,
                                                const float* __restrict__ xpe,
                                                const float* __restrict__ lam1,
                                                float* __restrict__ out) {
    __shared__ ushortT sm[20480];
    int bx = blockIdx.x, t = threadIdx.x;
    if (bx < 512) {
        int it = bx & 31, jc = (bx >> 5) & 7, b = bx >> 8;
        flash_body<0>(it, jc, b, t, Mtb, Ntb, Wvtb, pMg, pLg, pAccG,
                      sm, sm + 8192, sm + 16384);
    } else {
        // TSA reduce + epilogue: out = lam1*tsa + xpe  (runs concurrent with GSA flash)
        int rb = bx - 512;                 // 0..255
        int b = rb >> 7, n0 = (rb & 127) * 32;
        float (*sT_)[65] = (float(*)[65])sm;
        int pp = t >> 3, seg = t & 7, n = n0 + pp;

        float vt[8];
        reduce_set(pMt, pLt, pAccT, b, n, seg, vt);
        #pragma unroll
        for (int e = 0; e < 8; e++) sT_[pp][seg * 8 + e] = vt[e];
        __syncthreads();

        int c = t >> 2, ns = (t & 3) * 8;
        float la1 = lam1[0];
        size_t ob = ((size_t)(b * 64 + c)) * NN + n0 + ns;
        const float* xp = xpe + ob;
        #pragma unroll
        for (int j = 0; j < 8; j += 4) {
            float4 ov;
            ov.x = la1 * sT_[ns + j + 0][c] + xp[j + 0];
            ov.y = la1 * sT_[ns + j + 1][c] + xp[j + 1];
            ov.z = la1 * sT_[ns + j + 2][c] + xp[j + 2];
            ov.w = la1 * sT_[ns + j + 3][c] + xp[j + 3];
            *(float4*)(out + ob + j) = ov;
        }
    }
}

// ---------------- Final: out += lam2 * gsa ----------------
__global__ __launch_bounds__(256) void k_reduce_g(const float* __restrict__ pMg,
                                                  const float* __restrict__ pLg,
                                                  const ushortT* __restrict__ pAccG,
                                                  const float* __restrict__ lam2,
                                                  float* __restrict__ out) {
    __shared__ float sG[32][65];
    int t = threadIdx.x;
    int b = blockIdx.y;
    int n0 = blockIdx.x * 32;
    int pp = t >> 3, seg = t & 7;
    int n = n0 + pp;

    float vg[8];
    reduce_set(pMg, pLg, pAccG, b, n, seg, vg);
    #pragma unroll
    for (int e = 0; e < 8; e++) sG[pp][seg * 8 + e] = vg[e];
    __syncthreads();

    int c = t >> 2, ns = (t & 3) * 8;
    float la2 = lam2[0];
    size_t ob = ((size_t)(b * 64 + c)) * NN + n0 + ns;
    #pragma unroll
    for (int j = 0; j < 8; j += 4) {
        float4 cur = *(const float4*)(out + ob + j);
        cur.x += la2 * sG[ns + j + 0][c];
        cur.y += la2 * sG[ns + j + 1][c];
        cur.z += la2 * sG[ns + j + 2][c];
        cur.w += la2 * sG[ns + j + 3][c];
        *(float4*)(out + ob + j) = cur;
    }
}

extern "C" void kernel_launch(void* const* d_in, const int* in_sizes, int n_in,
                              void* d_out, int out_size, void* d_ws, size_t ws_size,
                              hipStream_t stream) {
    const float* x    = (const float*)d_in[0];
    const float* Wq   = (const float*)d_in[1];
    const float* Wk   = (const float*)d_in[2];
    const float* Wv   = (const float*)d_in[3];
    const float* qw   = (const float*)d_in[4];
    const float* qb   = (const float*)d_in[5];
    const float* kw   = (const float*)d_in[6];
    const float* kb   = (const float*)d_in[7];
    const float* vw   = (const float*)d_in[8];
    const float* vb   = (const float*)d_in[9];
    const float* lam1 = (const float*)d_in[10];
    const float* lam2 = (const float*)d_in[11];
    float* out = (float*)d_out;

    char* W = (char*)d_ws;
    float*   xpe   = (float*)(W);                               // 2 MB
    ushortT* Qb    = (ushortT*)(W + (2u << 20));                // 1 MB
    ushortT* Kb    = (ushortT*)(W + (3u << 20));                // 1 MB
    ushortT* Vtb   = (ushortT*)(W + (4u << 20));                // 1 MB
    ushortT* Mtb   = (ushortT*)(W + (5u << 20));                // 128 KB
    ushortT* Ntb   = (ushortT*)(W + (5u << 20) + (1u << 17));   // 128 KB
    ushortT* Wvtb  = (ushortT*)(W + (5u << 20) + (2u << 17));   // 1 MB
    ushortT* Xt    = (ushortT*)(W + (6u << 20) + (2u << 17));   // ~1.0 MB
    ushortT* Wr    = (ushortT*)(W + (7u << 20) + (1u << 19));   // ~0.3 MB
    float*   pLt   = (float*)(W + (8u << 20));                  // 256 KB (NJ=8)
    float*   pLg   = (float*)(W + (8u << 20) + (1u << 18));     // 256 KB
    float*   pMt   = (float*)(W + (8u << 20) + (2u << 18));     // 256 KB
    float*   pMg   = (float*)(W + (8u << 20) + (3u << 18));     // 256 KB
    ushortT* pAccT = (ushortT*)(W + (9u << 20));                // 8 MB
    ushortT* pAccG = (ushortT*)(W + (17u << 20));               // 8 MB (ends 25 MB)

    // 1. x_pe + Xt + QKV (blocks 0..127) + conv weight reorg (blocks 128..667)
    k_pre<<<dim3(128 + WQKV_OFF / 256), dim3(256), 0, stream>>>(
        x, qw, kw, vw, Wq, Wk, Wv, xpe, Xt, Wr, Qb, Kb, Vtb);
    // 2. fused conv (128 blocks) + TSA flash (512 blocks)
    k_tsacv<<<dim3(128 + 32 * NJ * BB), dim3(256), 0, stream>>>(
        Qb, Kb, Vtb, Xt, Wr, qb, kb, vb, Mtb, Ntb, Wvtb, pMt, pLt, pAccT);
    // 3. GSA flash (512 blocks) + concurrent TSA-reduce/epilogue (256 blocks)
    k_gsa<<<dim3(512 + 256), dim3(256), 0, stream>>>(
        Mtb, Ntb, Wvtb, pMg, pLg, pAccG, pMt, pLt, pAccT, xpe, lam1, out);
    // 4. final GSA reduce: out += lam2 * gsa
    k_reduce_g<<<dim3(NN / 32, BB), dim3(256), 0, stream>>>(
        pMg, pLg, pAccG, lam2, out);
}